// Round 10
// baseline (1048.520 us; speedup 1.0000x reference)
//
#include <hip/hip_runtime.h>
#include <type_traits>
#include <utility>

typedef unsigned short u16;
typedef __attribute__((ext_vector_type(8))) short short8;
typedef __attribute__((ext_vector_type(8))) __bf16 bf16v8;
typedef __attribute__((ext_vector_type(4))) float f32x4;
typedef __attribute__((ext_vector_type(16))) float f32x16;

template <typename T, typename = void> struct mfma_ok : std::false_type {};
template <typename T>
struct mfma_ok<T, std::void_t<decltype(__builtin_amdgcn_mfma_f32_16x16x32_bf16(
    std::declval<T>(), std::declval<T>(), std::declval<f32x4>(), 0, 0, 0))>>
    : std::true_type {};
using frag8 = std::conditional_t<mfma_ok<bf16v8>::value, bf16v8, short8>;

#define MFMA16(a, b, c) __builtin_amdgcn_mfma_f32_16x16x32_bf16((a), (b), (c), 0, 0, 0)
#define MFMA32(a, b, c) __builtin_amdgcn_mfma_f32_32x32x16_bf16((a), (b), (c), 0, 0, 0)

__device__ __forceinline__ float bf2f(u16 u) {
  unsigned v = ((unsigned)u) << 16;
  return __builtin_bit_cast(float, v);
}
__device__ __forceinline__ u16 f2bf(float f) {
  unsigned u = __builtin_bit_cast(unsigned, f);
  u = (u + 0x7fffu + ((u >> 16) & 1u)) >> 16;
  return (u16)u;
}
__device__ __forceinline__ unsigned cvtpk_bf16(float lo, float hi) {
  unsigned r;
  asm("v_cvt_pk_bf16_f32 %0, %1, %2" : "=v"(r) : "v"(lo), "v"(hi));
  return r;
}
// async global->LDS, 16B per lane; lds ptr must be wave-uniform base (+lane*16 implicit)
__device__ __forceinline__ void gl16(const u16* g, u16* l) {
  __builtin_amdgcn_global_load_lds((__attribute__((address_space(1))) void*)(g),
                                   (__attribute__((address_space(3))) void*)(l), 16, 0, 0);
}
__device__ __forceinline__ void vmw8() { asm volatile("s_waitcnt vmcnt(8)" ::: "memory"); }
__device__ __forceinline__ void vmw0() { asm volatile("s_waitcnt vmcnt(0)" ::: "memory"); }
__device__ __forceinline__ void lgw0() { asm volatile("s_waitcnt lgkmcnt(0)" ::: "memory"); }

// ---------------------------------------------------------------- score
__global__ void k_score(const float* __restrict__ prob, const float* __restrict__ wfix,
                        float* __restrict__ scores) {
  const int b = blockIdx.x, tid = threadIdx.x;
  __shared__ float ent[64 * 64];
  __shared__ float wf[64];
  if (tid < 64) wf[tid] = wfix[tid];
  const float* pb = prob + (size_t)b * 4 * 4096;
  for (int p = tid; p < 4096; p += 256) {
    float e = 0.f;
#pragma unroll
    for (int ch = 0; ch < 4; ++ch) {
      float v = pb[ch * 4096 + p];
      e -= v * log2f(v + 1e-10f);
    }
    ent[p] = e;
  }
  __syncthreads();
  if (tid < 225) {
    int wy = tid / 15, wx = tid % 15;
    float s = 0.f;
    for (int a = 0; a < 8; ++a)
      for (int c = 0; c < 8; ++c)
        s += ent[(wy * 4 + a) * 64 + wx * 4 + c] * wf[a * 8 + c];
    scores[b * 225 + tid] = s * (1.0f / 64.0f);
  }
}

// ---------------------------------------------------------------- nms
__device__ __forceinline__ float iou_pair(int wa, int wb) {
  float x1a = (float)((wa % 15) * 8), y1a = (float)((wa / 15) * 8);
  float x1b = (float)((wb % 15) * 8), y1b = (float)((wb / 15) * 8);
  float iw = fminf(x1a, x1b) + 15.f - fmaxf(x1a, x1b);
  float ih = fminf(y1a, y1b) + 15.f - fmaxf(y1a, y1b);
  iw = fmaxf(iw, 0.f);
  ih = fmaxf(ih, 0.f);
  float inter = iw * ih;
  return inter / (450.f - inter);
}

__global__ void k_nms(const float* __restrict__ scores, int* __restrict__ sel,
                      int* __restrict__ kept, float* __restrict__ mult) {
  const int b = blockIdx.x, t = threadIdx.x;
  __shared__ float s[225];
  __shared__ int order[225];
  __shared__ unsigned char supp[225];
  __shared__ int idx44[44];
  __shared__ int ks[225];
  __shared__ float ml[225];
  if (t < 225) s[t] = scores[b * 225 + t];
  __syncthreads();
  if (t < 225) {
    float st = s[t];
    int r = 0;
    for (int j = 0; j < 225; ++j) {
      float sj = s[j];
      r += (sj > st) || (sj == st && j < t);
    }
    order[r] = t;
    supp[t] = 0;
    ks[t] = -1;
    ml[t] = 0.f;
  }
  __syncthreads();
  for (int i = 0; i < 224; ++i) {
    if (t > i && t < 225 && !supp[i]) {
      if (iou_pair(order[i], order[t]) > 0.2f) supp[t] = 1;
    }
    __syncthreads();
  }
  if (t == 0) {
    int k = 0;
    for (int i = 0; i < 225 && k < 44; ++i)
      if (!supp[i]) idx44[k++] = order[i];
    while (k < 44) idx44[k++] = order[224];
    for (int k2 = 0; k2 < 44; ++k2) {
      int w = idx44[k2];
      if (ks[w] < 0) ks[w] = k2;
      ml[w] += 1.f;
    }
  }
  __syncthreads();
  if (t < 225) {
    kept[b * 225 + t] = ks[t];
    mult[b * 225 + t] = ml[t];
  }
  if (t < 44) sel[b * 44 + t] = idx44[t];
}

// ---------------------------------------------------------------- weight cast
__global__ void k_castw(const float* __restrict__ Wq, const float* __restrict__ Wo,
                        u16* __restrict__ wqb, u16* __restrict__ wob) {
  int idx = blockIdx.x * 256 + threadIdx.x;
  if (idx < 786432) wqb[idx] = f2bf(Wq[idx]);
  int i2 = idx - 786432;
  if (i2 >= 0 && i2 < 262144) wob[i2] = f2bf(Wo[i2]);
}

// ---------------------------------------------------------------- gather + bilinear (direct 4-tap)
__global__ __launch_bounds__(256) void k_gather(const float* __restrict__ x,
                                                const int* __restrict__ sel,
                                                u16* __restrict__ xi) {
  const size_t idx = (size_t)blockIdx.x * 256 + threadIdx.x;
  const int dc = (int)(idx & 63);
  const int pq = (int)((idx >> 6) & 255);
  const int g = (int)(idx >> 14);
  const int b = g / 44;
  const int w = sel[g];
  const int sy = (w / 15) * 8, sx = (w % 15) * 8;
  const int p = pq >> 4, q = pq & 15;
  float rp = ((float)p + 0.5f) * 0.9375f;
  int i0 = (int)rp;
  float fp = rp - (float)i0;
  float rq = ((float)q + 0.5f) * 0.9375f;
  int j0 = (int)rq;
  float fq = rq - (float)j0;
  const float w00 = (1.f - fp) * (1.f - fq), w01 = (1.f - fp) * fq;
  const float w10 = fp * (1.f - fq), w11 = fp * fq;
  const float* xb = x + ((size_t)b * 16384 + (size_t)(sy + i0) * 128 + sx + j0) * 512 + dc * 8;
  const float4* t00 = (const float4*)xb;
  const float4* t01 = (const float4*)(xb + 512);
  const float4* t10 = (const float4*)(xb + 512 * 128);
  const float4* t11 = (const float4*)(xb + 512 * 129);
  float acc[8];
#pragma unroll
  for (int h = 0; h < 2; ++h) {
    float4 a = t00[h], bb = t01[h], c = t10[h], d = t11[h];
    acc[h * 4 + 0] = w00 * a.x + w01 * bb.x + w10 * c.x + w11 * d.x;
    acc[h * 4 + 1] = w00 * a.y + w01 * bb.y + w10 * c.y + w11 * d.y;
    acc[h * 4 + 2] = w00 * a.z + w01 * bb.z + w10 * c.z + w11 * d.z;
    acc[h * 4 + 3] = w00 * a.w + w01 * bb.w + w10 * c.w + w11 * d.w;
  }
  short8 o;
#pragma unroll
  for (int e = 0; e < 8; ++e) o[e] = (short)f2bf(acc[e]);
  *(short8*)&xi[((size_t)g * 256 + pq) * 512 + dc * 8] = o;
}

// ---------------------------------------------------------------- GEMM 256x256, BK=64, 8 waves
// Counted-vmcnt dbuf + T2 XOR swizzle + per-mh fragment hoist; compiler-scheduled lgkm inside
// the tile, explicit drain only before the buffer-release barrier.
template <int BIAS>
__global__ __launch_bounds__(512, 2) void k_gemm256(const u16* __restrict__ A,
                                                    const u16* __restrict__ B, u16* __restrict__ C,
                                                    const float* __restrict__ bias, int M, int N,
                                                    int K, int nbn) {
  __shared__ u16 sA[2][256 * 64];
  __shared__ u16 sB[2][256 * 64];
  const int tid = threadIdx.x, lane = tid & 63, wv = tid >> 6;
  const int f = blockIdx.x;
  const int q8 = gridDim.x >> 3;
  const int wg = (f & 7) * q8 + (f >> 3);
  const int bm = wg / nbn, bn = wg % nbn;
  const int wm = (wv >> 2) * 128, wn = (wv & 3) * 64;
  const int l15 = lane & 15, k8 = (lane >> 4) * 8;
  const int xorv = (l15 & 7) * 8;  // read-side swizzle (elements)
  const int srow = tid >> 3;
  const int sc8 = ((tid ^ (tid >> 3)) & 7) * 8;  // pre-swizzled source col
  const u16* Ab = A + (size_t)(bm * 256 + srow) * K + sc8;
  const u16* Bb = B + (size_t)(bn * 256 + srow) * K + sc8;

  f32x4 acc[8][4] = {};

#define STAGE(kt, buf)                                                       \
  {                                                                          \
    const int ko = (kt) * 64;                                                \
    _Pragma("unroll") for (int c = 0; c < 4; ++c) {                          \
      gl16(Ab + (size_t)(c * 64) * K + ko, &sA[buf][c * 4096 + wv * 512]);   \
      gl16(Bb + (size_t)(c * 64) * K + ko, &sB[buf][c * 4096 + wv * 512]);   \
    }                                                                        \
  }

  STAGE(0, 0);
  STAGE(1, 1);

  for (int t = 0; t < 8; ++t) {
    const int buf = t & 1;
    if (t == 7)
      vmw0();
    else
      vmw8();  // counted: next tile's 8 loads stay in flight
    __builtin_amdgcn_sched_barrier(0);
    __builtin_amdgcn_s_barrier();  // tile t resident for all waves
#pragma unroll
    for (int mh = 0; mh < 2; ++mh) {
      frag8 af[4][2], bf[2][2][2];
#pragma unroll
      for (int i = 0; i < 4; ++i)
#pragma unroll
        for (int kk = 0; kk < 2; ++kk)
          af[i][kk] = *(const frag8*)&sA[buf][(wm + (mh * 4 + i) * 16 + l15) * 64 +
                                             ((kk * 32 + k8) ^ xorv)];
#pragma unroll
      for (int nh = 0; nh < 2; ++nh)
#pragma unroll
        for (int j = 0; j < 2; ++j)
#pragma unroll
          for (int kk = 0; kk < 2; ++kk)
            bf[nh][j][kk] = *(const frag8*)&sB[buf][(wn + (nh * 2 + j) * 16 + l15) * 64 +
                                                    ((kk * 32 + k8) ^ xorv)];
      __builtin_amdgcn_s_setprio(1);
#pragma unroll
      for (int nh = 0; nh < 2; ++nh)
#pragma unroll
        for (int i = 0; i < 4; ++i)
#pragma unroll
          for (int j = 0; j < 2; ++j)
#pragma unroll
            for (int kk = 0; kk < 2; ++kk)
              acc[mh * 4 + i][nh * 2 + j] =
                  MFMA16(af[i][kk], bf[nh][j][kk], acc[mh * 4 + i][nh * 2 + j]);
      __builtin_amdgcn_s_setprio(0);
    }
    lgw0();  // this wave's ds_reads fully retired before buf can be overwritten
    __builtin_amdgcn_sched_barrier(0);
    __builtin_amdgcn_s_barrier();  // all waves done reading buf
    if (t < 6) STAGE(t + 2, buf);  // issued here: flies under next tile's compute
  }
#undef STAGE

  const int cc = lane & 15, rr = (lane >> 4) * 4;
#pragma unroll
  for (int i = 0; i < 8; ++i)
#pragma unroll
    for (int j = 0; j < 4; ++j) {
      int col = bn * 256 + wn + j * 16 + cc;
      float badd = BIAS ? bias[col] : 0.f;
#pragma unroll
      for (int e = 0; e < 4; ++e) {
        int row = bm * 256 + wm + i * 16 + rr + e;
        C[(size_t)row * N + col] = f2bf(acc[i][j][e] + badd);
      }
    }
}

// ---------------------------------------------------------------- attention (swapped 32x32)
// One block per (win, head); 4 waves x 64 q-rows. K AND V double-buffered per 64-key block.
// 4 blocks/CU (LDS 35.3KB x4 = 141KB); K-frags hoisted across qt (read once per kb).
__global__ __launch_bounds__(256, 4) void k_attn(const u16* __restrict__ qkv,
                                                 u16* __restrict__ aout) {
  const int g = blockIdx.x;
  const int win = g >> 3, h = g & 7;
  const int tid = threadIdx.x, lane = tid & 63, wv = tid >> 6;
  const int l31 = lane & 31, l5 = lane >> 5;
  __shared__ u16 smem[17664];  // Kb[2][64][68] (8704 u16) | Vt[2][64][70] (8960 u16)
  u16* KbB = smem;
  u16* VtB = smem + 8704;
  const u16* base = qkv + (size_t)win * 256 * 1536;
  const u16* kbase = base + 512 + h * 64;
  const u16* vbase = base + 1024 + h * 64;
  const int prow = tid >> 2, pc16 = (tid & 3) * 16;

  // Q B-frags first (longest-latency dependency)
  frag8 qf[2][4];
#pragma unroll
  for (int qt = 0; qt < 2; ++qt)
#pragma unroll
    for (int c = 0; c < 4; ++c)
      qf[qt][c] = *(const frag8*)(base + (size_t)(wv * 64 + qt * 32 + l31) * 1536 + h * 64 +
                                  c * 16 + l5 * 8);
  // K block 0 + V block 0 (thread: key=prow, d-range pc16..pc16+15)
  {
    const u16* kp = kbase + (size_t)prow * 1536 + pc16;
    short8 ka = *(const short8*)kp;
    short8 kb2 = *(const short8*)(kp + 8);
    const u16* vp = vbase + (size_t)prow * 1536 + pc16;
    short8 va = *(const short8*)vp;
    short8 vb2 = *(const short8*)(vp + 8);
    *(short8*)&KbB[prow * 68 + pc16] = ka;
    *(short8*)&KbB[prow * 68 + pc16 + 8] = kb2;
#pragma unroll
    for (int e = 0; e < 8; ++e) {
      VtB[(pc16 + e) * 70 + prow] = (u16)va[e];
      VtB[(pc16 + 8 + e) * 70 + prow] = (u16)vb2[e];
    }
  }
  __syncthreads();

  f32x16 of[2][2] = {};
  float m_run[2] = {-3e38f, -3e38f};
  float l_run[2] = {0.f, 0.f};

  int cur = 0;
  for (int kb = 0; kb < 4; ++kb) {
    short8 pk0 = {}, pk1 = {}, pv0 = {}, pv1 = {};
    if (kb < 3) {
      const u16* kp = kbase + (size_t)((kb + 1) * 64 + prow) * 1536 + pc16;
      pk0 = *(const short8*)kp;
      pk1 = *(const short8*)(kp + 8);
      const u16* vp = vbase + (size_t)((kb + 1) * 64 + prow) * 1536 + pc16;
      pv0 = *(const short8*)vp;
      pv1 = *(const short8*)(vp + 8);
    }
    // K-frags once per kb, shared by both qt passes
    frag8 kf[2][4];
#pragma unroll
    for (int kr = 0; kr < 2; ++kr)
#pragma unroll
      for (int c = 0; c < 4; ++c)
        kf[kr][c] = *(const frag8*)&KbB[cur * 4352 + (kr * 32 + l31) * 68 + c * 16 + l5 * 8];
#pragma unroll
    for (int qt = 0; qt < 2; ++qt) {
      f32x16 s0 = {}, s1 = {};
#pragma unroll
      for (int c = 0; c < 4; ++c) {
        s0 = MFMA32(kf[0][c], qf[qt][c], s0);
        s1 = MFMA32(kf[1][c], qf[qt][c], s1);
      }
      float tm[16];
#pragma unroll
      for (int r = 0; r < 16; ++r) tm[r] = fmaxf(s0[r], s1[r]);
#pragma unroll
      for (int r = 0; r < 8; ++r) tm[r] = fmaxf(tm[r], tm[r + 8]);
#pragma unroll
      for (int r = 0; r < 4; ++r) tm[r] = fmaxf(tm[r], tm[r + 4]);
      float pm = fmaxf(fmaxf(tm[0], tm[1]), fmaxf(tm[2], tm[3]));
      pm = fmaxf(pm, __shfl_xor(pm, 32));
      if (!__all(pm <= m_run[qt] + 64.f)) {  // defer-max (thr 8 post-scale)
        float mn = fmaxf(m_run[qt], pm);
        float corr = __expf((m_run[qt] - mn) * 0.125f);
        l_run[qt] *= corr;
#pragma unroll
        for (int dt = 0; dt < 2; ++dt)
#pragma unroll
          for (int r = 0; r < 16; ++r) of[qt][dt][r] *= corr;
        m_run[qt] = mn;
      }
      const float mqt = m_run[qt];
      float ls = 0.f;
#pragma unroll
      for (int kt = 0; kt < 2; ++kt) {
        const f32x16 sv = kt ? s1 : s0;
        float p[16];
#pragma unroll
        for (int r = 0; r < 16; ++r) p[r] = __expf((sv[r] - mqt) * 0.125f);
        float e0 = (p[0] + p[1]) + (p[2] + p[3]);
        float e1 = (p[4] + p[5]) + (p[6] + p[7]);
        float e2 = (p[8] + p[9]) + (p[10] + p[11]);
        float e3 = (p[12] + p[13]) + (p[14] + p[15]);
        ls += (e0 + e1) + (e2 + e3);
#pragma unroll
        for (int cc = 0; cc < 2; ++cc) {
          const int bx = cc * 8;
          unsigned a0 = cvtpk_bf16(p[bx + 0], p[bx + 1]);
          unsigned a1 = cvtpk_bf16(p[bx + 2], p[bx + 3]);
          unsigned b0 = cvtpk_bf16(p[bx + 4], p[bx + 5]);
          unsigned b1 = cvtpk_bf16(p[bx + 6], p[bx + 7]);
          // cross-half exchange: D_new={D.lo,S.lo}, S_new={D.hi,S.hi}
          asm("v_permlane32_swap_b32 %0, %1" : "+v"(a0), "+v"(b0));
          asm("v_permlane32_swap_b32 %0, %1" : "+v"(a1), "+v"(b1));
          uint4 fu;
          fu.x = a0;
          fu.y = a1;
          fu.z = b0;
          fu.w = b1;
          frag8 pb = __builtin_bit_cast(frag8, fu);
#pragma unroll
          for (int dt = 0; dt < 2; ++dt) {
            frag8 va = *(const frag8*)&VtB[cur * 4480 + (dt * 32 + l31) * 70 + kt * 32 + cc * 16 +
                                           l5 * 8];
            of[qt][dt] = MFMA32(va, pb, of[qt][dt]);
          }
        }
      }
      l_run[qt] += ls;
    }
    if (kb < 3) {
      *(short8*)&KbB[(cur ^ 1) * 4352 + prow * 68 + pc16] = pk0;
      *(short8*)&KbB[(cur ^ 1) * 4352 + prow * 68 + pc16 + 8] = pk1;
      u16* vd = &VtB[(cur ^ 1) * 4480 + prow];
#pragma unroll
      for (int e = 0; e < 8; ++e) {
        vd[(pc16 + e) * 70] = (u16)pv0[e];
        vd[(pc16 + 8 + e) * 70] = (u16)pv1[e];
      }
    }
    __syncthreads();
    cur ^= 1;
  }

  float inv[2];
#pragma unroll
  for (int qt = 0; qt < 2; ++qt) {
    float lt = l_run[qt] + __shfl_xor(l_run[qt], 32);
    inv[qt] = 1.0f / lt;
  }
  u16* sc = smem + wv * 4352;  // per-wave [64][68] scratch (reuses K/V LDS)
  __syncthreads();
#pragma unroll
  for (int qt = 0; qt < 2; ++qt)
#pragma unroll
    for (int dt = 0; dt < 2; ++dt)
#pragma unroll
      for (int j = 0; j < 4; ++j) {
        unsigned w0 = cvtpk_bf16(of[qt][dt][4 * j + 0] * inv[qt], of[qt][dt][4 * j + 1] * inv[qt]);
        unsigned w1 = cvtpk_bf16(of[qt][dt][4 * j + 2] * inv[qt], of[qt][dt][4 * j + 3] * inv[qt]);
        *(uint2*)&sc[(qt * 32 + l31) * 68 + dt * 32 + 8 * j + 4 * l5] = make_uint2(w0, w1);
      }
  asm volatile("" ::: "memory");
#pragma unroll
  for (int rep = 0; rep < 8; ++rep) {
    int row = rep * 8 + (lane >> 3);
    uint2 lo = *(const uint2*)&sc[row * 68 + (lane & 7) * 8];
    uint2 hi = *(const uint2*)&sc[row * 68 + (lane & 7) * 8 + 4];
    *(int4*)&aout[(size_t)(win * 256 + wv * 64 + row) * 512 + h * 64 + (lane & 7) * 8] =
        make_int4((int)lo.x, (int)lo.y, (int)hi.x, (int)hi.y);
  }
}

// ---------------------------------------------------------------- finalize
__global__ void k_final(const float* __restrict__ x, const u16* __restrict__ proj,
                        const int* __restrict__ kept, const float* __restrict__ mult,
                        float* __restrict__ out) {
  const size_t idx = (size_t)blockIdx.x * 256 + threadIdx.x;
  const int dci = (int)(idx & 31);
  const int pix = (int)((idx >> 5) & 16383);
  const int b = (int)(idx >> 19);
  const int y = pix >> 7, xc = pix & 127;
  float acc[16];
#pragma unroll
  for (int e = 0; e < 16; ++e) acc[e] = 0.f;
  float c = 0.f;
  const int wyh = y >> 3, wxh = xc >> 3;
#pragma unroll
  for (int a = 0; a < 2; ++a) {
    int wy = wyh - 1 + a;
    if (wy < 0 || wy > 14) continue;
#pragma unroll
    for (int bb = 0; bb < 2; ++bb) {
      int wx = wxh - 1 + bb;
      if (wx < 0 || wx > 14) continue;
      int w = wy * 15 + wx;
      int slot = kept[b * 225 + w];
      if (slot < 0) continue;
      float ml = mult[b * 225 + w];
      c += ml;
      const u16* pr = proj +
                      ((size_t)((b * 44 + slot) * 256 + (y - wy * 8) * 16 + (xc - wx * 8))) * 512 +
                      (size_t)dci * 16;
      short8 v0 = *(const short8*)pr;
      short8 v1 = *(const short8*)(pr + 8);
#pragma unroll
      for (int e = 0; e < 8; ++e) acc[e] += ml * bf2f((u16)v0[e]);
#pragma unroll
      for (int e = 0; e < 8; ++e) acc[8 + e] += ml * bf2f((u16)v1[e]);
    }
  }
  const float inv = 1.f / (c + 1e-10f);
  const size_t off = ((size_t)(b * 16384 + pix)) * 512 + (size_t)dci * 16;
  const float4* xp = (const float4*)(x + off);
  float4* op = (float4*)(out + off);
#pragma unroll
  for (int q4 = 0; q4 < 4; ++q4) {
    float4 xv = xp[q4];
    float4 ov;
    ov.x = xv.x + acc[q4 * 4 + 0] * inv;
    ov.y = xv.y + acc[q4 * 4 + 1] * inv;
    ov.z = xv.z + acc[q4 * 4 + 2] * inv;
    ov.w = xv.w + acc[q4 * 4 + 3] * inv;
    op[q4] = ov;
  }
}

// ---------------------------------------------------------------- launch
extern "C" void kernel_launch(void* const* d_in, const int* in_sizes, int n_in, void* d_out,
                              int out_size, void* d_ws, size_t ws_size, hipStream_t stream) {
  const float* x = (const float*)d_in[0];
  const float* prob = (const float*)d_in[1];
  const float* wfix = (const float*)d_in[2];
  const float* Wq = (const float*)d_in[3];
  const float* Wo = (const float*)d_in[4];
  const float* bo = (const float*)d_in[5];
  float* out = (float*)d_out;
  char* ws = (char*)d_ws;

  float* scores = (float*)(ws + 0);
  int* sel = (int*)(ws + 8192);
  int* kept = (int*)(ws + 16384);
  float* mult = (float*)(ws + 24576);
  u16* wqb = (u16*)(ws + 32768);
  u16* wob = (u16*)(ws + 32768 + 1572864);
  u16* xi = (u16*)(ws + 4194304);
  u16* qkv = (u16*)(ws + 4194304 + 92274688);
  u16* aout = xi;
  u16* proj = qkv;

  k_score<<<8, 256, 0, stream>>>(prob, wfix, scores);
  k_nms<<<8, 256, 0, stream>>>(scores, sel, kept, mult);
  k_castw<<<4096, 256, 0, stream>>>(Wq, Wo, wqb, wob);
  k_gather<<<22528, 256, 0, stream>>>(x, sel, xi);
  k_gemm256<0><<<2112, 512, 0, stream>>>(xi, wqb, qkv, nullptr, 90112, 1536, 512, 6);
  k_attn<<<2816, 256, 0, stream>>>(qkv, aout);
  k_gemm256<1><<<704, 512, 0, stream>>>(aout, wob, proj, bo, 90112, 512, 512, 2);
  k_final<<<16384, 256, 0, stream>>>(x, proj, kept, mult, out);
}

// Round 11
// 975.061 us; speedup vs baseline: 1.0753x; 1.0753x over previous
//
#include <hip/hip_runtime.h>
#include <type_traits>
#include <utility>

typedef unsigned short u16;
typedef __attribute__((ext_vector_type(8))) short short8;
typedef __attribute__((ext_vector_type(8))) __bf16 bf16v8;
typedef __attribute__((ext_vector_type(4))) float f32x4;
typedef __attribute__((ext_vector_type(16))) float f32x16;

template <typename T, typename = void> struct mfma_ok : std::false_type {};
template <typename T>
struct mfma_ok<T, std::void_t<decltype(__builtin_amdgcn_mfma_f32_16x16x32_bf16(
    std::declval<T>(), std::declval<T>(), std::declval<f32x4>(), 0, 0, 0))>>
    : std::true_type {};
using frag8 = std::conditional_t<mfma_ok<bf16v8>::value, bf16v8, short8>;

#define MFMA16(a, b, c) __builtin_amdgcn_mfma_f32_16x16x32_bf16((a), (b), (c), 0, 0, 0)
#define MFMA32(a, b, c) __builtin_amdgcn_mfma_f32_32x32x16_bf16((a), (b), (c), 0, 0, 0)

__device__ __forceinline__ float bf2f(u16 u) {
  unsigned v = ((unsigned)u) << 16;
  return __builtin_bit_cast(float, v);
}
__device__ __forceinline__ u16 f2bf(float f) {
  unsigned u = __builtin_bit_cast(unsigned, f);
  u = (u + 0x7fffu + ((u >> 16) & 1u)) >> 16;
  return (u16)u;
}
__device__ __forceinline__ unsigned cvtpk_bf16(float lo, float hi) {
  unsigned r;
  asm("v_cvt_pk_bf16_f32 %0, %1, %2" : "=v"(r) : "v"(lo), "v"(hi));
  return r;
}
// async global->LDS, 16B per lane; lds ptr must be wave-uniform base (+lane*16 implicit)
__device__ __forceinline__ void gl16(const u16* g, u16* l) {
  __builtin_amdgcn_global_load_lds((__attribute__((address_space(1))) void*)(g),
                                   (__attribute__((address_space(3))) void*)(l), 16, 0, 0);
}
__device__ __forceinline__ void vmw8() { asm volatile("s_waitcnt vmcnt(8)" ::: "memory"); }
__device__ __forceinline__ void vmw0() { asm volatile("s_waitcnt vmcnt(0)" ::: "memory"); }
__device__ __forceinline__ void lgw0() { asm volatile("s_waitcnt lgkmcnt(0)" ::: "memory"); }

// ---------------------------------------------------------------- score
__global__ void k_score(const float* __restrict__ prob, const float* __restrict__ wfix,
                        float* __restrict__ scores) {
  const int b = blockIdx.x, tid = threadIdx.x;
  __shared__ float ent[64 * 64];
  __shared__ float wf[64];
  if (tid < 64) wf[tid] = wfix[tid];
  const float* pb = prob + (size_t)b * 4 * 4096;
  for (int p = tid; p < 4096; p += 256) {
    float e = 0.f;
#pragma unroll
    for (int ch = 0; ch < 4; ++ch) {
      float v = pb[ch * 4096 + p];
      e -= v * log2f(v + 1e-10f);
    }
    ent[p] = e;
  }
  __syncthreads();
  if (tid < 225) {
    int wy = tid / 15, wx = tid % 15;
    float s = 0.f;
    for (int a = 0; a < 8; ++a)
      for (int c = 0; c < 8; ++c)
        s += ent[(wy * 4 + a) * 64 + wx * 4 + c] * wf[a * 8 + c];
    scores[b * 225 + tid] = s * (1.0f / 64.0f);
  }
}

// ---------------------------------------------------------------- nms
__device__ __forceinline__ float iou_pair(int wa, int wb) {
  float x1a = (float)((wa % 15) * 8), y1a = (float)((wa / 15) * 8);
  float x1b = (float)((wb % 15) * 8), y1b = (float)((wb / 15) * 8);
  float iw = fminf(x1a, x1b) + 15.f - fmaxf(x1a, x1b);
  float ih = fminf(y1a, y1b) + 15.f - fmaxf(y1a, y1b);
  iw = fmaxf(iw, 0.f);
  ih = fmaxf(ih, 0.f);
  float inter = iw * ih;
  return inter / (450.f - inter);
}

__global__ void k_nms(const float* __restrict__ scores, int* __restrict__ sel,
                      int* __restrict__ kept, float* __restrict__ mult) {
  const int b = blockIdx.x, t = threadIdx.x;
  __shared__ float s[225];
  __shared__ int order[225];
  __shared__ unsigned char supp[225];
  __shared__ int idx44[44];
  __shared__ int ks[225];
  __shared__ float ml[225];
  if (t < 225) s[t] = scores[b * 225 + t];
  __syncthreads();
  if (t < 225) {
    float st = s[t];
    int r = 0;
    for (int j = 0; j < 225; ++j) {
      float sj = s[j];
      r += (sj > st) || (sj == st && j < t);
    }
    order[r] = t;
    supp[t] = 0;
    ks[t] = -1;
    ml[t] = 0.f;
  }
  __syncthreads();
  for (int i = 0; i < 224; ++i) {
    if (t > i && t < 225 && !supp[i]) {
      if (iou_pair(order[i], order[t]) > 0.2f) supp[t] = 1;
    }
    __syncthreads();
  }
  if (t == 0) {
    int k = 0;
    for (int i = 0; i < 225 && k < 44; ++i)
      if (!supp[i]) idx44[k++] = order[i];
    while (k < 44) idx44[k++] = order[224];
    for (int k2 = 0; k2 < 44; ++k2) {
      int w = idx44[k2];
      if (ks[w] < 0) ks[w] = k2;
      ml[w] += 1.f;
    }
  }
  __syncthreads();
  if (t < 225) {
    kept[b * 225 + t] = ks[t];
    mult[b * 225 + t] = ml[t];
  }
  if (t < 44) sel[b * 44 + t] = idx44[t];
}

// ---------------------------------------------------------------- weight cast
__global__ void k_castw(const float* __restrict__ Wq, const float* __restrict__ Wo,
                        u16* __restrict__ wqb, u16* __restrict__ wob) {
  int idx = blockIdx.x * 256 + threadIdx.x;
  if (idx < 786432) wqb[idx] = f2bf(Wq[idx]);
  int i2 = idx - 786432;
  if (i2 >= 0 && i2 < 262144) wob[i2] = f2bf(Wo[i2]);
}

// ---------------------------------------------------------------- gather + bilinear (direct 4-tap)
__global__ __launch_bounds__(256) void k_gather(const float* __restrict__ x,
                                                const int* __restrict__ sel,
                                                u16* __restrict__ xi) {
  const size_t idx = (size_t)blockIdx.x * 256 + threadIdx.x;
  const int dc = (int)(idx & 63);
  const int pq = (int)((idx >> 6) & 255);
  const int g = (int)(idx >> 14);
  const int b = g / 44;
  const int w = sel[g];
  const int sy = (w / 15) * 8, sx = (w % 15) * 8;
  const int p = pq >> 4, q = pq & 15;
  float rp = ((float)p + 0.5f) * 0.9375f;
  int i0 = (int)rp;
  float fp = rp - (float)i0;
  float rq = ((float)q + 0.5f) * 0.9375f;
  int j0 = (int)rq;
  float fq = rq - (float)j0;
  const float w00 = (1.f - fp) * (1.f - fq), w01 = (1.f - fp) * fq;
  const float w10 = fp * (1.f - fq), w11 = fp * fq;
  const float* xb = x + ((size_t)b * 16384 + (size_t)(sy + i0) * 128 + sx + j0) * 512 + dc * 8;
  const float4* t00 = (const float4*)xb;
  const float4* t01 = (const float4*)(xb + 512);
  const float4* t10 = (const float4*)(xb + 512 * 128);
  const float4* t11 = (const float4*)(xb + 512 * 129);
  float acc[8];
#pragma unroll
  for (int h = 0; h < 2; ++h) {
    float4 a = t00[h], bb = t01[h], c = t10[h], d = t11[h];
    acc[h * 4 + 0] = w00 * a.x + w01 * bb.x + w10 * c.x + w11 * d.x;
    acc[h * 4 + 1] = w00 * a.y + w01 * bb.y + w10 * c.y + w11 * d.y;
    acc[h * 4 + 2] = w00 * a.z + w01 * bb.z + w10 * c.z + w11 * d.z;
    acc[h * 4 + 3] = w00 * a.w + w01 * bb.w + w10 * c.w + w11 * d.w;
  }
  short8 o;
#pragma unroll
  for (int e = 0; e < 8; ++e) o[e] = (short)f2bf(acc[e]);
  *(short8*)&xi[((size_t)g * 256 + pq) * 512 + dc * 8] = o;
}

// ---------------------------------------------------------------- GEMM 256x256, BK=64, 8 waves
// Counted-vmcnt dbuf + T2 XOR swizzle + per-mh fragment hoist; compiler-scheduled lgkm inside
// the tile, explicit drain only before the buffer-release barrier.
template <int BIAS>
__global__ __launch_bounds__(512, 2) void k_gemm256(const u16* __restrict__ A,
                                                    const u16* __restrict__ B, u16* __restrict__ C,
                                                    const float* __restrict__ bias, int M, int N,
                                                    int K, int nbn) {
  __shared__ u16 sA[2][256 * 64];
  __shared__ u16 sB[2][256 * 64];
  const int tid = threadIdx.x, lane = tid & 63, wv = tid >> 6;
  const int f = blockIdx.x;
  const int q8 = gridDim.x >> 3;
  const int wg = (f & 7) * q8 + (f >> 3);
  const int bm = wg / nbn, bn = wg % nbn;
  const int wm = (wv >> 2) * 128, wn = (wv & 3) * 64;
  const int l15 = lane & 15, k8 = (lane >> 4) * 8;
  const int xorv = (l15 & 7) * 8;  // read-side swizzle (elements)
  const int srow = tid >> 3;
  const int sc8 = ((tid ^ (tid >> 3)) & 7) * 8;  // pre-swizzled source col
  const u16* Ab = A + (size_t)(bm * 256 + srow) * K + sc8;
  const u16* Bb = B + (size_t)(bn * 256 + srow) * K + sc8;

  f32x4 acc[8][4] = {};

#define STAGE(kt, buf)                                                       \
  {                                                                          \
    const int ko = (kt) * 64;                                                \
    _Pragma("unroll") for (int c = 0; c < 4; ++c) {                          \
      gl16(Ab + (size_t)(c * 64) * K + ko, &sA[buf][c * 4096 + wv * 512]);   \
      gl16(Bb + (size_t)(c * 64) * K + ko, &sB[buf][c * 4096 + wv * 512]);   \
    }                                                                        \
  }

  STAGE(0, 0);
  STAGE(1, 1);

  for (int t = 0; t < 8; ++t) {
    const int buf = t & 1;
    if (t == 7)
      vmw0();
    else
      vmw8();  // counted: next tile's 8 loads stay in flight
    __builtin_amdgcn_sched_barrier(0);
    __builtin_amdgcn_s_barrier();  // tile t resident for all waves
#pragma unroll
    for (int mh = 0; mh < 2; ++mh) {
      frag8 af[4][2], bf[2][2][2];
#pragma unroll
      for (int i = 0; i < 4; ++i)
#pragma unroll
        for (int kk = 0; kk < 2; ++kk)
          af[i][kk] = *(const frag8*)&sA[buf][(wm + (mh * 4 + i) * 16 + l15) * 64 +
                                             ((kk * 32 + k8) ^ xorv)];
#pragma unroll
      for (int nh = 0; nh < 2; ++nh)
#pragma unroll
        for (int j = 0; j < 2; ++j)
#pragma unroll
          for (int kk = 0; kk < 2; ++kk)
            bf[nh][j][kk] = *(const frag8*)&sB[buf][(wn + (nh * 2 + j) * 16 + l15) * 64 +
                                                    ((kk * 32 + k8) ^ xorv)];
      __builtin_amdgcn_s_setprio(1);
#pragma unroll
      for (int nh = 0; nh < 2; ++nh)
#pragma unroll
        for (int i = 0; i < 4; ++i)
#pragma unroll
          for (int j = 0; j < 2; ++j)
#pragma unroll
            for (int kk = 0; kk < 2; ++kk)
              acc[mh * 4 + i][nh * 2 + j] =
                  MFMA16(af[i][kk], bf[nh][j][kk], acc[mh * 4 + i][nh * 2 + j]);
      __builtin_amdgcn_s_setprio(0);
    }
    lgw0();  // this wave's ds_reads fully retired before buf can be overwritten
    __builtin_amdgcn_sched_barrier(0);
    __builtin_amdgcn_s_barrier();  // all waves done reading buf
    if (t < 6) STAGE(t + 2, buf);  // issued here: flies under next tile's compute
  }
#undef STAGE

  const int cc = lane & 15, rr = (lane >> 4) * 4;
#pragma unroll
  for (int i = 0; i < 8; ++i)
#pragma unroll
    for (int j = 0; j < 4; ++j) {
      int col = bn * 256 + wn + j * 16 + cc;
      float badd = BIAS ? bias[col] : 0.f;
#pragma unroll
      for (int e = 0; e < 4; ++e) {
        int row = bm * 256 + wm + i * 16 + rr + e;
        C[(size_t)row * N + col] = f2bf(acc[i][j][e] + badd);
      }
    }
}

// ---------------------------------------------------------------- attention (swapped 32x32)
// One block per (win, head); 4 waves x 64 q-rows. K AND V double-buffered per 64-key block.
// Head-grouped index (win = g%352): the 8 heads of one window read the SAME qkv rows, and
// 352%8==0 puts them on the same XCD under round-robin dispatch -> L2-shared K/V/Q rows.
// launch_bounds (256,4): VGPR ~84 fits the 128-reg 4-wave budget; LDS 35.3KB x4 = 141KB.
__global__ __launch_bounds__(256, 4) void k_attn(const u16* __restrict__ qkv,
                                                 u16* __restrict__ aout) {
  const int g = blockIdx.x;
  const int win = g % 352, h = g / 352;
  const int tid = threadIdx.x, lane = tid & 63, wv = tid >> 6;
  const int l31 = lane & 31, l5 = lane >> 5;
  __shared__ u16 smem[17664];  // Kb[2][64][68] (8704 u16) | Vt[2][64][70] (8960 u16)
  u16* KbB = smem;
  u16* VtB = smem + 8704;
  const u16* base = qkv + (size_t)win * 256 * 1536;
  const u16* kbase = base + 512 + h * 64;
  const u16* vbase = base + 1024 + h * 64;
  const int prow = tid >> 2, pc16 = (tid & 3) * 16;

  // Q B-frags first (longest-latency dependency)
  frag8 qf[2][4];
#pragma unroll
  for (int qt = 0; qt < 2; ++qt)
#pragma unroll
    for (int c = 0; c < 4; ++c)
      qf[qt][c] = *(const frag8*)(base + (size_t)(wv * 64 + qt * 32 + l31) * 1536 + h * 64 +
                                  c * 16 + l5 * 8);
  // K block 0 + V block 0 (thread: key=prow, d-range pc16..pc16+15)
  {
    const u16* kp = kbase + (size_t)prow * 1536 + pc16;
    short8 ka = *(const short8*)kp;
    short8 kb2 = *(const short8*)(kp + 8);
    const u16* vp = vbase + (size_t)prow * 1536 + pc16;
    short8 va = *(const short8*)vp;
    short8 vb2 = *(const short8*)(vp + 8);
    *(short8*)&KbB[prow * 68 + pc16] = ka;
    *(short8*)&KbB[prow * 68 + pc16 + 8] = kb2;
#pragma unroll
    for (int e = 0; e < 8; ++e) {
      VtB[(pc16 + e) * 70 + prow] = (u16)va[e];
      VtB[(pc16 + 8 + e) * 70 + prow] = (u16)vb2[e];
    }
  }
  __syncthreads();

  f32x16 of[2][2] = {};
  float m_run[2] = {-3e38f, -3e38f};
  float l_run[2] = {0.f, 0.f};

  int cur = 0;
  for (int kb = 0; kb < 4; ++kb) {
    short8 pk0 = {}, pk1 = {}, pv0 = {}, pv1 = {};
    if (kb < 3) {
      const u16* kp = kbase + (size_t)((kb + 1) * 64 + prow) * 1536 + pc16;
      pk0 = *(const short8*)kp;
      pk1 = *(const short8*)(kp + 8);
      const u16* vp = vbase + (size_t)((kb + 1) * 64 + prow) * 1536 + pc16;
      pv0 = *(const short8*)vp;
      pv1 = *(const short8*)(vp + 8);
    }
#pragma unroll
    for (int qt = 0; qt < 2; ++qt) {
      f32x16 s0 = {}, s1 = {};
#pragma unroll
      for (int c = 0; c < 4; ++c) {
        frag8 kf0 = *(const frag8*)&KbB[cur * 4352 + l31 * 68 + c * 16 + l5 * 8];
        frag8 kf1 = *(const frag8*)&KbB[cur * 4352 + (32 + l31) * 68 + c * 16 + l5 * 8];
        s0 = MFMA32(kf0, qf[qt][c], s0);
        s1 = MFMA32(kf1, qf[qt][c], s1);
      }
      float tm[16];
#pragma unroll
      for (int r = 0; r < 16; ++r) tm[r] = fmaxf(s0[r], s1[r]);
#pragma unroll
      for (int r = 0; r < 8; ++r) tm[r] = fmaxf(tm[r], tm[r + 8]);
#pragma unroll
      for (int r = 0; r < 4; ++r) tm[r] = fmaxf(tm[r], tm[r + 4]);
      float pm = fmaxf(fmaxf(tm[0], tm[1]), fmaxf(tm[2], tm[3]));
      pm = fmaxf(pm, __shfl_xor(pm, 32));
      if (!__all(pm <= m_run[qt] + 64.f)) {  // defer-max (thr 8 post-scale)
        float mn = fmaxf(m_run[qt], pm);
        float corr = __expf((m_run[qt] - mn) * 0.125f);
        l_run[qt] *= corr;
#pragma unroll
        for (int dt = 0; dt < 2; ++dt)
#pragma unroll
          for (int r = 0; r < 16; ++r) of[qt][dt][r] *= corr;
        m_run[qt] = mn;
      }
      const float mqt = m_run[qt];
      float ls = 0.f;
#pragma unroll
      for (int kt = 0; kt < 2; ++kt) {
        const f32x16 sv = kt ? s1 : s0;
        float p[16];
#pragma unroll
        for (int r = 0; r < 16; ++r) p[r] = __expf((sv[r] - mqt) * 0.125f);
        float e0 = (p[0] + p[1]) + (p[2] + p[3]);
        float e1 = (p[4] + p[5]) + (p[6] + p[7]);
        float e2 = (p[8] + p[9]) + (p[10] + p[11]);
        float e3 = (p[12] + p[13]) + (p[14] + p[15]);
        ls += (e0 + e1) + (e2 + e3);
#pragma unroll
        for (int cc = 0; cc < 2; ++cc) {
          const int bx = cc * 8;
          unsigned a0 = cvtpk_bf16(p[bx + 0], p[bx + 1]);
          unsigned a1 = cvtpk_bf16(p[bx + 2], p[bx + 3]);
          unsigned b0 = cvtpk_bf16(p[bx + 4], p[bx + 5]);
          unsigned b1 = cvtpk_bf16(p[bx + 6], p[bx + 7]);
          // cross-half exchange: D_new={D.lo,S.lo}, S_new={D.hi,S.hi}
          asm("v_permlane32_swap_b32 %0, %1" : "+v"(a0), "+v"(b0));
          asm("v_permlane32_swap_b32 %0, %1" : "+v"(a1), "+v"(b1));
          uint4 fu;
          fu.x = a0;
          fu.y = a1;
          fu.z = b0;
          fu.w = b1;
          frag8 pb = __builtin_bit_cast(frag8, fu);
#pragma unroll
          for (int dt = 0; dt < 2; ++dt) {
            frag8 va = *(const frag8*)&VtB[cur * 4480 + (dt * 32 + l31) * 70 + kt * 32 + cc * 16 +
                                           l5 * 8];
            of[qt][dt] = MFMA32(va, pb, of[qt][dt]);
          }
        }
      }
      l_run[qt] += ls;
    }
    if (kb < 3) {
      *(short8*)&KbB[(cur ^ 1) * 4352 + prow * 68 + pc16] = pk0;
      *(short8*)&KbB[(cur ^ 1) * 4352 + prow * 68 + pc16 + 8] = pk1;
      u16* vd = &VtB[(cur ^ 1) * 4480 + prow];
#pragma unroll
      for (int e = 0; e < 8; ++e) {
        vd[(pc16 + e) * 70] = (u16)pv0[e];
        vd[(pc16 + 8 + e) * 70] = (u16)pv1[e];
      }
    }
    __syncthreads();
    cur ^= 1;
  }

  float inv[2];
#pragma unroll
  for (int qt = 0; qt < 2; ++qt) {
    float lt = l_run[qt] + __shfl_xor(l_run[qt], 32);
    inv[qt] = 1.0f / lt;
  }
  u16* sc = smem + wv * 4352;  // per-wave [64][68] scratch (reuses K/V LDS)
  __syncthreads();
#pragma unroll
  for (int qt = 0; qt < 2; ++qt)
#pragma unroll
    for (int dt = 0; dt < 2; ++dt)
#pragma unroll
      for (int j = 0; j < 4; ++j) {
        unsigned w0 = cvtpk_bf16(of[qt][dt][4 * j + 0] * inv[qt], of[qt][dt][4 * j + 1] * inv[qt]);
        unsigned w1 = cvtpk_bf16(of[qt][dt][4 * j + 2] * inv[qt], of[qt][dt][4 * j + 3] * inv[qt]);
        *(uint2*)&sc[(qt * 32 + l31) * 68 + dt * 32 + 8 * j + 4 * l5] = make_uint2(w0, w1);
      }
  asm volatile("" ::: "memory");
#pragma unroll
  for (int rep = 0; rep < 8; ++rep) {
    int row = rep * 8 + (lane >> 3);
    uint2 lo = *(const uint2*)&sc[row * 68 + (lane & 7) * 8];
    uint2 hi = *(const uint2*)&sc[row * 68 + (lane & 7) * 8 + 4];
    *(int4*)&aout[(size_t)(win * 256 + wv * 64 + row) * 512 + h * 64 + (lane & 7) * 8] =
        make_int4((int)lo.x, (int)lo.y, (int)hi.x, (int)hi.y);
  }
}

// ---------------------------------------------------------------- finalize
__global__ void k_final(const float* __restrict__ x, const u16* __restrict__ proj,
                        const int* __restrict__ kept, const float* __restrict__ mult,
                        float* __restrict__ out) {
  const size_t idx = (size_t)blockIdx.x * 256 + threadIdx.x;
  const int dci = (int)(idx & 31);
  const int pix = (int)((idx >> 5) & 16383);
  const int b = (int)(idx >> 19);
  const int y = pix >> 7, xc = pix & 127;
  float acc[16];
#pragma unroll
  for (int e = 0; e < 16; ++e) acc[e] = 0.f;
  float c = 0.f;
  const int wyh = y >> 3, wxh = xc >> 3;
#pragma unroll
  for (int a = 0; a < 2; ++a) {
    int wy = wyh - 1 + a;
    if (wy < 0 || wy > 14) continue;
#pragma unroll
    for (int bb = 0; bb < 2; ++bb) {
      int wx = wxh - 1 + bb;
      if (wx < 0 || wx > 14) continue;
      int w = wy * 15 + wx;
      int slot = kept[b * 225 + w];
      if (slot < 0) continue;
      float ml = mult[b * 225 + w];
      c += ml;
      const u16* pr = proj +
                      ((size_t)((b * 44 + slot) * 256 + (y - wy * 8) * 16 + (xc - wx * 8))) * 512 +
                      (size_t)dci * 16;
      short8 v0 = *(const short8*)pr;
      short8 v1 = *(const short8*)(pr + 8);
#pragma unroll
      for (int e = 0; e < 8; ++e) acc[e] += ml * bf2f((u16)v0[e]);
#pragma unroll
      for (int e = 0; e < 8; ++e) acc[8 + e] += ml * bf2f((u16)v1[e]);
    }
  }
  const float inv = 1.f / (c + 1e-10f);
  const size_t off = ((size_t)(b * 16384 + pix)) * 512 + (size_t)dci * 16;
  const float4* xp = (const float4*)(x + off);
  float4* op = (float4*)(out + off);
#pragma unroll
  for (int q4 = 0; q4 < 4; ++q4) {
    float4 xv = xp[q4];
    float4 ov;
    ov.x = xv.x + acc[q4 * 4 + 0] * inv;
    ov.y = xv.y + acc[q4 * 4 + 1] * inv;
    ov.z = xv.z + acc[q4 * 4 + 2] * inv;
    ov.w = xv.w + acc[q4 * 4 + 3] * inv;
    op[q4] = ov;
  }
}

// ---------------------------------------------------------------- launch
extern "C" void kernel_launch(void* const* d_in, const int* in_sizes, int n_in, void* d_out,
                              int out_size, void* d_ws, size_t ws_size, hipStream_t stream) {
  const float* x = (const float*)d_in[0];
  const float* prob = (const float*)d_in[1];
  const float* wfix = (const float*)d_in[2];
  const float* Wq = (const float*)d_in[3];
  const float* Wo = (const float*)d_in[4];
  const float* bo = (const float*)d_in[5];
  float* out = (float*)d_out;
  char* ws = (char*)d_ws;

  float* scores = (float*)(ws + 0);
  int* sel = (int*)(ws + 8192);
  int* kept = (int*)(ws + 16384);
  float* mult = (float*)(ws + 24576);
  u16* wqb = (u16*)(ws + 32768);
  u16* wob = (u16*)(ws + 32768 + 1572864);
  u16* xi = (u16*)(ws + 4194304);
  u16* qkv = (u16*)(ws + 4194304 + 92274688);
  u16* aout = xi;
  u16* proj = qkv;

  k_score<<<8, 256, 0, stream>>>(prob, wfix, scores);
  k_nms<<<8, 256, 0, stream>>>(scores, sel, kept, mult);
  k_castw<<<4096, 256, 0, stream>>>(Wq, Wo, wqb, wob);
  k_gather<<<22528, 256, 0, stream>>>(x, sel, xi);
  k_gemm256<0><<<2112, 512, 0, stream>>>(xi, wqb, qkv, nullptr, 90112, 1536, 512, 6);
  k_attn<<<2816, 256, 0, stream>>>(qkv, aout);
  k_gemm256<1><<<704, 512, 0, stream>>>(aout, wob, proj, bo, 90112, 512, 512, 2);
  k_final<<<16384, 256, 0, stream>>>(x, proj, kept, mult, out);
}

// Round 12
// 749.998 us; speedup vs baseline: 1.3980x; 1.3001x over previous
//
#include <hip/hip_runtime.h>
#include <type_traits>
#include <utility>

typedef unsigned short u16;
typedef __attribute__((ext_vector_type(8))) short short8;
typedef __attribute__((ext_vector_type(8))) __bf16 bf16v8;
typedef __attribute__((ext_vector_type(4))) float f32x4;
typedef __attribute__((ext_vector_type(16))) float f32x16;

template <typename T, typename = void> struct mfma_ok : std::false_type {};
template <typename T>
struct mfma_ok<T, std::void_t<decltype(__builtin_amdgcn_mfma_f32_16x16x32_bf16(
    std::declval<T>(), std::declval<T>(), std::declval<f32x4>(), 0, 0, 0))>>
    : std::true_type {};
using frag8 = std::conditional_t<mfma_ok<bf16v8>::value, bf16v8, short8>;

#define MFMA16(a, b, c) __builtin_amdgcn_mfma_f32_16x16x32_bf16((a), (b), (c), 0, 0, 0)
#define MFMA32(a, b, c) __builtin_amdgcn_mfma_f32_32x32x16_bf16((a), (b), (c), 0, 0, 0)

__device__ __forceinline__ float bf2f(u16 u) {
  unsigned v = ((unsigned)u) << 16;
  return __builtin_bit_cast(float, v);
}
__device__ __forceinline__ u16 f2bf(float f) {
  unsigned u = __builtin_bit_cast(unsigned, f);
  u = (u + 0x7fffu + ((u >> 16) & 1u)) >> 16;
  return (u16)u;
}
__device__ __forceinline__ unsigned cvtpk_bf16(float lo, float hi) {
  unsigned r;
  asm("v_cvt_pk_bf16_f32 %0, %1, %2" : "=v"(r) : "v"(lo), "v"(hi));
  return r;
}
// async global->LDS, 16B per lane; lds ptr must be wave-uniform base (+lane*16 implicit)
__device__ __forceinline__ void gl16(const u16* g, u16* l) {
  __builtin_amdgcn_global_load_lds((__attribute__((address_space(1))) void*)(g),
                                   (__attribute__((address_space(3))) void*)(l), 16, 0, 0);
}
__device__ __forceinline__ void vmw8() { asm volatile("s_waitcnt vmcnt(8)" ::: "memory"); }
__device__ __forceinline__ void vmw0() { asm volatile("s_waitcnt vmcnt(0)" ::: "memory"); }
__device__ __forceinline__ void lgw0() { asm volatile("s_waitcnt lgkmcnt(0)" ::: "memory"); }

// ---------------------------------------------------------------- score
__global__ void k_score(const float* __restrict__ prob, const float* __restrict__ wfix,
                        float* __restrict__ scores) {
  const int b = blockIdx.x, tid = threadIdx.x;
  __shared__ float ent[64 * 64];
  __shared__ float wf[64];
  if (tid < 64) wf[tid] = wfix[tid];
  const float* pb = prob + (size_t)b * 4 * 4096;
  for (int p = tid; p < 4096; p += 256) {
    float e = 0.f;
#pragma unroll
    for (int ch = 0; ch < 4; ++ch) {
      float v = pb[ch * 4096 + p];
      e -= v * log2f(v + 1e-10f);
    }
    ent[p] = e;
  }
  __syncthreads();
  if (tid < 225) {
    int wy = tid / 15, wx = tid % 15;
    float s = 0.f;
    for (int a = 0; a < 8; ++a)
      for (int c = 0; c < 8; ++c)
        s += ent[(wy * 4 + a) * 64 + wx * 4 + c] * wf[a * 8 + c];
    scores[b * 225 + tid] = s * (1.0f / 64.0f);
  }
}

// ---------------------------------------------------------------- nms
__device__ __forceinline__ float iou_pair(int wa, int wb) {
  float x1a = (float)((wa % 15) * 8), y1a = (float)((wa / 15) * 8);
  float x1b = (float)((wb % 15) * 8), y1b = (float)((wb / 15) * 8);
  float iw = fminf(x1a, x1b) + 15.f - fmaxf(x1a, x1b);
  float ih = fminf(y1a, y1b) + 15.f - fmaxf(y1a, y1b);
  iw = fmaxf(iw, 0.f);
  ih = fmaxf(ih, 0.f);
  float inter = iw * ih;
  return inter / (450.f - inter);
}

__global__ void k_nms(const float* __restrict__ scores, int* __restrict__ sel,
                      int* __restrict__ kept, float* __restrict__ mult) {
  const int b = blockIdx.x, t = threadIdx.x;
  __shared__ float s[225];
  __shared__ int order[225];
  __shared__ unsigned char supp[225];
  __shared__ int idx44[44];
  __shared__ int ks[225];
  __shared__ float ml[225];
  if (t < 225) s[t] = scores[b * 225 + t];
  __syncthreads();
  if (t < 225) {
    float st = s[t];
    int r = 0;
    for (int j = 0; j < 225; ++j) {
      float sj = s[j];
      r += (sj > st) || (sj == st && j < t);
    }
    order[r] = t;
    supp[t] = 0;
    ks[t] = -1;
    ml[t] = 0.f;
  }
  __syncthreads();
  for (int i = 0; i < 224; ++i) {
    if (t > i && t < 225 && !supp[i]) {
      if (iou_pair(order[i], order[t]) > 0.2f) supp[t] = 1;
    }
    __syncthreads();
  }
  if (t == 0) {
    int k = 0;
    for (int i = 0; i < 225 && k < 44; ++i)
      if (!supp[i]) idx44[k++] = order[i];
    while (k < 44) idx44[k++] = order[224];
    for (int k2 = 0; k2 < 44; ++k2) {
      int w = idx44[k2];
      if (ks[w] < 0) ks[w] = k2;
      ml[w] += 1.f;
    }
  }
  __syncthreads();
  if (t < 225) {
    kept[b * 225 + t] = ks[t];
    mult[b * 225 + t] = ml[t];
  }
  if (t < 44) sel[b * 44 + t] = idx44[t];
}

// ---------------------------------------------------------------- weight cast
__global__ void k_castw(const float* __restrict__ Wq, const float* __restrict__ Wo,
                        u16* __restrict__ wqb, u16* __restrict__ wob) {
  int idx = blockIdx.x * 256 + threadIdx.x;
  if (idx < 786432) wqb[idx] = f2bf(Wq[idx]);
  int i2 = idx - 786432;
  if (i2 >= 0 && i2 < 262144) wob[i2] = f2bf(Wo[i2]);
}

// ---------------------------------------------------------------- gather + bilinear (direct 4-tap)
__global__ __launch_bounds__(256) void k_gather(const float* __restrict__ x,
                                                const int* __restrict__ sel,
                                                u16* __restrict__ xi) {
  const size_t idx = (size_t)blockIdx.x * 256 + threadIdx.x;
  const int dc = (int)(idx & 63);
  const int pq = (int)((idx >> 6) & 255);
  const int g = (int)(idx >> 14);
  const int b = g / 44;
  const int w = sel[g];
  const int sy = (w / 15) * 8, sx = (w % 15) * 8;
  const int p = pq >> 4, q = pq & 15;
  float rp = ((float)p + 0.5f) * 0.9375f;
  int i0 = (int)rp;
  float fp = rp - (float)i0;
  float rq = ((float)q + 0.5f) * 0.9375f;
  int j0 = (int)rq;
  float fq = rq - (float)j0;
  const float w00 = (1.f - fp) * (1.f - fq), w01 = (1.f - fp) * fq;
  const float w10 = fp * (1.f - fq), w11 = fp * fq;
  const float* xb = x + ((size_t)b * 16384 + (size_t)(sy + i0) * 128 + sx + j0) * 512 + dc * 8;
  const float4* t00 = (const float4*)xb;
  const float4* t01 = (const float4*)(xb + 512);
  const float4* t10 = (const float4*)(xb + 512 * 128);
  const float4* t11 = (const float4*)(xb + 512 * 129);
  float acc[8];
#pragma unroll
  for (int h = 0; h < 2; ++h) {
    float4 a = t00[h], bb = t01[h], c = t10[h], d = t11[h];
    acc[h * 4 + 0] = w00 * a.x + w01 * bb.x + w10 * c.x + w11 * d.x;
    acc[h * 4 + 1] = w00 * a.y + w01 * bb.y + w10 * c.y + w11 * d.y;
    acc[h * 4 + 2] = w00 * a.z + w01 * bb.z + w10 * c.z + w11 * d.z;
    acc[h * 4 + 3] = w00 * a.w + w01 * bb.w + w10 * c.w + w11 * d.w;
  }
  short8 o;
#pragma unroll
  for (int e = 0; e < 8; ++e) o[e] = (short)f2bf(acc[e]);
  *(short8*)&xi[((size_t)g * 256 + pq) * 512 + dc * 8] = o;
}

// ---------------------------------------------------------------- GEMM 128x128, BK=64, 4 waves
// Counted-vmcnt dbuf + T2 XOR swizzle. LDS 64KB -> 2 blocks/CU: barrier/vmcnt stalls of one
// block hide under the other block's compute (m114 wave-level overlap). acc = 64 AGPR/wave +
// ~90 arch VGPR fits the 2-waves/SIMD budget (256) with huge margin -> no spill.
template <int BIAS>
__global__ __launch_bounds__(256, 2) void k_gemm128(const u16* __restrict__ A,
                                                    const u16* __restrict__ B, u16* __restrict__ C,
                                                    const float* __restrict__ bias, int M, int N,
                                                    int K, int nbn) {
  __shared__ u16 sA[2][128 * 64];
  __shared__ u16 sB[2][128 * 64];
  const int tid = threadIdx.x, lane = tid & 63, wv = tid >> 6;
  const int f = blockIdx.x;
  const int q8 = gridDim.x >> 3;
  const int wg = (f & 7) * q8 + (f >> 3);  // bijective XCD swizzle (nwg % 8 == 0)
  const int bm = wg / nbn, bn = wg % nbn;
  const int wm = (wv >> 1) * 64, wn = (wv & 1) * 64;
  const int l15 = lane & 15, k8 = (lane >> 4) * 8;
  const int xorv = (l15 & 7) * 8;  // read-side swizzle (elements)
  const int srow = tid >> 3;                     // 0..31 (rows within 32-row chunk)
  const int sc8 = ((tid ^ (tid >> 3)) & 7) * 8;  // pre-swizzled source col
  const u16* Ab = A + (size_t)(bm * 128 + srow) * K + sc8;
  const u16* Bb = B + (size_t)(bn * 128 + srow) * K + sc8;

  f32x4 acc[4][4] = {};

  // STAGE tile kt into buf: 8 gl16 per thread-set (4 chunks x A,B), 32 rows per chunk
#define STAGE(kt, buf)                                                      \
  {                                                                         \
    const int ko = (kt) * 64;                                               \
    _Pragma("unroll") for (int c = 0; c < 4; ++c) {                         \
      gl16(Ab + (size_t)(c * 32) * K + ko, &sA[buf][c * 2048 + wv * 512]);  \
      gl16(Bb + (size_t)(c * 32) * K + ko, &sB[buf][c * 2048 + wv * 512]);  \
    }                                                                       \
  }

  STAGE(0, 0);
  STAGE(1, 1);

  for (int t = 0; t < 8; ++t) {
    const int buf = t & 1;
    if (t == 7)
      vmw0();
    else
      vmw8();  // counted: next tile's 8 loads stay in flight
    __builtin_amdgcn_sched_barrier(0);
    __builtin_amdgcn_s_barrier();  // tile t resident for all waves
    frag8 af[4][2], bf[4][2];
#pragma unroll
    for (int i = 0; i < 4; ++i)
#pragma unroll
      for (int kk = 0; kk < 2; ++kk) {
        af[i][kk] = *(const frag8*)&sA[buf][(wm + i * 16 + l15) * 64 + ((kk * 32 + k8) ^ xorv)];
        bf[i][kk] = *(const frag8*)&sB[buf][(wn + i * 16 + l15) * 64 + ((kk * 32 + k8) ^ xorv)];
      }
    __builtin_amdgcn_s_setprio(1);
#pragma unroll
    for (int i = 0; i < 4; ++i)
#pragma unroll
      for (int j = 0; j < 4; ++j)
#pragma unroll
        for (int kk = 0; kk < 2; ++kk)
          acc[i][j] = MFMA16(af[i][kk], bf[j][kk], acc[i][j]);
    __builtin_amdgcn_s_setprio(0);
    lgw0();  // this wave's ds_reads fully retired before buf can be overwritten
    __builtin_amdgcn_sched_barrier(0);
    __builtin_amdgcn_s_barrier();  // all waves done reading buf
    if (t < 6) STAGE(t + 2, buf);  // issued here: flies under next tile's compute
  }
#undef STAGE

  const int cc = lane & 15, rr = (lane >> 4) * 4;
#pragma unroll
  for (int i = 0; i < 4; ++i)
#pragma unroll
    for (int j = 0; j < 4; ++j) {
      int col = bn * 128 + wn + j * 16 + cc;
      float badd = BIAS ? bias[col] : 0.f;
#pragma unroll
      for (int e = 0; e < 4; ++e) {
        int row = bm * 128 + wm + i * 16 + rr + e;
        C[(size_t)row * N + col] = f2bf(acc[i][j][e] + badd);
      }
    }
}

// ---------------------------------------------------------------- attention (swapped 32x32)
// One block per (win, head); 4 waves x 64 q-rows. K AND V double-buffered per 64-key block.
// Head-grouped index (win = g%352, 352%8==0): the 8 heads of one window share an XCD's L2.
// launch_bounds (256,3): budget ~170 regs/wave >= 84 arch + 64 AGPR (unified file) -> no spill.
__global__ __launch_bounds__(256, 3) void k_attn(const u16* __restrict__ qkv,
                                                 u16* __restrict__ aout) {
  const int g = blockIdx.x;
  const int win = g % 352, h = g / 352;
  const int tid = threadIdx.x, lane = tid & 63, wv = tid >> 6;
  const int l31 = lane & 31, l5 = lane >> 5;
  __shared__ u16 smem[17664];  // Kb[2][64][68] (8704 u16) | Vt[2][64][70] (8960 u16)
  u16* KbB = smem;
  u16* VtB = smem + 8704;
  const u16* base = qkv + (size_t)win * 256 * 1536;
  const u16* kbase = base + 512 + h * 64;
  const u16* vbase = base + 1024 + h * 64;
  const int prow = tid >> 2, pc16 = (tid & 3) * 16;

  // Q B-frags first (longest-latency dependency)
  frag8 qf[2][4];
#pragma unroll
  for (int qt = 0; qt < 2; ++qt)
#pragma unroll
    for (int c = 0; c < 4; ++c)
      qf[qt][c] = *(const frag8*)(base + (size_t)(wv * 64 + qt * 32 + l31) * 1536 + h * 64 +
                                  c * 16 + l5 * 8);
  // K block 0 + V block 0 (thread: key=prow, d-range pc16..pc16+15)
  {
    const u16* kp = kbase + (size_t)prow * 1536 + pc16;
    short8 ka = *(const short8*)kp;
    short8 kb2 = *(const short8*)(kp + 8);
    const u16* vp = vbase + (size_t)prow * 1536 + pc16;
    short8 va = *(const short8*)vp;
    short8 vb2 = *(const short8*)(vp + 8);
    *(short8*)&KbB[prow * 68 + pc16] = ka;
    *(short8*)&KbB[prow * 68 + pc16 + 8] = kb2;
#pragma unroll
    for (int e = 0; e < 8; ++e) {
      VtB[(pc16 + e) * 70 + prow] = (u16)va[e];
      VtB[(pc16 + 8 + e) * 70 + prow] = (u16)vb2[e];
    }
  }
  __syncthreads();

  f32x16 of[2][2] = {};
  float m_run[2] = {-3e38f, -3e38f};
  float l_run[2] = {0.f, 0.f};

  int cur = 0;
  for (int kb = 0; kb < 4; ++kb) {
    short8 pk0 = {}, pk1 = {}, pv0 = {}, pv1 = {};
    if (kb < 3) {
      const u16* kp = kbase + (size_t)((kb + 1) * 64 + prow) * 1536 + pc16;
      pk0 = *(const short8*)kp;
      pk1 = *(const short8*)(kp + 8);
      const u16* vp = vbase + (size_t)((kb + 1) * 64 + prow) * 1536 + pc16;
      pv0 = *(const short8*)vp;
      pv1 = *(const short8*)(vp + 8);
    }
#pragma unroll
    for (int qt = 0; qt < 2; ++qt) {
      f32x16 s0 = {}, s1 = {};
#pragma unroll
      for (int c = 0; c < 4; ++c) {
        frag8 kf0 = *(const frag8*)&KbB[cur * 4352 + l31 * 68 + c * 16 + l5 * 8];
        frag8 kf1 = *(const frag8*)&KbB[cur * 4352 + (32 + l31) * 68 + c * 16 + l5 * 8];
        s0 = MFMA32(kf0, qf[qt][c], s0);
        s1 = MFMA32(kf1, qf[qt][c], s1);
      }
      float tm[16];
#pragma unroll
      for (int r = 0; r < 16; ++r) tm[r] = fmaxf(s0[r], s1[r]);
#pragma unroll
      for (int r = 0; r < 8; ++r) tm[r] = fmaxf(tm[r], tm[r + 8]);
#pragma unroll
      for (int r = 0; r < 4; ++r) tm[r] = fmaxf(tm[r], tm[r + 4]);
      float pm = fmaxf(fmaxf(tm[0], tm[1]), fmaxf(tm[2], tm[3]));
      pm = fmaxf(pm, __shfl_xor(pm, 32));
      if (!__all(pm <= m_run[qt] + 64.f)) {  // defer-max (thr 8 post-scale)
        float mn = fmaxf(m_run[qt], pm);
        float corr = __expf((m_run[qt] - mn) * 0.125f);
        l_run[qt] *= corr;
#pragma unroll
        for (int dt = 0; dt < 2; ++dt)
#pragma unroll
          for (int r = 0; r < 16; ++r) of[qt][dt][r] *= corr;
        m_run[qt] = mn;
      }
      const float mqt = m_run[qt];
      float ls = 0.f;
#pragma unroll
      for (int kt = 0; kt < 2; ++kt) {
        const f32x16 sv = kt ? s1 : s0;
        float p[16];
#pragma unroll
        for (int r = 0; r < 16; ++r) p[r] = __expf((sv[r] - mqt) * 0.125f);
        float e0 = (p[0] + p[1]) + (p[2] + p[3]);
        float e1 = (p[4] + p[5]) + (p[6] + p[7]);
        float e2 = (p[8] + p[9]) + (p[10] + p[11]);
        float e3 = (p[12] + p[13]) + (p[14] + p[15]);
        ls += (e0 + e1) + (e2 + e3);
#pragma unroll
        for (int cc = 0; cc < 2; ++cc) {
          const int bx = cc * 8;
          unsigned a0 = cvtpk_bf16(p[bx + 0], p[bx + 1]);
          unsigned a1 = cvtpk_bf16(p[bx + 2], p[bx + 3]);
          unsigned b0 = cvtpk_bf16(p[bx + 4], p[bx + 5]);
          unsigned b1 = cvtpk_bf16(p[bx + 6], p[bx + 7]);
          // cross-half exchange: D_new={D.lo,S.lo}, S_new={D.hi,S.hi}
          asm("v_permlane32_swap_b32 %0, %1" : "+v"(a0), "+v"(b0));
          asm("v_permlane32_swap_b32 %0, %1" : "+v"(a1), "+v"(b1));
          uint4 fu;
          fu.x = a0;
          fu.y = a1;
          fu.z = b0;
          fu.w = b1;
          frag8 pb = __builtin_bit_cast(frag8, fu);
#pragma unroll
          for (int dt = 0; dt < 2; ++dt) {
            frag8 va = *(const frag8*)&VtB[cur * 4480 + (dt * 32 + l31) * 70 + kt * 32 + cc * 16 +
                                           l5 * 8];
            of[qt][dt] = MFMA32(va, pb, of[qt][dt]);
          }
        }
      }
      l_run[qt] += ls;
    }
    if (kb < 3) {
      *(short8*)&KbB[(cur ^ 1) * 4352 + prow * 68 + pc16] = pk0;
      *(short8*)&KbB[(cur ^ 1) * 4352 + prow * 68 + pc16 + 8] = pk1;
      u16* vd = &VtB[(cur ^ 1) * 4480 + prow];
#pragma unroll
      for (int e = 0; e < 8; ++e) {
        vd[(pc16 + e) * 70] = (u16)pv0[e];
        vd[(pc16 + 8 + e) * 70] = (u16)pv1[e];
      }
    }
    __syncthreads();
    cur ^= 1;
  }

  float inv[2];
#pragma unroll
  for (int qt = 0; qt < 2; ++qt) {
    float lt = l_run[qt] + __shfl_xor(l_run[qt], 32);
    inv[qt] = 1.0f / lt;
  }
  u16* sc = smem + wv * 4352;  // per-wave [64][68] scratch (reuses K/V LDS)
  __syncthreads();
#pragma unroll
  for (int qt = 0; qt < 2; ++qt)
#pragma unroll
    for (int dt = 0; dt < 2; ++dt)
#pragma unroll
      for (int j = 0; j < 4; ++j) {
        unsigned w0 = cvtpk_bf16(of[qt][dt][4 * j + 0] * inv[qt], of[qt][dt][4 * j + 1] * inv[qt]);
        unsigned w1 = cvtpk_bf16(of[qt][dt][4 * j + 2] * inv[qt], of[qt][dt][4 * j + 3] * inv[qt]);
        *(uint2*)&sc[(qt * 32 + l31) * 68 + dt * 32 + 8 * j + 4 * l5] = make_uint2(w0, w1);
      }
  asm volatile("" ::: "memory");
#pragma unroll
  for (int rep = 0; rep < 8; ++rep) {
    int row = rep * 8 + (lane >> 3);
    uint2 lo = *(const uint2*)&sc[row * 68 + (lane & 7) * 8];
    uint2 hi = *(const uint2*)&sc[row * 68 + (lane & 7) * 8 + 4];
    *(int4*)&aout[(size_t)(win * 256 + wv * 64 + row) * 512 + h * 64 + (lane & 7) * 8] =
        make_int4((int)lo.x, (int)lo.y, (int)hi.x, (int)hi.y);
  }
}

// ---------------------------------------------------------------- finalize
__global__ void k_final(const float* __restrict__ x, const u16* __restrict__ proj,
                        const int* __restrict__ kept, const float* __restrict__ mult,
                        float* __restrict__ out) {
  const size_t idx = (size_t)blockIdx.x * 256 + threadIdx.x;
  const int dci = (int)(idx & 31);
  const int pix = (int)((idx >> 5) & 16383);
  const int b = (int)(idx >> 19);
  const int y = pix >> 7, xc = pix & 127;
  float acc[16];
#pragma unroll
  for (int e = 0; e < 16; ++e) acc[e] = 0.f;
  float c = 0.f;
  const int wyh = y >> 3, wxh = xc >> 3;
#pragma unroll
  for (int a = 0; a < 2; ++a) {
    int wy = wyh - 1 + a;
    if (wy < 0 || wy > 14) continue;
#pragma unroll
    for (int bb = 0; bb < 2; ++bb) {
      int wx = wxh - 1 + bb;
      if (wx < 0 || wx > 14) continue;
      int w = wy * 15 + wx;
      int slot = kept[b * 225 + w];
      if (slot < 0) continue;
      float ml = mult[b * 225 + w];
      c += ml;
      const u16* pr = proj +
                      ((size_t)((b * 44 + slot) * 256 + (y - wy * 8) * 16 + (xc - wx * 8))) * 512 +
                      (size_t)dci * 16;
      short8 v0 = *(const short8*)pr;
      short8 v1 = *(const short8*)(pr + 8);
#pragma unroll
      for (int e = 0; e < 8; ++e) acc[e] += ml * bf2f((u16)v0[e]);
#pragma unroll
      for (int e = 0; e < 8; ++e) acc[8 + e] += ml * bf2f((u16)v1[e]);
    }
  }
  const float inv = 1.f / (c + 1e-10f);
  const size_t off = ((size_t)(b * 16384 + pix)) * 512 + (size_t)dci * 16;
  const float4* xp = (const float4*)(x + off);
  float4* op = (float4*)(out + off);
#pragma unroll
  for (int q4 = 0; q4 < 4; ++q4) {
    float4 xv = xp[q4];
    float4 ov;
    ov.x = xv.x + acc[q4 * 4 + 0] * inv;
    ov.y = xv.y + acc[q4 * 4 + 1] * inv;
    ov.z = xv.z + acc[q4 * 4 + 2] * inv;
    ov.w = xv.w + acc[q4 * 4 + 3] * inv;
    op[q4] = ov;
  }
}

// ---------------------------------------------------------------- launch
extern "C" void kernel_launch(void* const* d_in, const int* in_sizes, int n_in, void* d_out,
                              int out_size, void* d_ws, size_t ws_size, hipStream_t stream) {
  const float* x = (const float*)d_in[0];
  const float* prob = (const float*)d_in[1];
  const float* wfix = (const float*)d_in[2];
  const float* Wq = (const float*)d_in[3];
  const float* Wo = (const float*)d_in[4];
  const float* bo = (const float*)d_in[5];
  float* out = (float*)d_out;
  char* ws = (char*)d_ws;

  float* scores = (float*)(ws + 0);
  int* sel = (int*)(ws + 8192);
  int* kept = (int*)(ws + 16384);
  float* mult = (float*)(ws + 24576);
  u16* wqb = (u16*)(ws + 32768);
  u16* wob = (u16*)(ws + 32768 + 1572864);
  u16* xi = (u16*)(ws + 4194304);
  u16* qkv = (u16*)(ws + 4194304 + 92274688);
  u16* aout = xi;
  u16* proj = qkv;

  k_score<<<8, 256, 0, stream>>>(prob, wfix, scores);
  k_nms<<<8, 256, 0, stream>>>(scores, sel, kept, mult);
  k_castw<<<4096, 256, 0, stream>>>(Wq, Wo, wqb, wob);
  k_gather<<<22528, 256, 0, stream>>>(x, sel, xi);
  k_gemm128<0><<<8448, 256, 0, stream>>>(xi, wqb, qkv, nullptr, 90112, 1536, 512, 12);
  k_attn<<<2816, 256, 0, stream>>>(qkv, aout);
  k_gemm128<1><<<2816, 256, 0, stream>>>(aout, wob, proj, bo, 90112, 512, 512, 4);
  k_final<<<16384, 256, 0, stream>>>(x, proj, kept, mult, out);
}

// Round 13
// 747.795 us; speedup vs baseline: 1.4021x; 1.0029x over previous
//
#include <hip/hip_runtime.h>
#include <type_traits>
#include <utility>

typedef unsigned short u16;
typedef __attribute__((ext_vector_type(8))) short short8;
typedef __attribute__((ext_vector_type(8))) __bf16 bf16v8;
typedef __attribute__((ext_vector_type(4))) float f32x4;
typedef __attribute__((ext_vector_type(16))) float f32x16;

template <typename T, typename = void> struct mfma_ok : std::false_type {};
template <typename T>
struct mfma_ok<T, std::void_t<decltype(__builtin_amdgcn_mfma_f32_16x16x32_bf16(
    std::declval<T>(), std::declval<T>(), std::declval<f32x4>(), 0, 0, 0))>>
    : std::true_type {};
using frag8 = std::conditional_t<mfma_ok<bf16v8>::value, bf16v8, short8>;

#define MFMA16(a, b, c) __builtin_amdgcn_mfma_f32_16x16x32_bf16((a), (b), (c), 0, 0, 0)
#define MFMA32(a, b, c) __builtin_amdgcn_mfma_f32_32x32x16_bf16((a), (b), (c), 0, 0, 0)

__device__ __forceinline__ float bf2f(u16 u) {
  unsigned v = ((unsigned)u) << 16;
  return __builtin_bit_cast(float, v);
}
__device__ __forceinline__ u16 f2bf(float f) {
  unsigned u = __builtin_bit_cast(unsigned, f);
  u = (u + 0x7fffu + ((u >> 16) & 1u)) >> 16;
  return (u16)u;
}
__device__ __forceinline__ unsigned cvtpk_bf16(float lo, float hi) {
  unsigned r;
  asm("v_cvt_pk_bf16_f32 %0, %1, %2" : "=v"(r) : "v"(lo), "v"(hi));
  return r;
}
// async global->LDS, 16B per lane; lds ptr must be wave-uniform base (+lane*16 implicit)
__device__ __forceinline__ void gl16(const u16* g, u16* l) {
  __builtin_amdgcn_global_load_lds((__attribute__((address_space(1))) void*)(g),
                                   (__attribute__((address_space(3))) void*)(l), 16, 0, 0);
}
__device__ __forceinline__ void vmw8() { asm volatile("s_waitcnt vmcnt(8)" ::: "memory"); }
__device__ __forceinline__ void vmw0() { asm volatile("s_waitcnt vmcnt(0)" ::: "memory"); }
__device__ __forceinline__ void lgw0() { asm volatile("s_waitcnt lgkmcnt(0)" ::: "memory"); }

// head-major qkv layout (u16 units): win*393216 + type*131072 + h*16384 + r*64 + d
// head-major aout layout:            win*131072 + h*16384 + r*64 + d

// ---------------------------------------------------------------- score
__global__ void k_score(const float* __restrict__ prob, const float* __restrict__ wfix,
                        float* __restrict__ scores) {
  const int b = blockIdx.x, tid = threadIdx.x;
  __shared__ float ent[64 * 64];
  __shared__ float wf[64];
  if (tid < 64) wf[tid] = wfix[tid];
  const float* pb = prob + (size_t)b * 4 * 4096;
  for (int p = tid; p < 4096; p += 256) {
    float e = 0.f;
#pragma unroll
    for (int ch = 0; ch < 4; ++ch) {
      float v = pb[ch * 4096 + p];
      e -= v * log2f(v + 1e-10f);
    }
    ent[p] = e;
  }
  __syncthreads();
  if (tid < 225) {
    int wy = tid / 15, wx = tid % 15;
    float s = 0.f;
    for (int a = 0; a < 8; ++a)
      for (int c = 0; c < 8; ++c)
        s += ent[(wy * 4 + a) * 64 + wx * 4 + c] * wf[a * 8 + c];
    scores[b * 225 + tid] = s * (1.0f / 64.0f);
  }
}

// ---------------------------------------------------------------- nms
__device__ __forceinline__ float iou_pair(int wa, int wb) {
  float x1a = (float)((wa % 15) * 8), y1a = (float)((wa / 15) * 8);
  float x1b = (float)((wb % 15) * 8), y1b = (float)((wb / 15) * 8);
  float iw = fminf(x1a, x1b) + 15.f - fmaxf(x1a, x1b);
  float ih = fminf(y1a, y1b) + 15.f - fmaxf(y1a, y1b);
  iw = fmaxf(iw, 0.f);
  ih = fmaxf(ih, 0.f);
  float inter = iw * ih;
  return inter / (450.f - inter);
}

__global__ void k_nms(const float* __restrict__ scores, int* __restrict__ sel,
                      int* __restrict__ kept, float* __restrict__ mult) {
  const int b = blockIdx.x, t = threadIdx.x;
  __shared__ float s[225];
  __shared__ int order[225];
  __shared__ unsigned char supp[225];
  __shared__ int idx44[44];
  __shared__ int ks[225];
  __shared__ float ml[225];
  if (t < 225) s[t] = scores[b * 225 + t];
  __syncthreads();
  if (t < 225) {
    float st = s[t];
    int r = 0;
    for (int j = 0; j < 225; ++j) {
      float sj = s[j];
      r += (sj > st) || (sj == st && j < t);
    }
    order[r] = t;
    supp[t] = 0;
    ks[t] = -1;
    ml[t] = 0.f;
  }
  __syncthreads();
  for (int i = 0; i < 224; ++i) {
    if (t > i && t < 225 && !supp[i]) {
      if (iou_pair(order[i], order[t]) > 0.2f) supp[t] = 1;
    }
    __syncthreads();
  }
  if (t == 0) {
    int k = 0;
    for (int i = 0; i < 225 && k < 44; ++i)
      if (!supp[i]) idx44[k++] = order[i];
    while (k < 44) idx44[k++] = order[224];
    for (int k2 = 0; k2 < 44; ++k2) {
      int w = idx44[k2];
      if (ks[w] < 0) ks[w] = k2;
      ml[w] += 1.f;
    }
  }
  __syncthreads();
  if (t < 225) {
    kept[b * 225 + t] = ks[t];
    mult[b * 225 + t] = ml[t];
  }
  if (t < 44) sel[b * 44 + t] = idx44[t];
}

// ---------------------------------------------------------------- weight cast
__global__ void k_castw(const float* __restrict__ Wq, const float* __restrict__ Wo,
                        u16* __restrict__ wqb, u16* __restrict__ wob) {
  int idx = blockIdx.x * 256 + threadIdx.x;
  if (idx < 786432) wqb[idx] = f2bf(Wq[idx]);
  int i2 = idx - 786432;
  if (i2 >= 0 && i2 < 262144) wob[i2] = f2bf(Wo[i2]);
}

// ---------------------------------------------------------------- gather + bilinear (direct 4-tap)
__global__ __launch_bounds__(256) void k_gather(const float* __restrict__ x,
                                                const int* __restrict__ sel,
                                                u16* __restrict__ xi) {
  const size_t idx = (size_t)blockIdx.x * 256 + threadIdx.x;
  const int dc = (int)(idx & 63);
  const int pq = (int)((idx >> 6) & 255);
  const int g = (int)(idx >> 14);
  const int b = g / 44;
  const int w = sel[g];
  const int sy = (w / 15) * 8, sx = (w % 15) * 8;
  const int p = pq >> 4, q = pq & 15;
  float rp = ((float)p + 0.5f) * 0.9375f;
  int i0 = (int)rp;
  float fp = rp - (float)i0;
  float rq = ((float)q + 0.5f) * 0.9375f;
  int j0 = (int)rq;
  float fq = rq - (float)j0;
  const float w00 = (1.f - fp) * (1.f - fq), w01 = (1.f - fp) * fq;
  const float w10 = fp * (1.f - fq), w11 = fp * fq;
  const float* xb = x + ((size_t)b * 16384 + (size_t)(sy + i0) * 128 + sx + j0) * 512 + dc * 8;
  const float4* t00 = (const float4*)xb;
  const float4* t01 = (const float4*)(xb + 512);
  const float4* t10 = (const float4*)(xb + 512 * 128);
  const float4* t11 = (const float4*)(xb + 512 * 129);
  float acc[8];
#pragma unroll
  for (int h = 0; h < 2; ++h) {
    float4 a = t00[h], bb = t01[h], c = t10[h], d = t11[h];
    acc[h * 4 + 0] = w00 * a.x + w01 * bb.x + w10 * c.x + w11 * d.x;
    acc[h * 4 + 1] = w00 * a.y + w01 * bb.y + w10 * c.y + w11 * d.y;
    acc[h * 4 + 2] = w00 * a.z + w01 * bb.z + w10 * c.z + w11 * d.z;
    acc[h * 4 + 3] = w00 * a.w + w01 * bb.w + w10 * c.w + w11 * d.w;
  }
  short8 o;
#pragma unroll
  for (int e = 0; e < 8; ++e) o[e] = (short)f2bf(acc[e]);
  *(short8*)&xi[((size_t)g * 256 + pq) * 512 + dc * 8] = o;
}

// ---------------------------------------------------------------- GEMM 128x128, BK=64, 4 waves
// Counted-vmcnt dbuf + T2 XOR swizzle; 2 blocks/CU.
// OPERM: C written head-major qkv' layout. APERM: A read head-major aout' layout (BK==64==Dh).
template <int BIAS, int OPERM, int APERM>
__global__ __launch_bounds__(256, 2) void k_gemm128(const u16* __restrict__ A,
                                                    const u16* __restrict__ B, u16* __restrict__ C,
                                                    const float* __restrict__ bias, int M, int N,
                                                    int K, int nbn) {
  __shared__ u16 sA[2][128 * 64];
  __shared__ u16 sB[2][128 * 64];
  const int tid = threadIdx.x, lane = tid & 63, wv = tid >> 6;
  const int f = blockIdx.x;
  const int q8 = gridDim.x >> 3;
  const int wg = (f & 7) * q8 + (f >> 3);  // bijective XCD swizzle (nwg % 8 == 0)
  const int bm = wg / nbn, bn = wg % nbn;
  const int wm = (wv >> 1) * 64, wn = (wv & 1) * 64;
  const int l15 = lane & 15, k8 = (lane >> 4) * 8;
  const int xorv = (l15 & 7) * 8;  // read-side swizzle (elements)
  const int srow = tid >> 3;                     // 0..31 (rows within 32-row chunk)
  const int sc8 = ((tid ^ (tid >> 3)) & 7) * 8;  // pre-swizzled source col
  const int arow0 = bm * 128 + srow, brow0 = bn * 128 + srow;

  f32x4 acc[4][4] = {};

  // STAGE tile kt into buf: 8 gl16 (4 chunks x A,B), 32 rows per chunk
#define STAGE(kt, buf)                                                                          \
  {                                                                                             \
    _Pragma("unroll") for (int c = 0; c < 4; ++c) {                                             \
      const int ar = arow0 + c * 32;                                                            \
      size_t aoffs = APERM ? ((size_t)(ar >> 8) * 131072 + (size_t)(kt) * 16384 +               \
                              (size_t)(ar & 255) * 64 + sc8)                                    \
                           : ((size_t)ar * K + (kt) * 64 + sc8);                                \
      gl16(A + aoffs, &sA[buf][c * 2048 + wv * 512]);                                           \
      gl16(B + (size_t)(brow0 + c * 32) * K + (kt) * 64 + sc8, &sB[buf][c * 2048 + wv * 512]); \
    }                                                                                           \
  }

  STAGE(0, 0);
  STAGE(1, 1);

  for (int t = 0; t < 8; ++t) {
    const int buf = t & 1;
    if (t == 7)
      vmw0();
    else
      vmw8();  // counted: next tile's 8 loads stay in flight
    __builtin_amdgcn_sched_barrier(0);
    __builtin_amdgcn_s_barrier();  // tile t resident for all waves
    frag8 af[4][2], bf[4][2];
#pragma unroll
    for (int i = 0; i < 4; ++i)
#pragma unroll
      for (int kk = 0; kk < 2; ++kk) {
        af[i][kk] = *(const frag8*)&sA[buf][(wm + i * 16 + l15) * 64 + ((kk * 32 + k8) ^ xorv)];
        bf[i][kk] = *(const frag8*)&sB[buf][(wn + i * 16 + l15) * 64 + ((kk * 32 + k8) ^ xorv)];
      }
    __builtin_amdgcn_s_setprio(1);
#pragma unroll
    for (int i = 0; i < 4; ++i)
#pragma unroll
      for (int j = 0; j < 4; ++j)
#pragma unroll
        for (int kk = 0; kk < 2; ++kk)
          acc[i][j] = MFMA16(af[i][kk], bf[j][kk], acc[i][j]);
    __builtin_amdgcn_s_setprio(0);
    lgw0();  // this wave's ds_reads fully retired before buf can be overwritten
    __builtin_amdgcn_sched_barrier(0);
    __builtin_amdgcn_s_barrier();  // all waves done reading buf
    if (t < 6) STAGE(t + 2, buf);  // issued here: flies under next tile's compute
  }
#undef STAGE

  const int cc = lane & 15, rr = (lane >> 4) * 4;
#pragma unroll
  for (int i = 0; i < 4; ++i)
#pragma unroll
    for (int j = 0; j < 4; ++j) {
      int col = bn * 128 + wn + j * 16 + cc;
      float badd = BIAS ? bias[col] : 0.f;
#pragma unroll
      for (int e = 0; e < 4; ++e) {
        int row = bm * 128 + wm + i * 16 + rr + e;
        if (OPERM) {
          size_t caddr = (size_t)(row >> 8) * 393216 + (size_t)(col >> 9) * 131072 +
                         (size_t)((col >> 6) & 7) * 16384 + (size_t)(row & 255) * 64 + (col & 63);
          C[caddr] = f2bf(acc[i][j][e] + badd);
        } else {
          C[(size_t)row * N + col] = f2bf(acc[i][j][e] + badd);
        }
      }
    }
}

// ---------------------------------------------------------------- attention (swapped 32x32)
// Head-major layout: each (win,h) block's Q/K/V slices are CONTIGUOUS 32KB -> DRAM-friendly.
// 4 waves x 64 q-rows; K AND V double-buffered per 64-key block; launch_bounds (256,3).
__global__ __launch_bounds__(256, 3) void k_attn(const u16* __restrict__ qkv,
                                                 u16* __restrict__ aout) {
  const int g = blockIdx.x;
  const int win = g % 352, h = g / 352;
  const int tid = threadIdx.x, lane = tid & 63, wv = tid >> 6;
  const int l31 = lane & 31, l5 = lane >> 5;
  __shared__ u16 smem[17664];  // Kb[2][64][68] (8704 u16) | Vt[2][64][70] (8960 u16)
  u16* KbB = smem;
  u16* VtB = smem + 8704;
  const u16* qbase = qkv + (size_t)win * 393216 + (size_t)h * 16384;
  const u16* kbase = qbase + 131072;
  const u16* vbase = qbase + 262144;
  const int prow = tid >> 2, pc16 = (tid & 3) * 16;

  // Q B-frags first (longest-latency dependency); rows are 64-u16 strided (contiguous 4KB/wave)
  frag8 qf[2][4];
#pragma unroll
  for (int qt = 0; qt < 2; ++qt)
#pragma unroll
    for (int c = 0; c < 4; ++c)
      qf[qt][c] = *(const frag8*)(qbase + (size_t)(wv * 64 + qt * 32 + l31) * 64 + c * 16 +
                                  l5 * 8);
  // K block 0 + V block 0 (thread: key=prow, d-range pc16..pc16+15) — contiguous 2KB per wave
  {
    const u16* kp = kbase + (size_t)prow * 64 + pc16;
    short8 ka = *(const short8*)kp;
    short8 kb2 = *(const short8*)(kp + 8);
    const u16* vp = vbase + (size_t)prow * 64 + pc16;
    short8 va = *(const short8*)vp;
    short8 vb2 = *(const short8*)(vp + 8);
    *(short8*)&KbB[prow * 68 + pc16] = ka;
    *(short8*)&KbB[prow * 68 + pc16 + 8] = kb2;
#pragma unroll
    for (int e = 0; e < 8; ++e) {
      VtB[(pc16 + e) * 70 + prow] = (u16)va[e];
      VtB[(pc16 + 8 + e) * 70 + prow] = (u16)vb2[e];
    }
  }
  __syncthreads();

  f32x16 of[2][2] = {};
  float m_run[2] = {-3e38f, -3e38f};
  float l_run[2] = {0.f, 0.f};

  int cur = 0;
  for (int kb = 0; kb < 4; ++kb) {
    short8 pk0 = {}, pk1 = {}, pv0 = {}, pv1 = {};
    if (kb < 3) {
      const u16* kp = kbase + (size_t)((kb + 1) * 64 + prow) * 64 + pc16;
      pk0 = *(const short8*)kp;
      pk1 = *(const short8*)(kp + 8);
      const u16* vp = vbase + (size_t)((kb + 1) * 64 + prow) * 64 + pc16;
      pv0 = *(const short8*)vp;
      pv1 = *(const short8*)(vp + 8);
    }
#pragma unroll
    for (int qt = 0; qt < 2; ++qt) {
      f32x16 s0 = {}, s1 = {};
#pragma unroll
      for (int c = 0; c < 4; ++c) {
        frag8 kf0 = *(const frag8*)&KbB[cur * 4352 + l31 * 68 + c * 16 + l5 * 8];
        frag8 kf1 = *(const frag8*)&KbB[cur * 4352 + (32 + l31) * 68 + c * 16 + l5 * 8];
        s0 = MFMA32(kf0, qf[qt][c], s0);
        s1 = MFMA32(kf1, qf[qt][c], s1);
      }
      float tm[16];
#pragma unroll
      for (int r = 0; r < 16; ++r) tm[r] = fmaxf(s0[r], s1[r]);
#pragma unroll
      for (int r = 0; r < 8; ++r) tm[r] = fmaxf(tm[r], tm[r + 8]);
#pragma unroll
      for (int r = 0; r < 4; ++r) tm[r] = fmaxf(tm[r], tm[r + 4]);
      float pm = fmaxf(fmaxf(tm[0], tm[1]), fmaxf(tm[2], tm[3]));
      pm = fmaxf(pm, __shfl_xor(pm, 32));
      if (!__all(pm <= m_run[qt] + 64.f)) {  // defer-max (thr 8 post-scale)
        float mn = fmaxf(m_run[qt], pm);
        float corr = __expf((m_run[qt] - mn) * 0.125f);
        l_run[qt] *= corr;
#pragma unroll
        for (int dt = 0; dt < 2; ++dt)
#pragma unroll
          for (int r = 0; r < 16; ++r) of[qt][dt][r] *= corr;
        m_run[qt] = mn;
      }
      const float mqt = m_run[qt];
      float ls = 0.f;
#pragma unroll
      for (int kt = 0; kt < 2; ++kt) {
        const f32x16 sv = kt ? s1 : s0;
        float p[16];
#pragma unroll
        for (int r = 0; r < 16; ++r) p[r] = __expf((sv[r] - mqt) * 0.125f);
        float e0 = (p[0] + p[1]) + (p[2] + p[3]);
        float e1 = (p[4] + p[5]) + (p[6] + p[7]);
        float e2 = (p[8] + p[9]) + (p[10] + p[11]);
        float e3 = (p[12] + p[13]) + (p[14] + p[15]);
        ls += (e0 + e1) + (e2 + e3);
#pragma unroll
        for (int cc = 0; cc < 2; ++cc) {
          const int bx = cc * 8;
          unsigned a0 = cvtpk_bf16(p[bx + 0], p[bx + 1]);
          unsigned a1 = cvtpk_bf16(p[bx + 2], p[bx + 3]);
          unsigned b0 = cvtpk_bf16(p[bx + 4], p[bx + 5]);
          unsigned b1 = cvtpk_bf16(p[bx + 6], p[bx + 7]);
          // cross-half exchange: D_new={D.lo,S.lo}, S_new={D.hi,S.hi}
          asm("v_permlane32_swap_b32 %0, %1" : "+v"(a0), "+v"(b0));
          asm("v_permlane32_swap_b32 %0, %1" : "+v"(a1), "+v"(b1));
          uint4 fu;
          fu.x = a0;
          fu.y = a1;
          fu.z = b0;
          fu.w = b1;
          frag8 pb = __builtin_bit_cast(frag8, fu);
#pragma unroll
          for (int dt = 0; dt < 2; ++dt) {
            frag8 va = *(const frag8*)&VtB[cur * 4480 + (dt * 32 + l31) * 70 + kt * 32 + cc * 16 +
                                           l5 * 8];
            of[qt][dt] = MFMA32(va, pb, of[qt][dt]);
          }
        }
      }
      l_run[qt] += ls;
    }
    if (kb < 3) {
      *(short8*)&KbB[(cur ^ 1) * 4352 + prow * 68 + pc16] = pk0;
      *(short8*)&KbB[(cur ^ 1) * 4352 + prow * 68 + pc16 + 8] = pk1;
      u16* vd = &VtB[(cur ^ 1) * 4480 + prow];
#pragma unroll
      for (int e = 0; e < 8; ++e) {
        vd[(pc16 + e) * 70] = (u16)pv0[e];
        vd[(pc16 + 8 + e) * 70] = (u16)pv1[e];
      }
    }
    __syncthreads();
    cur ^= 1;
  }

  float inv[2];
#pragma unroll
  for (int qt = 0; qt < 2; ++qt) {
    float lt = l_run[qt] + __shfl_xor(l_run[qt], 32);
    inv[qt] = 1.0f / lt;
  }
  u16* sc = smem + wv * 4352;  // per-wave [64][68] scratch (reuses K/V LDS)
  __syncthreads();
#pragma unroll
  for (int qt = 0; qt < 2; ++qt)
#pragma unroll
    for (int dt = 0; dt < 2; ++dt)
#pragma unroll
      for (int j = 0; j < 4; ++j) {
        unsigned w0 = cvtpk_bf16(of[qt][dt][4 * j + 0] * inv[qt], of[qt][dt][4 * j + 1] * inv[qt]);
        unsigned w1 = cvtpk_bf16(of[qt][dt][4 * j + 2] * inv[qt], of[qt][dt][4 * j + 3] * inv[qt]);
        *(uint2*)&sc[(qt * 32 + l31) * 68 + dt * 32 + 8 * j + 4 * l5] = make_uint2(w0, w1);
      }
  asm volatile("" ::: "memory");
  // head-major aout': contiguous 1KB per rep instr
  u16* obase = aout + (size_t)win * 131072 + (size_t)h * 16384 + (size_t)wv * 64 * 64;
#pragma unroll
  for (int rep = 0; rep < 8; ++rep) {
    int row = rep * 8 + (lane >> 3);
    uint2 lo = *(const uint2*)&sc[row * 68 + (lane & 7) * 8];
    uint2 hi = *(const uint2*)&sc[row * 68 + (lane & 7) * 8 + 4];
    *(int4*)&obase[(size_t)row * 64 + (lane & 7) * 8] =
        make_int4((int)lo.x, (int)lo.y, (int)hi.x, (int)hi.y);
  }
}

// ---------------------------------------------------------------- finalize
__global__ void k_final(const float* __restrict__ x, const u16* __restrict__ proj,
                        const int* __restrict__ kept, const float* __restrict__ mult,
                        float* __restrict__ out) {
  const size_t idx = (size_t)blockIdx.x * 256 + threadIdx.x;
  const int dci = (int)(idx & 31);
  const int pix = (int)((idx >> 5) & 16383);
  const int b = (int)(idx >> 19);
  const int y = pix >> 7, xc = pix & 127;
  float acc[16];
#pragma unroll
  for (int e = 0; e < 16; ++e) acc[e] = 0.f;
  float c = 0.f;
  const int wyh = y >> 3, wxh = xc >> 3;
#pragma unroll
  for (int a = 0; a < 2; ++a) {
    int wy = wyh - 1 + a;
    if (wy < 0 || wy > 14) continue;
#pragma unroll
    for (int bb = 0; bb < 2; ++bb) {
      int wx = wxh - 1 + bb;
      if (wx < 0 || wx > 14) continue;
      int w = wy * 15 + wx;
      int slot = kept[b * 225 + w];
      if (slot < 0) continue;
      float ml = mult[b * 225 + w];
      c += ml;
      const u16* pr = proj +
                      ((size_t)((b * 44 + slot) * 256 + (y - wy * 8) * 16 + (xc - wx * 8))) * 512 +
                      (size_t)dci * 16;
      short8 v0 = *(const short8*)pr;
      short8 v1 = *(const short8*)(pr + 8);
#pragma unroll
      for (int e = 0; e < 8; ++e) acc[e] += ml * bf2f((u16)v0[e]);
#pragma unroll
      for (int e = 0; e < 8; ++e) acc[8 + e] += ml * bf2f((u16)v1[e]);
    }
  }
  const float inv = 1.f / (c + 1e-10f);
  const size_t off = ((size_t)(b * 16384 + pix)) * 512 + (size_t)dci * 16;
  const float4* xp = (const float4*)(x + off);
  float4* op = (float4*)(out + off);
#pragma unroll
  for (int q4 = 0; q4 < 4; ++q4) {
    float4 xv = xp[q4];
    float4 ov;
    ov.x = xv.x + acc[q4 * 4 + 0] * inv;
    ov.y = xv.y + acc[q4 * 4 + 1] * inv;
    ov.z = xv.z + acc[q4 * 4 + 2] * inv;
    ov.w = xv.w + acc[q4 * 4 + 3] * inv;
    op[q4] = ov;
  }
}

// ---------------------------------------------------------------- launch
extern "C" void kernel_launch(void* const* d_in, const int* in_sizes, int n_in, void* d_out,
                              int out_size, void* d_ws, size_t ws_size, hipStream_t stream) {
  const float* x = (const float*)d_in[0];
  const float* prob = (const float*)d_in[1];
  const float* wfix = (const float*)d_in[2];
  const float* Wq = (const float*)d_in[3];
  const float* Wo = (const float*)d_in[4];
  const float* bo = (const float*)d_in[5];
  float* out = (float*)d_out;
  char* ws = (char*)d_ws;

  float* scores = (float*)(ws + 0);
  int* sel = (int*)(ws + 8192);
  int* kept = (int*)(ws + 16384);
  float* mult = (float*)(ws + 24576);
  u16* wqb = (u16*)(ws + 32768);
  u16* wob = (u16*)(ws + 32768 + 1572864);
  u16* xi = (u16*)(ws + 4194304);
  u16* qkv = (u16*)(ws + 4194304 + 92274688);
  u16* aout = xi;   // head-major aout' reuses xi buffer (same 92.3 MB footprint)
  u16* proj = qkv;  // proj output reuses qkv buffer

  k_score<<<8, 256, 0, stream>>>(prob, wfix, scores);
  k_nms<<<8, 256, 0, stream>>>(scores, sel, kept, mult);
  k_castw<<<4096, 256, 0, stream>>>(Wq, Wo, wqb, wob);
  k_gather<<<22528, 256, 0, stream>>>(x, sel, xi);
  k_gemm128<0, 1, 0><<<8448, 256, 0, stream>>>(xi, wqb, qkv, nullptr, 90112, 1536, 512, 12);
  k_attn<<<2816, 256, 0, stream>>>(qkv, aout);
  k_gemm128<1, 0, 1><<<2816, 256, 0, stream>>>(aout, wob, proj, bo, 90112, 512, 512, 4);
  k_final<<<16384, 256, 0, stream>>>(x, proj, kept, mult, out);
}

// Round 14
// 742.397 us; speedup vs baseline: 1.4123x; 1.0073x over previous
//
#include <hip/hip_runtime.h>
#include <type_traits>
#include <utility>

typedef unsigned short u16;
typedef __attribute__((ext_vector_type(8))) short short8;
typedef __attribute__((ext_vector_type(8))) __bf16 bf16v8;
typedef __attribute__((ext_vector_type(4))) float f32x4;
typedef __attribute__((ext_vector_type(16))) float f32x16;

template <typename T, typename = void> struct mfma_ok : std::false_type {};
template <typename T>
struct mfma_ok<T, std::void_t<decltype(__builtin_amdgcn_mfma_f32_16x16x32_bf16(
    std::declval<T>(), std::declval<T>(), std::declval<f32x4>(), 0, 0, 0))>>
    : std::true_type {};
using frag8 = std::conditional_t<mfma_ok<bf16v8>::value, bf16v8, short8>;

#define MFMA16(a, b, c) __builtin_amdgcn_mfma_f32_16x16x32_bf16((a), (b), (c), 0, 0, 0)
#define MFMA32(a, b, c) __builtin_amdgcn_mfma_f32_32x32x16_bf16((a), (b), (c), 0, 0, 0)

__device__ __forceinline__ float bf2f(u16 u) {
  unsigned v = ((unsigned)u) << 16;
  return __builtin_bit_cast(float, v);
}
__device__ __forceinline__ u16 f2bf(float f) {
  unsigned u = __builtin_bit_cast(unsigned, f);
  u = (u + 0x7fffu + ((u >> 16) & 1u)) >> 16;
  return (u16)u;
}
__device__ __forceinline__ unsigned cvtpk_bf16(float lo, float hi) {
  unsigned r;
  asm("v_cvt_pk_bf16_f32 %0, %1, %2" : "=v"(r) : "v"(lo), "v"(hi));
  return r;
}
// async global->LDS, 16B per lane; lds ptr must be wave-uniform base (+lane*16 implicit)
__device__ __forceinline__ void gl16(const u16* g, u16* l) {
  __builtin_amdgcn_global_load_lds((__attribute__((address_space(1))) void*)(g),
                                   (__attribute__((address_space(3))) void*)(l), 16, 0, 0);
}
__device__ __forceinline__ void vmw8() { asm volatile("s_waitcnt vmcnt(8)" ::: "memory"); }
__device__ __forceinline__ void vmw0() { asm volatile("s_waitcnt vmcnt(0)" ::: "memory"); }
__device__ __forceinline__ void lgw0() { asm volatile("s_waitcnt lgkmcnt(0)" ::: "memory"); }

// head-major qkv layout (u16 units): win*393216 + type*131072 + h*16384 + r*64 + d
// head-major aout layout:            win*131072 + h*16384 + r*64 + d

// ---------------------------------------------------------------- score
__global__ void k_score(const float* __restrict__ prob, const float* __restrict__ wfix,
                        float* __restrict__ scores) {
  const int b = blockIdx.x, tid = threadIdx.x;
  __shared__ float ent[64 * 64];
  __shared__ float wf[64];
  if (tid < 64) wf[tid] = wfix[tid];
  const float* pb = prob + (size_t)b * 4 * 4096;
  for (int p = tid; p < 4096; p += 256) {
    float e = 0.f;
#pragma unroll
    for (int ch = 0; ch < 4; ++ch) {
      float v = pb[ch * 4096 + p];
      e -= v * log2f(v + 1e-10f);
    }
    ent[p] = e;
  }
  __syncthreads();
  if (tid < 225) {
    int wy = tid / 15, wx = tid % 15;
    float s = 0.f;
    for (int a = 0; a < 8; ++a)
      for (int c = 0; c < 8; ++c)
        s += ent[(wy * 4 + a) * 64 + wx * 4 + c] * wf[a * 8 + c];
    scores[b * 225 + tid] = s * (1.0f / 64.0f);
  }
}

// ---------------------------------------------------------------- nms
__device__ __forceinline__ float iou_pair(int wa, int wb) {
  float x1a = (float)((wa % 15) * 8), y1a = (float)((wa / 15) * 8);
  float x1b = (float)((wb % 15) * 8), y1b = (float)((wb / 15) * 8);
  float iw = fminf(x1a, x1b) + 15.f - fmaxf(x1a, x1b);
  float ih = fminf(y1a, y1b) + 15.f - fmaxf(y1a, y1b);
  iw = fmaxf(iw, 0.f);
  ih = fmaxf(ih, 0.f);
  float inter = iw * ih;
  return inter / (450.f - inter);
}

__global__ void k_nms(const float* __restrict__ scores, int* __restrict__ sel,
                      int* __restrict__ kept, float* __restrict__ mult) {
  const int b = blockIdx.x, t = threadIdx.x;
  __shared__ float s[225];
  __shared__ int order[225];
  __shared__ unsigned char supp[225];
  __shared__ int idx44[44];
  __shared__ int ks[225];
  __shared__ float ml[225];
  if (t < 225) s[t] = scores[b * 225 + t];
  __syncthreads();
  if (t < 225) {
    float st = s[t];
    int r = 0;
    for (int j = 0; j < 225; ++j) {
      float sj = s[j];
      r += (sj > st) || (sj == st && j < t);
    }
    order[r] = t;
    supp[t] = 0;
    ks[t] = -1;
    ml[t] = 0.f;
  }
  __syncthreads();
  for (int i = 0; i < 224; ++i) {
    if (t > i && t < 225 && !supp[i]) {
      if (iou_pair(order[i], order[t]) > 0.2f) supp[t] = 1;
    }
    __syncthreads();
  }
  if (t == 0) {
    int k = 0;
    for (int i = 0; i < 225 && k < 44; ++i)
      if (!supp[i]) idx44[k++] = order[i];
    while (k < 44) idx44[k++] = order[224];
    for (int k2 = 0; k2 < 44; ++k2) {
      int w = idx44[k2];
      if (ks[w] < 0) ks[w] = k2;
      ml[w] += 1.f;
    }
  }
  __syncthreads();
  if (t < 225) {
    kept[b * 225 + t] = ks[t];
    mult[b * 225 + t] = ml[t];
  }
  if (t < 44) sel[b * 44 + t] = idx44[t];
}

// ---------------------------------------------------------------- weight cast
__global__ void k_castw(const float* __restrict__ Wq, const float* __restrict__ Wo,
                        u16* __restrict__ wqb, u16* __restrict__ wob) {
  int idx = blockIdx.x * 256 + threadIdx.x;
  if (idx < 786432) wqb[idx] = f2bf(Wq[idx]);
  int i2 = idx - 786432;
  if (i2 >= 0 && i2 < 262144) wob[i2] = f2bf(Wo[i2]);
}

// ---------------------------------------------------------------- gather + bilinear (direct 4-tap)
__global__ __launch_bounds__(256) void k_gather(const float* __restrict__ x,
                                                const int* __restrict__ sel,
                                                u16* __restrict__ xi) {
  const size_t idx = (size_t)blockIdx.x * 256 + threadIdx.x;
  const int dc = (int)(idx & 63);
  const int pq = (int)((idx >> 6) & 255);
  const int g = (int)(idx >> 14);
  const int b = g / 44;
  const int w = sel[g];
  const int sy = (w / 15) * 8, sx = (w % 15) * 8;
  const int p = pq >> 4, q = pq & 15;
  float rp = ((float)p + 0.5f) * 0.9375f;
  int i0 = (int)rp;
  float fp = rp - (float)i0;
  float rq = ((float)q + 0.5f) * 0.9375f;
  int j0 = (int)rq;
  float fq = rq - (float)j0;
  const float w00 = (1.f - fp) * (1.f - fq), w01 = (1.f - fp) * fq;
  const float w10 = fp * (1.f - fq), w11 = fp * fq;
  const float* xb = x + ((size_t)b * 16384 + (size_t)(sy + i0) * 128 + sx + j0) * 512 + dc * 8;
  const float4* t00 = (const float4*)xb;
  const float4* t01 = (const float4*)(xb + 512);
  const float4* t10 = (const float4*)(xb + 512 * 128);
  const float4* t11 = (const float4*)(xb + 512 * 129);
  float acc[8];
#pragma unroll
  for (int h = 0; h < 2; ++h) {
    float4 a = t00[h], bb = t01[h], c = t10[h], d = t11[h];
    acc[h * 4 + 0] = w00 * a.x + w01 * bb.x + w10 * c.x + w11 * d.x;
    acc[h * 4 + 1] = w00 * a.y + w01 * bb.y + w10 * c.y + w11 * d.y;
    acc[h * 4 + 2] = w00 * a.z + w01 * bb.z + w10 * c.z + w11 * d.z;
    acc[h * 4 + 3] = w00 * a.w + w01 * bb.w + w10 * c.w + w11 * d.w;
  }
  short8 o;
#pragma unroll
  for (int e = 0; e < 8; ++e) o[e] = (short)f2bf(acc[e]);
  *(short8*)&xi[((size_t)g * 256 + pq) * 512 + dc * 8] = o;
}

// ---------------------------------------------------------------- GEMM 128x128, BK=64, 4 waves
// Counted-vmcnt dbuf + T2 XOR swizzle; 2 blocks/CU.
// OPERM: C written head-major qkv' layout. APERM: A read head-major aout' layout (BK==64==Dh).
template <int BIAS, int OPERM, int APERM>
__global__ __launch_bounds__(256, 2) void k_gemm128(const u16* __restrict__ A,
                                                    const u16* __restrict__ B, u16* __restrict__ C,
                                                    const float* __restrict__ bias, int M, int N,
                                                    int K, int nbn) {
  __shared__ u16 sA[2][128 * 64];
  __shared__ u16 sB[2][128 * 64];
  const int tid = threadIdx.x, lane = tid & 63, wv = tid >> 6;
  const int f = blockIdx.x;
  const int q8 = gridDim.x >> 3;
  const int wg = (f & 7) * q8 + (f >> 3);  // bijective XCD swizzle (nwg % 8 == 0)
  const int bm = wg / nbn, bn = wg % nbn;
  const int wm = (wv >> 1) * 64, wn = (wv & 1) * 64;
  const int l15 = lane & 15, k8 = (lane >> 4) * 8;
  const int xorv = (l15 & 7) * 8;  // read-side swizzle (elements)
  const int srow = tid >> 3;                     // 0..31 (rows within 32-row chunk)
  const int sc8 = ((tid ^ (tid >> 3)) & 7) * 8;  // pre-swizzled source col
  const int arow0 = bm * 128 + srow, brow0 = bn * 128 + srow;

  f32x4 acc[4][4] = {};

  // STAGE tile kt into buf: 8 gl16 (4 chunks x A,B), 32 rows per chunk
#define STAGE(kt, buf)                                                                          \
  {                                                                                             \
    _Pragma("unroll") for (int c = 0; c < 4; ++c) {                                             \
      const int ar = arow0 + c * 32;                                                            \
      size_t aoffs = APERM ? ((size_t)(ar >> 8) * 131072 + (size_t)(kt) * 16384 +               \
                              (size_t)(ar & 255) * 64 + sc8)                                    \
                           : ((size_t)ar * K + (kt) * 64 + sc8);                                \
      gl16(A + aoffs, &sA[buf][c * 2048 + wv * 512]);                                           \
      gl16(B + (size_t)(brow0 + c * 32) * K + (kt) * 64 + sc8, &sB[buf][c * 2048 + wv * 512]); \
    }                                                                                           \
  }

  STAGE(0, 0);
  STAGE(1, 1);

  for (int t = 0; t < 8; ++t) {
    const int buf = t & 1;
    if (t == 7)
      vmw0();
    else
      vmw8();  // counted: next tile's 8 loads stay in flight
    __builtin_amdgcn_sched_barrier(0);
    __builtin_amdgcn_s_barrier();  // tile t resident for all waves
    frag8 af[4][2], bf[4][2];
#pragma unroll
    for (int i = 0; i < 4; ++i)
#pragma unroll
      for (int kk = 0; kk < 2; ++kk) {
        af[i][kk] = *(const frag8*)&sA[buf][(wm + i * 16 + l15) * 64 + ((kk * 32 + k8) ^ xorv)];
        bf[i][kk] = *(const frag8*)&sB[buf][(wn + i * 16 + l15) * 64 + ((kk * 32 + k8) ^ xorv)];
      }
    __builtin_amdgcn_s_setprio(1);
#pragma unroll
    for (int i = 0; i < 4; ++i)
#pragma unroll
      for (int j = 0; j < 4; ++j)
#pragma unroll
        for (int kk = 0; kk < 2; ++kk)
          acc[i][j] = MFMA16(af[i][kk], bf[j][kk], acc[i][j]);
    __builtin_amdgcn_s_setprio(0);
    lgw0();  // this wave's ds_reads fully retired before buf can be overwritten
    __builtin_amdgcn_sched_barrier(0);
    __builtin_amdgcn_s_barrier();  // all waves done reading buf
    if (t < 6) STAGE(t + 2, buf);  // issued here: flies under next tile's compute
  }
#undef STAGE

  const int cc = lane & 15, rr = (lane >> 4) * 4;
#pragma unroll
  for (int i = 0; i < 4; ++i)
#pragma unroll
    for (int j = 0; j < 4; ++j) {
      int col = bn * 128 + wn + j * 16 + cc;
      float badd = BIAS ? bias[col] : 0.f;
#pragma unroll
      for (int e = 0; e < 4; ++e) {
        int row = bm * 128 + wm + i * 16 + rr + e;
        if (OPERM) {
          size_t caddr = (size_t)(row >> 8) * 393216 + (size_t)(col >> 9) * 131072 +
                         (size_t)((col >> 6) & 7) * 16384 + (size_t)(row & 255) * 64 + (col & 63);
          C[caddr] = f2bf(acc[i][j][e] + badd);
        } else {
          C[(size_t)row * N + col] = f2bf(acc[i][j][e] + badd);
        }
      }
    }
}

// ---------------------------------------------------------------- attention (swapped 32x32)
// grid 5632: 2 blocks per (win,head), each 128 q-rows; wave owns ONE 32-row q-tile.
// acc footprint halves (of[2]=32 AGPR) -> peak live ~115 regs fits (256,4): 16 waves/CU.
// K AND V double-buffered per 64-key block; head-major layout (contiguous K/V/Q slices).
__global__ __launch_bounds__(256, 4) void k_attn(const u16* __restrict__ qkv,
                                                 u16* __restrict__ aout) {
  const int g = blockIdx.x;
  const int win = g % 352;
  const int hq = g / 352;           // 0..15
  const int h = hq & 7, qh = hq >> 3;
  const int tid = threadIdx.x, lane = tid & 63, wv = tid >> 6;
  const int l31 = lane & 31, l5 = lane >> 5;
  __shared__ u16 smem[17664];  // Kb[2][64][68] (8704 u16) | Vt[2][64][70] (8960 u16)
  u16* KbB = smem;
  u16* VtB = smem + 8704;
  const u16* qbase = qkv + (size_t)win * 393216 + (size_t)h * 16384;
  const u16* kbase = qbase + 131072;
  const u16* vbase = qbase + 262144;
  const int prow = tid >> 2, pc16 = (tid & 3) * 16;
  const int qrow0 = qh * 128 + wv * 32;

  // Q B-frags (single 32-row tile per wave)
  frag8 qf[4];
#pragma unroll
  for (int c = 0; c < 4; ++c)
    qf[c] = *(const frag8*)(qbase + (size_t)(qrow0 + l31) * 64 + c * 16 + l5 * 8);
  // K block 0 + V block 0 (thread: key=prow, d-range pc16..pc16+15)
  {
    const u16* kp = kbase + (size_t)prow * 64 + pc16;
    short8 ka = *(const short8*)kp;
    short8 kb2 = *(const short8*)(kp + 8);
    const u16* vp = vbase + (size_t)prow * 64 + pc16;
    short8 va = *(const short8*)vp;
    short8 vb2 = *(const short8*)(vp + 8);
    *(short8*)&KbB[prow * 68 + pc16] = ka;
    *(short8*)&KbB[prow * 68 + pc16 + 8] = kb2;
#pragma unroll
    for (int e = 0; e < 8; ++e) {
      VtB[(pc16 + e) * 70 + prow] = (u16)va[e];
      VtB[(pc16 + 8 + e) * 70 + prow] = (u16)vb2[e];
    }
  }
  __syncthreads();

  f32x16 of[2] = {};
  float m_run = -3e38f;
  float l_run = 0.f;

  int cur = 0;
  for (int kb = 0; kb < 4; ++kb) {
    short8 pk0 = {}, pk1 = {}, pv0 = {}, pv1 = {};
    if (kb < 3) {
      const u16* kp = kbase + (size_t)((kb + 1) * 64 + prow) * 64 + pc16;
      pk0 = *(const short8*)kp;
      pk1 = *(const short8*)(kp + 8);
      const u16* vp = vbase + (size_t)((kb + 1) * 64 + prow) * 64 + pc16;
      pv0 = *(const short8*)vp;
      pv1 = *(const short8*)(vp + 8);
    }
    f32x16 s0 = {}, s1 = {};
#pragma unroll
    for (int c = 0; c < 4; ++c) {
      frag8 kf0 = *(const frag8*)&KbB[cur * 4352 + l31 * 68 + c * 16 + l5 * 8];
      frag8 kf1 = *(const frag8*)&KbB[cur * 4352 + (32 + l31) * 68 + c * 16 + l5 * 8];
      s0 = MFMA32(kf0, qf[c], s0);
      s1 = MFMA32(kf1, qf[c], s1);
    }
    float tm[16];
#pragma unroll
    for (int r = 0; r < 16; ++r) tm[r] = fmaxf(s0[r], s1[r]);
#pragma unroll
    for (int r = 0; r < 8; ++r) tm[r] = fmaxf(tm[r], tm[r + 8]);
#pragma unroll
    for (int r = 0; r < 4; ++r) tm[r] = fmaxf(tm[r], tm[r + 4]);
    float pm = fmaxf(fmaxf(tm[0], tm[1]), fmaxf(tm[2], tm[3]));
    pm = fmaxf(pm, __shfl_xor(pm, 32));
    if (!__all(pm <= m_run + 64.f)) {  // defer-max (thr 8 post-scale)
      float mn = fmaxf(m_run, pm);
      float corr = __expf((m_run - mn) * 0.125f);
      l_run *= corr;
#pragma unroll
      for (int dt = 0; dt < 2; ++dt)
#pragma unroll
        for (int r = 0; r < 16; ++r) of[dt][r] *= corr;
      m_run = mn;
    }
    const float mqt = m_run;
    float ls = 0.f;
#pragma unroll
    for (int kt = 0; kt < 2; ++kt) {
      const f32x16 sv = kt ? s1 : s0;
      float p[16];
#pragma unroll
      for (int r = 0; r < 16; ++r) p[r] = __expf((sv[r] - mqt) * 0.125f);
      float e0 = (p[0] + p[1]) + (p[2] + p[3]);
      float e1 = (p[4] + p[5]) + (p[6] + p[7]);
      float e2 = (p[8] + p[9]) + (p[10] + p[11]);
      float e3 = (p[12] + p[13]) + (p[14] + p[15]);
      ls += (e0 + e1) + (e2 + e3);
#pragma unroll
      for (int cc = 0; cc < 2; ++cc) {
        const int bx = cc * 8;
        unsigned a0 = cvtpk_bf16(p[bx + 0], p[bx + 1]);
        unsigned a1 = cvtpk_bf16(p[bx + 2], p[bx + 3]);
        unsigned b0 = cvtpk_bf16(p[bx + 4], p[bx + 5]);
        unsigned b1 = cvtpk_bf16(p[bx + 6], p[bx + 7]);
        // cross-half exchange: D_new={D.lo,S.lo}, S_new={D.hi,S.hi}
        asm("v_permlane32_swap_b32 %0, %1" : "+v"(a0), "+v"(b0));
        asm("v_permlane32_swap_b32 %0, %1" : "+v"(a1), "+v"(b1));
        uint4 fu;
        fu.x = a0;
        fu.y = a1;
        fu.z = b0;
        fu.w = b1;
        frag8 pb = __builtin_bit_cast(frag8, fu);
#pragma unroll
        for (int dt = 0; dt < 2; ++dt) {
          frag8 va = *(const frag8*)&VtB[cur * 4480 + (dt * 32 + l31) * 70 + kt * 32 + cc * 16 +
                                         l5 * 8];
          of[dt] = MFMA32(va, pb, of[dt]);
        }
      }
    }
    l_run += ls;
    if (kb < 3) {
      *(short8*)&KbB[(cur ^ 1) * 4352 + prow * 68 + pc16] = pk0;
      *(short8*)&KbB[(cur ^ 1) * 4352 + prow * 68 + pc16 + 8] = pk1;
      u16* vd = &VtB[(cur ^ 1) * 4480 + prow];
#pragma unroll
      for (int e = 0; e < 8; ++e) {
        vd[(pc16 + e) * 70] = (u16)pv0[e];
        vd[(pc16 + 8 + e) * 70] = (u16)pv1[e];
      }
    }
    __syncthreads();
    cur ^= 1;
  }

  float lt = l_run + __shfl_xor(l_run, 32);
  float inv = 1.0f / lt;
  u16* sc = smem + wv * 2176;  // per-wave [32][68] scratch (reuses K/V LDS)
  __syncthreads();
#pragma unroll
  for (int dt = 0; dt < 2; ++dt)
#pragma unroll
    for (int j = 0; j < 4; ++j) {
      unsigned w0 = cvtpk_bf16(of[dt][4 * j + 0] * inv, of[dt][4 * j + 1] * inv);
      unsigned w1 = cvtpk_bf16(of[dt][4 * j + 2] * inv, of[dt][4 * j + 3] * inv);
      *(uint2*)&sc[l31 * 68 + dt * 32 + 8 * j + 4 * l5] = make_uint2(w0, w1);
    }
  asm volatile("" ::: "memory");
  // head-major aout': contiguous 1KB per rep instr
  u16* obase = aout + (size_t)win * 131072 + (size_t)h * 16384 + (size_t)qrow0 * 64;
#pragma unroll
  for (int rep = 0; rep < 4; ++rep) {
    int row = rep * 8 + (lane >> 3);
    uint2 lo = *(const uint2*)&sc[row * 68 + (lane & 7) * 8];
    uint2 hi = *(const uint2*)&sc[row * 68 + (lane & 7) * 8 + 4];
    *(int4*)&obase[(size_t)row * 64 + (lane & 7) * 8] =
        make_int4((int)lo.x, (int)lo.y, (int)hi.x, (int)hi.y);
  }
}

// ---------------------------------------------------------------- finalize
__global__ void k_final(const float* __restrict__ x, const u16* __restrict__ proj,
                        const int* __restrict__ kept, const float* __restrict__ mult,
                        float* __restrict__ out) {
  const size_t idx = (size_t)blockIdx.x * 256 + threadIdx.x;
  const int dci = (int)(idx & 31);
  const int pix = (int)((idx >> 5) & 16383);
  const int b = (int)(idx >> 19);
  const int y = pix >> 7, xc = pix & 127;
  float acc[16];
#pragma unroll
  for (int e = 0; e < 16; ++e) acc[e] = 0.f;
  float c = 0.f;
  const int wyh = y >> 3, wxh = xc >> 3;
#pragma unroll
  for (int a = 0; a < 2; ++a) {
    int wy = wyh - 1 + a;
    if (wy < 0 || wy > 14) continue;
#pragma unroll
    for (int bb = 0; bb < 2; ++bb) {
      int wx = wxh - 1 + bb;
      if (wx < 0 || wx > 14) continue;
      int w = wy * 15 + wx;
      int slot = kept[b * 225 + w];
      if (slot < 0) continue;
      float ml = mult[b * 225 + w];
      c += ml;
      const u16* pr = proj +
                      ((size_t)((b * 44 + slot) * 256 + (y - wy * 8) * 16 + (xc - wx * 8))) * 512 +
                      (size_t)dci * 16;
      short8 v0 = *(const short8*)pr;
      short8 v1 = *(const short8*)(pr + 8);
#pragma unroll
      for (int e = 0; e < 8; ++e) acc[e] += ml * bf2f((u16)v0[e]);
#pragma unroll
      for (int e = 0; e < 8; ++e) acc[8 + e] += ml * bf2f((u16)v1[e]);
    }
  }
  const float inv = 1.f / (c + 1e-10f);
  const size_t off = ((size_t)(b * 16384 + pix)) * 512 + (size_t)dci * 16;
  const float4* xp = (const float4*)(x + off);
  float4* op = (float4*)(out + off);
#pragma unroll
  for (int q4 = 0; q4 < 4; ++q4) {
    float4 xv = xp[q4];
    float4 ov;
    ov.x = xv.x + acc[q4 * 4 + 0] * inv;
    ov.y = xv.y + acc[q4 * 4 + 1] * inv;
    ov.z = xv.z + acc[q4 * 4 + 2] * inv;
    ov.w = xv.w + acc[q4 * 4 + 3] * inv;
    op[q4] = ov;
  }
}

// ---------------------------------------------------------------- launch
extern "C" void kernel_launch(void* const* d_in, const int* in_sizes, int n_in, void* d_out,
                              int out_size, void* d_ws, size_t ws_size, hipStream_t stream) {
  const float* x = (const float*)d_in[0];
  const float* prob = (const float*)d_in[1];
  const float* wfix = (const float*)d_in[2];
  const float* Wq = (const float*)d_in[3];
  const float* Wo = (const float*)d_in[4];
  const float* bo = (const float*)d_in[5];
  float* out = (float*)d_out;
  char* ws = (char*)d_ws;

  float* scores = (float*)(ws + 0);
  int* sel = (int*)(ws + 8192);
  int* kept = (int*)(ws + 16384);
  float* mult = (float*)(ws + 24576);
  u16* wqb = (u16*)(ws + 32768);
  u16* wob = (u16*)(ws + 32768 + 1572864);
  u16* xi = (u16*)(ws + 4194304);
  u16* qkv = (u16*)(ws + 4194304 + 92274688);
  u16* aout = xi;   // head-major aout' reuses xi buffer
  u16* proj = qkv;  // proj output reuses qkv buffer

  k_score<<<8, 256, 0, stream>>>(prob, wfix, scores);
  k_nms<<<8, 256, 0, stream>>>(scores, sel, kept, mult);
  k_castw<<<4096, 256, 0, stream>>>(Wq, Wo, wqb, wob);
  k_gather<<<22528, 256, 0, stream>>>(x, sel, xi);
  k_gemm128<0, 1, 0><<<8448, 256, 0, stream>>>(xi, wqb, qkv, nullptr, 90112, 1536, 512, 12);
  k_attn<<<5632, 256, 0, stream>>>(qkv, aout);
  k_gemm128<1, 0, 1><<<2816, 256, 0, stream>>>(aout, wob, proj, bo, 90112, 512, 512, 4);
  k_final<<<16384, 256, 0, stream>>>(x, proj, kept, mult, out);
}

// Round 15
// 713.795 us; speedup vs baseline: 1.4689x; 1.0401x over previous
//
#include <hip/hip_runtime.h>
#include <type_traits>
#include <utility>

typedef unsigned short u16;
typedef __attribute__((ext_vector_type(8))) short short8;
typedef __attribute__((ext_vector_type(8))) __bf16 bf16v8;
typedef __attribute__((ext_vector_type(4))) float f32x4;
typedef __attribute__((ext_vector_type(16))) float f32x16;

template <typename T, typename = void> struct mfma_ok : std::false_type {};
template <typename T>
struct mfma_ok<T, std::void_t<decltype(__builtin_amdgcn_mfma_f32_16x16x32_bf16(
    std::declval<T>(), std::declval<T>(), std::declval<f32x4>(), 0, 0, 0))>>
    : std::true_type {};
using frag8 = std::conditional_t<mfma_ok<bf16v8>::value, bf16v8, short8>;

#define MFMA16(a, b, c) __builtin_amdgcn_mfma_f32_16x16x32_bf16((a), (b), (c), 0, 0, 0)
#define MFMA32(a, b, c) __builtin_amdgcn_mfma_f32_32x32x16_bf16((a), (b), (c), 0, 0, 0)

__device__ __forceinline__ float bf2f(u16 u) {
  unsigned v = ((unsigned)u) << 16;
  return __builtin_bit_cast(float, v);
}
__device__ __forceinline__ u16 f2bf(float f) {
  unsigned u = __builtin_bit_cast(unsigned, f);
  u = (u + 0x7fffu + ((u >> 16) & 1u)) >> 16;
  return (u16)u;
}
__device__ __forceinline__ unsigned cvtpk_bf16(float lo, float hi) {
  unsigned r;
  asm("v_cvt_pk_bf16_f32 %0, %1, %2" : "=v"(r) : "v"(lo), "v"(hi));
  return r;
}
// async global->LDS, 16B per lane; lds ptr must be wave-uniform base (+lane*16 implicit)
__device__ __forceinline__ void gl16(const u16* g, u16* l) {
  __builtin_amdgcn_global_load_lds((__attribute__((address_space(1))) void*)(g),
                                   (__attribute__((address_space(3))) void*)(l), 16, 0, 0);
}
__device__ __forceinline__ void vmw8() { asm volatile("s_waitcnt vmcnt(8)" ::: "memory"); }
__device__ __forceinline__ void vmw0() { asm volatile("s_waitcnt vmcnt(0)" ::: "memory"); }
__device__ __forceinline__ void lgw0() { asm volatile("s_waitcnt lgkmcnt(0)" ::: "memory"); }

// head-major qkv layout (u16 units): win*393216 + type*131072 + h*16384 + r*64 + d
// head-major aout layout:            win*131072 + h*16384 + r*64 + d

// ---------------------------------------------------------------- score
__global__ void k_score(const float* __restrict__ prob, const float* __restrict__ wfix,
                        float* __restrict__ scores) {
  const int b = blockIdx.x, tid = threadIdx.x;
  __shared__ float ent[64 * 64];
  __shared__ float wf[64];
  if (tid < 64) wf[tid] = wfix[tid];
  const float* pb = prob + (size_t)b * 4 * 4096;
  for (int p = tid; p < 4096; p += 256) {
    float e = 0.f;
#pragma unroll
    for (int ch = 0; ch < 4; ++ch) {
      float v = pb[ch * 4096 + p];
      e -= v * log2f(v + 1e-10f);
    }
    ent[p] = e;
  }
  __syncthreads();
  if (tid < 225) {
    int wy = tid / 15, wx = tid % 15;
    float s = 0.f;
    for (int a = 0; a < 8; ++a)
      for (int c = 0; c < 8; ++c)
        s += ent[(wy * 4 + a) * 64 + wx * 4 + c] * wf[a * 8 + c];
    scores[b * 225 + tid] = s * (1.0f / 64.0f);
  }
}

// ---------------------------------------------------------------- nms
__device__ __forceinline__ float iou_pair(int wa, int wb) {
  float x1a = (float)((wa % 15) * 8), y1a = (float)((wa / 15) * 8);
  float x1b = (float)((wb % 15) * 8), y1b = (float)((wb / 15) * 8);
  float iw = fminf(x1a, x1b) + 15.f - fmaxf(x1a, x1b);
  float ih = fminf(y1a, y1b) + 15.f - fmaxf(y1a, y1b);
  iw = fmaxf(iw, 0.f);
  ih = fmaxf(ih, 0.f);
  float inter = iw * ih;
  return inter / (450.f - inter);
}

__global__ void k_nms(const float* __restrict__ scores, int* __restrict__ sel,
                      int* __restrict__ kept, float* __restrict__ mult) {
  const int b = blockIdx.x, t = threadIdx.x;
  __shared__ float s[225];
  __shared__ int order[225];
  __shared__ unsigned char supp[225];
  __shared__ int idx44[44];
  __shared__ int ks[225];
  __shared__ float ml[225];
  if (t < 225) s[t] = scores[b * 225 + t];
  __syncthreads();
  if (t < 225) {
    float st = s[t];
    int r = 0;
    for (int j = 0; j < 225; ++j) {
      float sj = s[j];
      r += (sj > st) || (sj == st && j < t);
    }
    order[r] = t;
    supp[t] = 0;
    ks[t] = -1;
    ml[t] = 0.f;
  }
  __syncthreads();
  for (int i = 0; i < 224; ++i) {
    if (t > i && t < 225 && !supp[i]) {
      if (iou_pair(order[i], order[t]) > 0.2f) supp[t] = 1;
    }
    __syncthreads();
  }
  if (t == 0) {
    int k = 0;
    for (int i = 0; i < 225 && k < 44; ++i)
      if (!supp[i]) idx44[k++] = order[i];
    while (k < 44) idx44[k++] = order[224];
    for (int k2 = 0; k2 < 44; ++k2) {
      int w = idx44[k2];
      if (ks[w] < 0) ks[w] = k2;
      ml[w] += 1.f;
    }
  }
  __syncthreads();
  if (t < 225) {
    kept[b * 225 + t] = ks[t];
    mult[b * 225 + t] = ml[t];
  }
  if (t < 44) sel[b * 44 + t] = idx44[t];
}

// ---------------------------------------------------------------- weight cast
__global__ void k_castw(const float* __restrict__ Wq, const float* __restrict__ Wo,
                        u16* __restrict__ wqb, u16* __restrict__ wob) {
  int idx = blockIdx.x * 256 + threadIdx.x;
  if (idx < 786432) wqb[idx] = f2bf(Wq[idx]);
  int i2 = idx - 786432;
  if (i2 >= 0 && i2 < 262144) wob[i2] = f2bf(Wo[i2]);
}

// ---------------------------------------------------------------- gather + bilinear (direct 4-tap)
__global__ __launch_bounds__(256) void k_gather(const float* __restrict__ x,
                                                const int* __restrict__ sel,
                                                u16* __restrict__ xi) {
  const size_t idx = (size_t)blockIdx.x * 256 + threadIdx.x;
  const int dc = (int)(idx & 63);
  const int pq = (int)((idx >> 6) & 255);
  const int g = (int)(idx >> 14);
  const int b = g / 44;
  const int w = sel[g];
  const int sy = (w / 15) * 8, sx = (w % 15) * 8;
  const int p = pq >> 4, q = pq & 15;
  float rp = ((float)p + 0.5f) * 0.9375f;
  int i0 = (int)rp;
  float fp = rp - (float)i0;
  float rq = ((float)q + 0.5f) * 0.9375f;
  int j0 = (int)rq;
  float fq = rq - (float)j0;
  const float w00 = (1.f - fp) * (1.f - fq), w01 = (1.f - fp) * fq;
  const float w10 = fp * (1.f - fq), w11 = fp * fq;
  const float* xb = x + ((size_t)b * 16384 + (size_t)(sy + i0) * 128 + sx + j0) * 512 + dc * 8;
  const float4* t00 = (const float4*)xb;
  const float4* t01 = (const float4*)(xb + 512);
  const float4* t10 = (const float4*)(xb + 512 * 128);
  const float4* t11 = (const float4*)(xb + 512 * 129);
  float acc[8];
#pragma unroll
  for (int h = 0; h < 2; ++h) {
    float4 a = t00[h], bb = t01[h], c = t10[h], d = t11[h];
    acc[h * 4 + 0] = w00 * a.x + w01 * bb.x + w10 * c.x + w11 * d.x;
    acc[h * 4 + 1] = w00 * a.y + w01 * bb.y + w10 * c.y + w11 * d.y;
    acc[h * 4 + 2] = w00 * a.z + w01 * bb.z + w10 * c.z + w11 * d.z;
    acc[h * 4 + 3] = w00 * a.w + w01 * bb.w + w10 * c.w + w11 * d.w;
  }
  short8 o;
#pragma unroll
  for (int e = 0; e < 8; ++e) o[e] = (short)f2bf(acc[e]);
  *(short8*)&xi[((size_t)g * 256 + pq) * 512 + dc * 8] = o;
}

// ---------------------------------------------------------------- GEMM 128x128, BK=64, 4 waves
// Counted-vmcnt dbuf + T2 XOR swizzle; 2 blocks/CU. Epilogue packs C through LDS -> 8x 1KB
// contiguous dwordx4 stores per wave (replaces 64 scattered 2B stores — the K=512 epilogue tax).
template <int BIAS, int OPERM, int APERM>
__global__ __launch_bounds__(256, 2) void k_gemm128(const u16* __restrict__ A,
                                                    const u16* __restrict__ B, u16* __restrict__ C,
                                                    const float* __restrict__ bias, int M, int N,
                                                    int K, int nbn) {
  __shared__ u16 smem[32768];  // sA = smem[0..16383], sB = smem[16384..32767]; reused by epilogue
  u16* sA = smem;
  u16* sB = smem + 16384;
  const int tid = threadIdx.x, lane = tid & 63, wv = tid >> 6;
  const int f = blockIdx.x;
  const int q8 = gridDim.x >> 3;
  const int wg = (f & 7) * q8 + (f >> 3);  // bijective XCD swizzle (nwg % 8 == 0)
  const int bm = wg / nbn, bn = wg % nbn;
  const int wm = (wv >> 1) * 64, wn = (wv & 1) * 64;
  const int l15 = lane & 15, k8 = (lane >> 4) * 8;
  const int xorv = (l15 & 7) * 8;  // read-side swizzle (elements)
  const int srow = tid >> 3;                     // 0..31 (rows within 32-row chunk)
  const int sc8 = ((tid ^ (tid >> 3)) & 7) * 8;  // pre-swizzled source col
  const int arow0 = bm * 128 + srow, brow0 = bn * 128 + srow;

  f32x4 acc[4][4] = {};

  // STAGE tile kt into buf: 8 gl16 (4 chunks x A,B), 32 rows per chunk
#define STAGE(kt, buf)                                                                      \
  {                                                                                         \
    _Pragma("unroll") for (int c = 0; c < 4; ++c) {                                         \
      const int ar = arow0 + c * 32;                                                        \
      size_t aoffs = APERM ? ((size_t)(ar >> 8) * 131072 + (size_t)(kt) * 16384 +           \
                              (size_t)(ar & 255) * 64 + sc8)                                \
                           : ((size_t)ar * K + (kt) * 64 + sc8);                            \
      gl16(A + aoffs, &sA[(buf) * 8192 + c * 2048 + wv * 512]);                             \
      gl16(B + (size_t)(brow0 + c * 32) * K + (kt) * 64 + sc8,                              \
           &sB[(buf) * 8192 + c * 2048 + wv * 512]);                                        \
    }                                                                                       \
  }

  STAGE(0, 0);
  STAGE(1, 1);

  for (int t = 0; t < 8; ++t) {
    const int buf = t & 1;
    if (t == 7)
      vmw0();
    else
      vmw8();  // counted: next tile's 8 loads stay in flight
    __builtin_amdgcn_sched_barrier(0);
    __builtin_amdgcn_s_barrier();  // tile t resident for all waves
    frag8 af[4][2], bf[4][2];
#pragma unroll
    for (int i = 0; i < 4; ++i)
#pragma unroll
      for (int kk = 0; kk < 2; ++kk) {
        af[i][kk] =
            *(const frag8*)&sA[buf * 8192 + (wm + i * 16 + l15) * 64 + ((kk * 32 + k8) ^ xorv)];
        bf[i][kk] =
            *(const frag8*)&sB[buf * 8192 + (wn + i * 16 + l15) * 64 + ((kk * 32 + k8) ^ xorv)];
      }
    __builtin_amdgcn_s_setprio(1);
#pragma unroll
    for (int i = 0; i < 4; ++i)
#pragma unroll
      for (int j = 0; j < 4; ++j)
#pragma unroll
        for (int kk = 0; kk < 2; ++kk)
          acc[i][j] = MFMA16(af[i][kk], bf[j][kk], acc[i][j]);
    __builtin_amdgcn_s_setprio(0);
    lgw0();  // this wave's ds_reads fully retired before buf can be overwritten
    __builtin_amdgcn_sched_barrier(0);
    __builtin_amdgcn_s_barrier();  // all waves done reading buf
    if (t < 6) STAGE(t + 2, buf);  // issued here: flies under next tile's compute
  }
#undef STAGE

  // epilogue: pack through LDS (per-wave disjoint region), store contiguous 16B/lane.
  const int cc = lane & 15, rr = (lane >> 4) * 4;
  u16* sc = smem + wv * 4352;  // [64][68] per wave
#pragma unroll
  for (int i = 0; i < 4; ++i)
#pragma unroll
    for (int j = 0; j < 4; ++j) {
      int cloc = j * 16 + cc;
      float badd = BIAS ? bias[bn * 128 + wn + cloc] : 0.f;
#pragma unroll
      for (int e = 0; e < 4; ++e)
        sc[(i * 16 + rr + e) * 68 + cloc] = f2bf(acc[i][j][e] + badd);
    }
  asm volatile("" ::: "memory");  // in-wave LDS write->read ordering (compiler fence)
  const int row0 = bm * 128 + wm, col0 = bn * 128 + wn;
  u16* Cb;
  size_t rstride;
  if (OPERM) {
    Cb = C + (size_t)(row0 >> 8) * 393216 + (size_t)(col0 >> 9) * 131072 +
         (size_t)((col0 >> 6) & 7) * 16384 + (size_t)(row0 & 255) * 64;
    rstride = 64;
  } else {
    Cb = C + (size_t)row0 * N + col0;
    rstride = (size_t)N;
  }
#pragma unroll
  for (int rep = 0; rep < 8; ++rep) {
    int r = rep * 8 + (lane >> 3);
    int c8 = (lane & 7) * 8;
    uint2 lo = *(const uint2*)&sc[r * 68 + c8];
    uint2 hi = *(const uint2*)&sc[r * 68 + c8 + 4];
    *(int4*)&Cb[(size_t)r * rstride + c8] = make_int4((int)lo.x, (int)lo.y, (int)hi.x, (int)hi.y);
  }
}

// ---------------------------------------------------------------- attention (swapped 32x32)
// grid 5632: 2 blocks per (win,head), each 128 q-rows; wave owns ONE 32-row q-tile.
// K AND V double-buffered per 64-key block; head-major layout (contiguous K/V/Q slices).
__global__ __launch_bounds__(256, 4) void k_attn(const u16* __restrict__ qkv,
                                                 u16* __restrict__ aout) {
  const int g = blockIdx.x;
  const int win = g % 352;
  const int hq = g / 352;  // 0..15
  const int h = hq & 7, qh = hq >> 3;
  const int tid = threadIdx.x, lane = tid & 63, wv = tid >> 6;
  const int l31 = lane & 31, l5 = lane >> 5;
  __shared__ u16 smem[17664];  // Kb[2][64][68] (8704 u16) | Vt[2][64][70] (8960 u16)
  u16* KbB = smem;
  u16* VtB = smem + 8704;
  const u16* qbase = qkv + (size_t)win * 393216 + (size_t)h * 16384;
  const u16* kbase = qbase + 131072;
  const u16* vbase = qbase + 262144;
  const int prow = tid >> 2, pc16 = (tid & 3) * 16;
  const int qrow0 = qh * 128 + wv * 32;

  // Q B-frags (single 32-row tile per wave)
  frag8 qf[4];
#pragma unroll
  for (int c = 0; c < 4; ++c)
    qf[c] = *(const frag8*)(qbase + (size_t)(qrow0 + l31) * 64 + c * 16 + l5 * 8);
  // K block 0 + V block 0 (thread: key=prow, d-range pc16..pc16+15)
  {
    const u16* kp = kbase + (size_t)prow * 64 + pc16;
    short8 ka = *(const short8*)kp;
    short8 kb2 = *(const short8*)(kp + 8);
    const u16* vp = vbase + (size_t)prow * 64 + pc16;
    short8 va = *(const short8*)vp;
    short8 vb2 = *(const short8*)(vp + 8);
    *(short8*)&KbB[prow * 68 + pc16] = ka;
    *(short8*)&KbB[prow * 68 + pc16 + 8] = kb2;
#pragma unroll
    for (int e = 0; e < 8; ++e) {
      VtB[(pc16 + e) * 70 + prow] = (u16)va[e];
      VtB[(pc16 + 8 + e) * 70 + prow] = (u16)vb2[e];
    }
  }
  __syncthreads();

  f32x16 of[2] = {};
  float m_run = -3e38f;
  float l_run = 0.f;

  int cur = 0;
  for (int kb = 0; kb < 4; ++kb) {
    short8 pk0 = {}, pk1 = {}, pv0 = {}, pv1 = {};
    if (kb < 3) {
      const u16* kp = kbase + (size_t)((kb + 1) * 64 + prow) * 64 + pc16;
      pk0 = *(const short8*)kp;
      pk1 = *(const short8*)(kp + 8);
      const u16* vp = vbase + (size_t)((kb + 1) * 64 + prow) * 64 + pc16;
      pv0 = *(const short8*)vp;
      pv1 = *(const short8*)(vp + 8);
    }
    f32x16 s0 = {}, s1 = {};
#pragma unroll
    for (int c = 0; c < 4; ++c) {
      frag8 kf0 = *(const frag8*)&KbB[cur * 4352 + l31 * 68 + c * 16 + l5 * 8];
      frag8 kf1 = *(const frag8*)&KbB[cur * 4352 + (32 + l31) * 68 + c * 16 + l5 * 8];
      s0 = MFMA32(kf0, qf[c], s0);
      s1 = MFMA32(kf1, qf[c], s1);
    }
    float tm[16];
#pragma unroll
    for (int r = 0; r < 16; ++r) tm[r] = fmaxf(s0[r], s1[r]);
#pragma unroll
    for (int r = 0; r < 8; ++r) tm[r] = fmaxf(tm[r], tm[r + 8]);
#pragma unroll
    for (int r = 0; r < 4; ++r) tm[r] = fmaxf(tm[r], tm[r + 4]);
    float pm = fmaxf(fmaxf(tm[0], tm[1]), fmaxf(tm[2], tm[3]));
    pm = fmaxf(pm, __shfl_xor(pm, 32));
    if (!__all(pm <= m_run + 64.f)) {  // defer-max (thr 8 post-scale)
      float mn = fmaxf(m_run, pm);
      float corr = __expf((m_run - mn) * 0.125f);
      l_run *= corr;
#pragma unroll
      for (int dt = 0; dt < 2; ++dt)
#pragma unroll
        for (int r = 0; r < 16; ++r) of[dt][r] *= corr;
      m_run = mn;
    }
    const float mqt = m_run;
    float ls = 0.f;
#pragma unroll
    for (int kt = 0; kt < 2; ++kt) {
      const f32x16 sv = kt ? s1 : s0;
      float p[16];
#pragma unroll
      for (int r = 0; r < 16; ++r) p[r] = __expf((sv[r] - mqt) * 0.125f);
      float e0 = (p[0] + p[1]) + (p[2] + p[3]);
      float e1 = (p[4] + p[5]) + (p[6] + p[7]);
      float e2 = (p[8] + p[9]) + (p[10] + p[11]);
      float e3 = (p[12] + p[13]) + (p[14] + p[15]);
      ls += (e0 + e1) + (e2 + e3);
#pragma unroll
      for (int cc = 0; cc < 2; ++cc) {
        const int bx = cc * 8;
        unsigned a0 = cvtpk_bf16(p[bx + 0], p[bx + 1]);
        unsigned a1 = cvtpk_bf16(p[bx + 2], p[bx + 3]);
        unsigned b0 = cvtpk_bf16(p[bx + 4], p[bx + 5]);
        unsigned b1 = cvtpk_bf16(p[bx + 6], p[bx + 7]);
        // cross-half exchange: D_new={D.lo,S.lo}, S_new={D.hi,S.hi}
        asm("v_permlane32_swap_b32 %0, %1" : "+v"(a0), "+v"(b0));
        asm("v_permlane32_swap_b32 %0, %1" : "+v"(a1), "+v"(b1));
        uint4 fu;
        fu.x = a0;
        fu.y = a1;
        fu.z = b0;
        fu.w = b1;
        frag8 pb = __builtin_bit_cast(frag8, fu);
#pragma unroll
        for (int dt = 0; dt < 2; ++dt) {
          frag8 va = *(const frag8*)&VtB[cur * 4480 + (dt * 32 + l31) * 70 + kt * 32 + cc * 16 +
                                         l5 * 8];
          of[dt] = MFMA32(va, pb, of[dt]);
        }
      }
    }
    l_run += ls;
    if (kb < 3) {
      *(short8*)&KbB[(cur ^ 1) * 4352 + prow * 68 + pc16] = pk0;
      *(short8*)&KbB[(cur ^ 1) * 4352 + prow * 68 + pc16 + 8] = pk1;
      u16* vd = &VtB[(cur ^ 1) * 4480 + prow];
#pragma unroll
      for (int e = 0; e < 8; ++e) {
        vd[(pc16 + e) * 70] = (u16)pv0[e];
        vd[(pc16 + 8 + e) * 70] = (u16)pv1[e];
      }
    }
    __syncthreads();
    cur ^= 1;
  }

  float lt = l_run + __shfl_xor(l_run, 32);
  float inv = 1.0f / lt;
  u16* sc = smem + wv * 2176;  // per-wave [32][68] scratch (reuses K/V LDS)
  __syncthreads();
#pragma unroll
  for (int dt = 0; dt < 2; ++dt)
#pragma unroll
    for (int j = 0; j < 4; ++j) {
      unsigned w0 = cvtpk_bf16(of[dt][4 * j + 0] * inv, of[dt][4 * j + 1] * inv);
      unsigned w1 = cvtpk_bf16(of[dt][4 * j + 2] * inv, of[dt][4 * j + 3] * inv);
      *(uint2*)&sc[l31 * 68 + dt * 32 + 8 * j + 4 * l5] = make_uint2(w0, w1);
    }
  asm volatile("" ::: "memory");
  // head-major aout': contiguous 1KB per rep instr
  u16* obase = aout + (size_t)win * 131072 + (size_t)h * 16384 + (size_t)qrow0 * 64;
#pragma unroll
  for (int rep = 0; rep < 4; ++rep) {
    int row = rep * 8 + (lane >> 3);
    uint2 lo = *(const uint2*)&sc[row * 68 + (lane & 7) * 8];
    uint2 hi = *(const uint2*)&sc[row * 68 + (lane & 7) * 8 + 4];
    *(int4*)&obase[(size_t)row * 64 + (lane & 7) * 8] =
        make_int4((int)lo.x, (int)lo.y, (int)hi.x, (int)hi.y);
  }
}

// ---------------------------------------------------------------- finalize
__global__ void k_final(const float* __restrict__ x, const u16* __restrict__ proj,
                        const int* __restrict__ kept, const float* __restrict__ mult,
                        float* __restrict__ out) {
  const size_t idx = (size_t)blockIdx.x * 256 + threadIdx.x;
  const int dci = (int)(idx & 31);
  const int pix = (int)((idx >> 5) & 16383);
  const int b = (int)(idx >> 19);
  const int y = pix >> 7, xc = pix & 127;
  float acc[16];
#pragma unroll
  for (int e = 0; e < 16; ++e) acc[e] = 0.f;
  float c = 0.f;
  const int wyh = y >> 3, wxh = xc >> 3;
#pragma unroll
  for (int a = 0; a < 2; ++a) {
    int wy = wyh - 1 + a;
    if (wy < 0 || wy > 14) continue;
#pragma unroll
    for (int bb = 0; bb < 2; ++bb) {
      int wx = wxh - 1 + bb;
      if (wx < 0 || wx > 14) continue;
      int w = wy * 15 + wx;
      int slot = kept[b * 225 + w];
      if (slot < 0) continue;
      float ml = mult[b * 225 + w];
      c += ml;
      const u16* pr = proj +
                      ((size_t)((b * 44 + slot) * 256 + (y - wy * 8) * 16 + (xc - wx * 8))) * 512 +
                      (size_t)dci * 16;
      short8 v0 = *(const short8*)pr;
      short8 v1 = *(const short8*)(pr + 8);
#pragma unroll
      for (int e = 0; e < 8; ++e) acc[e] += ml * bf2f((u16)v0[e]);
#pragma unroll
      for (int e = 0; e < 8; ++e) acc[8 + e] += ml * bf2f((u16)v1[e]);
    }
  }
  const float inv = 1.f / (c + 1e-10f);
  const size_t off = ((size_t)(b * 16384 + pix)) * 512 + (size_t)dci * 16;
  const float4* xp = (const float4*)(x + off);
  float4* op = (float4*)(out + off);
#pragma unroll
  for (int q4 = 0; q4 < 4; ++q4) {
    float4 xv = xp[q4];
    float4 ov;
    ov.x = xv.x + acc[q4 * 4 + 0] * inv;
    ov.y = xv.y + acc[q4 * 4 + 1] * inv;
    ov.z = xv.z + acc[q4 * 4 + 2] * inv;
    ov.w = xv.w + acc[q4 * 4 + 3] * inv;
    op[q4] = ov;
  }
}

// ---------------------------------------------------------------- launch
extern "C" void kernel_launch(void* const* d_in, const int* in_sizes, int n_in, void* d_out,
                              int out_size, void* d_ws, size_t ws_size, hipStream_t stream) {
  const float* x = (const float*)d_in[0];
  const float* prob = (const float*)d_in[1];
  const float* wfix = (const float*)d_in[2];
  const float* Wq = (const float*)d_in[3];
  const float* Wo = (const float*)d_in[4];
  const float* bo = (const float*)d_in[5];
  float* out = (float*)d_out;
  char* ws = (char*)d_ws;

  float* scores = (float*)(ws + 0);
  int* sel = (int*)(ws + 8192);
  int* kept = (int*)(ws + 16384);
  float* mult = (float*)(ws + 24576);
  u16* wqb = (u16*)(ws + 32768);
  u16* wob = (u16*)(ws + 32768 + 1572864);
  u16* xi = (u16*)(ws + 4194304);
  u16* qkv = (u16*)(ws + 4194304 + 92274688);
  u16* aout = xi;   // head-major aout' reuses xi buffer
  u16* proj = qkv;  // proj output reuses qkv buffer

  k_score<<<8, 256, 0, stream>>>(prob, wfix, scores);
  k_nms<<<8, 256, 0, stream>>>(scores, sel, kept, mult);
  k_castw<<<4096, 256, 0, stream>>>(Wq, Wo, wqb, wob);
  k_gather<<<22528, 256, 0, stream>>>(x, sel, xi);
  k_gemm128<0, 1, 0><<<8448, 256, 0, stream>>>(xi, wqb, qkv, nullptr, 90112, 1536, 512, 12);
  k_attn<<<5632, 256, 0, stream>>>(qkv, aout);
  k_gemm128<1, 0, 1><<<2816, 256, 0, stream>>>(aout, wob, proj, bo, 90112, 512, 512, 4);
  k_final<<<16384, 256, 0, stream>>>(x, proj, kept, mult, out);
}

// Round 16
// 698.443 us; speedup vs baseline: 1.5012x; 1.0220x over previous
//
#include <hip/hip_runtime.h>
#include <type_traits>
#include <utility>

typedef unsigned short u16;
typedef __attribute__((ext_vector_type(8))) short short8;
typedef __attribute__((ext_vector_type(8))) __bf16 bf16v8;
typedef __attribute__((ext_vector_type(4))) float f32x4;
typedef __attribute__((ext_vector_type(16))) float f32x16;

template <typename T, typename = void> struct mfma_ok : std::false_type {};
template <typename T>
struct mfma_ok<T, std::void_t<decltype(__builtin_amdgcn_mfma_f32_16x16x32_bf16(
    std::declval<T>(), std::declval<T>(), std::declval<f32x4>(), 0, 0, 0))>>
    : std::true_type {};
using frag8 = std::conditional_t<mfma_ok<bf16v8>::value, bf16v8, short8>;

#define MFMA16(a, b, c) __builtin_amdgcn_mfma_f32_16x16x32_bf16((a), (b), (c), 0, 0, 0)
#define MFMA32(a, b, c) __builtin_amdgcn_mfma_f32_32x32x16_bf16((a), (b), (c), 0, 0, 0)

__device__ __forceinline__ float bf2f(u16 u) {
  unsigned v = ((unsigned)u) << 16;
  return __builtin_bit_cast(float, v);
}
__device__ __forceinline__ u16 f2bf(float f) {
  unsigned u = __builtin_bit_cast(unsigned, f);
  u = (u + 0x7fffu + ((u >> 16) & 1u)) >> 16;
  return (u16)u;
}
__device__ __forceinline__ unsigned cvtpk_bf16(float lo, float hi) {
  unsigned r;
  asm("v_cvt_pk_bf16_f32 %0, %1, %2" : "=v"(r) : "v"(lo), "v"(hi));
  return r;
}
// async global->LDS, 16B per lane; lds ptr must be wave-uniform base (+lane*16 implicit)
__device__ __forceinline__ void gl16(const u16* g, u16* l) {
  __builtin_amdgcn_global_load_lds((__attribute__((address_space(1))) void*)(g),
                                   (__attribute__((address_space(3))) void*)(l), 16, 0, 0);
}
__device__ __forceinline__ void vmw8() { asm volatile("s_waitcnt vmcnt(8)" ::: "memory"); }
__device__ __forceinline__ void vmw0() { asm volatile("s_waitcnt vmcnt(0)" ::: "memory"); }
__device__ __forceinline__ void lgw0() { asm volatile("s_waitcnt lgkmcnt(0)" ::: "memory"); }

// head-major qkv layout (u16 units): win*393216 + type*131072 + h*16384 + r*64 + d
// head-major aout layout:            win*131072 + h*16384 + r*64 + d

// ---------------------------------------------------------------- score
__global__ void k_score(const float* __restrict__ prob, const float* __restrict__ wfix,
                        float* __restrict__ scores) {
  const int b = blockIdx.x, tid = threadIdx.x;
  __shared__ float ent[64 * 64];
  __shared__ float wf[64];
  if (tid < 64) wf[tid] = wfix[tid];
  const float* pb = prob + (size_t)b * 4 * 4096;
  for (int p = tid; p < 4096; p += 256) {
    float e = 0.f;
#pragma unroll
    for (int ch = 0; ch < 4; ++ch) {
      float v = pb[ch * 4096 + p];
      e -= v * log2f(v + 1e-10f);
    }
    ent[p] = e;
  }
  __syncthreads();
  if (tid < 225) {
    int wy = tid / 15, wx = tid % 15;
    float s = 0.f;
    for (int a = 0; a < 8; ++a)
      for (int c = 0; c < 8; ++c)
        s += ent[(wy * 4 + a) * 64 + wx * 4 + c] * wf[a * 8 + c];
    scores[b * 225 + tid] = s * (1.0f / 64.0f);
  }
}

// ---------------------------------------------------------------- nms
__device__ __forceinline__ float iou_pair(int wa, int wb) {
  float x1a = (float)((wa % 15) * 8), y1a = (float)((wa / 15) * 8);
  float x1b = (float)((wb % 15) * 8), y1b = (float)((wb / 15) * 8);
  float iw = fminf(x1a, x1b) + 15.f - fmaxf(x1a, x1b);
  float ih = fminf(y1a, y1b) + 15.f - fmaxf(y1a, y1b);
  iw = fmaxf(iw, 0.f);
  ih = fmaxf(ih, 0.f);
  float inter = iw * ih;
  return inter / (450.f - inter);
}

__global__ void k_nms(const float* __restrict__ scores, int* __restrict__ sel,
                      int* __restrict__ kept, float* __restrict__ mult) {
  const int b = blockIdx.x, t = threadIdx.x;
  __shared__ float s[225];
  __shared__ int order[225];
  __shared__ unsigned char supp[225];
  __shared__ int idx44[44];
  __shared__ int ks[225];
  __shared__ float ml[225];
  if (t < 225) s[t] = scores[b * 225 + t];
  __syncthreads();
  if (t < 225) {
    float st = s[t];
    int r = 0;
    for (int j = 0; j < 225; ++j) {
      float sj = s[j];
      r += (sj > st) || (sj == st && j < t);
    }
    order[r] = t;
    supp[t] = 0;
    ks[t] = -1;
    ml[t] = 0.f;
  }
  __syncthreads();
  for (int i = 0; i < 224; ++i) {
    if (t > i && t < 225 && !supp[i]) {
      if (iou_pair(order[i], order[t]) > 0.2f) supp[t] = 1;
    }
    __syncthreads();
  }
  if (t == 0) {
    int k = 0;
    for (int i = 0; i < 225 && k < 44; ++i)
      if (!supp[i]) idx44[k++] = order[i];
    while (k < 44) idx44[k++] = order[224];
    for (int k2 = 0; k2 < 44; ++k2) {
      int w = idx44[k2];
      if (ks[w] < 0) ks[w] = k2;
      ml[w] += 1.f;
    }
  }
  __syncthreads();
  if (t < 225) {
    kept[b * 225 + t] = ks[t];
    mult[b * 225 + t] = ml[t];
  }
  if (t < 44) sel[b * 44 + t] = idx44[t];
}

// ---------------------------------------------------------------- weight cast
__global__ void k_castw(const float* __restrict__ Wq, const float* __restrict__ Wo,
                        u16* __restrict__ wqb, u16* __restrict__ wob) {
  int idx = blockIdx.x * 256 + threadIdx.x;
  if (idx < 786432) wqb[idx] = f2bf(Wq[idx]);
  int i2 = idx - 786432;
  if (i2 >= 0 && i2 < 262144) wob[i2] = f2bf(Wo[i2]);
}

// ---------------------------------------------------------------- gather + bilinear (direct 4-tap)
__global__ __launch_bounds__(256) void k_gather(const float* __restrict__ x,
                                                const int* __restrict__ sel,
                                                u16* __restrict__ xi) {
  const size_t idx = (size_t)blockIdx.x * 256 + threadIdx.x;
  const int dc = (int)(idx & 63);
  const int pq = (int)((idx >> 6) & 255);
  const int g = (int)(idx >> 14);
  const int b = g / 44;
  const int w = sel[g];
  const int sy = (w / 15) * 8, sx = (w % 15) * 8;
  const int p = pq >> 4, q = pq & 15;
  float rp = ((float)p + 0.5f) * 0.9375f;
  int i0 = (int)rp;
  float fp = rp - (float)i0;
  float rq = ((float)q + 0.5f) * 0.9375f;
  int j0 = (int)rq;
  float fq = rq - (float)j0;
  const float w00 = (1.f - fp) * (1.f - fq), w01 = (1.f - fp) * fq;
  const float w10 = fp * (1.f - fq), w11 = fp * fq;
  const float* xb = x + ((size_t)b * 16384 + (size_t)(sy + i0) * 128 + sx + j0) * 512 + dc * 8;
  const float4* t00 = (const float4*)xb;
  const float4* t01 = (const float4*)(xb + 512);
  const float4* t10 = (const float4*)(xb + 512 * 128);
  const float4* t11 = (const float4*)(xb + 512 * 129);
  float acc[8];
#pragma unroll
  for (int h = 0; h < 2; ++h) {
    float4 a = t00[h], bb = t01[h], c = t10[h], d = t11[h];
    acc[h * 4 + 0] = w00 * a.x + w01 * bb.x + w10 * c.x + w11 * d.x;
    acc[h * 4 + 1] = w00 * a.y + w01 * bb.y + w10 * c.y + w11 * d.y;
    acc[h * 4 + 2] = w00 * a.z + w01 * bb.z + w10 * c.z + w11 * d.z;
    acc[h * 4 + 3] = w00 * a.w + w01 * bb.w + w10 * c.w + w11 * d.w;
  }
  short8 o;
#pragma unroll
  for (int e = 0; e < 8; ++e) o[e] = (short)f2bf(acc[e]);
  *(short8*)&xi[((size_t)g * 256 + pq) * 512 + dc * 8] = o;
}

// ---------------------------------------------------------------- GEMM 128x128, BK=64, 4 waves
// Counted-vmcnt dbuf + T2 XOR swizzle; 2 blocks/CU. Epilogue packs C through LDS -> 8x 1KB
// contiguous dwordx4 stores per wave.
template <int BIAS, int OPERM, int APERM>
__global__ __launch_bounds__(256, 2) void k_gemm128(const u16* __restrict__ A,
                                                    const u16* __restrict__ B, u16* __restrict__ C,
                                                    const float* __restrict__ bias, int M, int N,
                                                    int K, int nbn) {
  __shared__ u16 smem[32768];  // sA = smem[0..16383], sB = smem[16384..32767]; reused by epilogue
  u16* sA = smem;
  u16* sB = smem + 16384;
  const int tid = threadIdx.x, lane = tid & 63, wv = tid >> 6;
  const int f = blockIdx.x;
  const int q8 = gridDim.x >> 3;
  const int wg = (f & 7) * q8 + (f >> 3);  // bijective XCD swizzle (nwg % 8 == 0)
  const int bm = wg / nbn, bn = wg % nbn;
  const int wm = (wv >> 1) * 64, wn = (wv & 1) * 64;
  const int l15 = lane & 15, k8 = (lane >> 4) * 8;
  const int xorv = (l15 & 7) * 8;  // read-side swizzle (elements)
  const int srow = tid >> 3;                     // 0..31 (rows within 32-row chunk)
  const int sc8 = ((tid ^ (tid >> 3)) & 7) * 8;  // pre-swizzled source col
  const int arow0 = bm * 128 + srow, brow0 = bn * 128 + srow;

  f32x4 acc[4][4] = {};

  // STAGE tile kt into buf: 8 gl16 (4 chunks x A,B), 32 rows per chunk
#define STAGE(kt, buf)                                                                      \
  {                                                                                         \
    _Pragma("unroll") for (int c = 0; c < 4; ++c) {                                         \
      const int ar = arow0 + c * 32;                                                        \
      size_t aoffs = APERM ? ((size_t)(ar >> 8) * 131072 + (size_t)(kt) * 16384 +           \
                              (size_t)(ar & 255) * 64 + sc8)                                \
                           : ((size_t)ar * K + (kt) * 64 + sc8);                            \
      gl16(A + aoffs, &sA[(buf) * 8192 + c * 2048 + wv * 512]);                             \
      gl16(B + (size_t)(brow0 + c * 32) * K + (kt) * 64 + sc8,                              \
           &sB[(buf) * 8192 + c * 2048 + wv * 512]);                                        \
    }                                                                                       \
  }

  STAGE(0, 0);
  STAGE(1, 1);

  for (int t = 0; t < 8; ++t) {
    const int buf = t & 1;
    if (t == 7)
      vmw0();
    else
      vmw8();  // counted: next tile's 8 loads stay in flight
    __builtin_amdgcn_sched_barrier(0);
    __builtin_amdgcn_s_barrier();  // tile t resident for all waves
    frag8 af[4][2], bf[4][2];
#pragma unroll
    for (int i = 0; i < 4; ++i)
#pragma unroll
      for (int kk = 0; kk < 2; ++kk) {
        af[i][kk] =
            *(const frag8*)&sA[buf * 8192 + (wm + i * 16 + l15) * 64 + ((kk * 32 + k8) ^ xorv)];
        bf[i][kk] =
            *(const frag8*)&sB[buf * 8192 + (wn + i * 16 + l15) * 64 + ((kk * 32 + k8) ^ xorv)];
      }
    __builtin_amdgcn_s_setprio(1);
#pragma unroll
    for (int i = 0; i < 4; ++i)
#pragma unroll
      for (int j = 0; j < 4; ++j)
#pragma unroll
        for (int kk = 0; kk < 2; ++kk)
          acc[i][j] = MFMA16(af[i][kk], bf[j][kk], acc[i][j]);
    __builtin_amdgcn_s_setprio(0);
    lgw0();  // this wave's ds_reads fully retired before buf can be overwritten
    __builtin_amdgcn_sched_barrier(0);
    __builtin_amdgcn_s_barrier();  // all waves done reading buf
    if (t < 6) STAGE(t + 2, buf);  // issued here: flies under next tile's compute
  }
#undef STAGE

  // epilogue: pack through LDS (per-wave disjoint region), store contiguous 16B/lane.
  const int cc = lane & 15, rr = (lane >> 4) * 4;
  u16* sc = smem + wv * 4352;  // [64][68] per wave
#pragma unroll
  for (int i = 0; i < 4; ++i)
#pragma unroll
    for (int j = 0; j < 4; ++j) {
      int cloc = j * 16 + cc;
      float badd = BIAS ? bias[bn * 128 + wn + cloc] : 0.f;
#pragma unroll
      for (int e = 0; e < 4; ++e)
        sc[(i * 16 + rr + e) * 68 + cloc] = f2bf(acc[i][j][e] + badd);
    }
  asm volatile("" ::: "memory");  // in-wave LDS write->read ordering (compiler fence)
  const int row0 = bm * 128 + wm, col0 = bn * 128 + wn;
  u16* Cb;
  size_t rstride;
  if (OPERM) {
    Cb = C + (size_t)(row0 >> 8) * 393216 + (size_t)(col0 >> 9) * 131072 +
         (size_t)((col0 >> 6) & 7) * 16384 + (size_t)(row0 & 255) * 64;
    rstride = 64;
  } else {
    Cb = C + (size_t)row0 * N + col0;
    rstride = (size_t)N;
  }
#pragma unroll
  for (int rep = 0; rep < 8; ++rep) {
    int r = rep * 8 + (lane >> 3);
    int c8 = (lane & 7) * 8;
    uint2 lo = *(const uint2*)&sc[r * 68 + c8];
    uint2 hi = *(const uint2*)&sc[r * 68 + c8 + 4];
    *(int4*)&Cb[(size_t)r * rstride + c8] = make_int4((int)lo.x, (int)lo.y, (int)hi.x, (int)hi.y);
  }
}

// ---------------------------------------------------------------- attention (swapped 32x32)
// grid 5632: 2 blocks per (win,head), each 128 q-rows; wave owns ONE 32-row q-tile.
// SINGLE-buffered K/V staged inside barriers (no prefetch regs -> no spill at (256,4);
// 16 waves/CU of out-of-phase blocks cover the staging latency). Head-major layout.
__global__ __launch_bounds__(256, 4) void k_attn(const u16* __restrict__ qkv,
                                                 u16* __restrict__ aout) {
  const int g = blockIdx.x;
  const int win = g % 352;
  const int hq = g / 352;  // 0..15
  const int h = hq & 7, qh = hq >> 3;
  const int tid = threadIdx.x, lane = tid & 63, wv = tid >> 6;
  const int l31 = lane & 31, l5 = lane >> 5;
  __shared__ u16 smem[8832];  // Kb[64][68] (4352 u16) | Vt[64][70] (4480 u16)
  u16* KbB = smem;
  u16* VtB = smem + 4352;
  const u16* qbase = qkv + (size_t)win * 393216 + (size_t)h * 16384;
  const u16* kbase = qbase + 131072;
  const u16* vbase = qbase + 262144;
  const int prow = tid >> 2, pc16 = (tid & 3) * 16;
  const int qrow0 = qh * 128 + wv * 32;

  // Q B-frags (single 32-row tile per wave)
  frag8 qf[4];
#pragma unroll
  for (int c = 0; c < 4; ++c)
    qf[c] = *(const frag8*)(qbase + (size_t)(qrow0 + l31) * 64 + c * 16 + l5 * 8);

  f32x16 of[2] = {};
  float m_run = -3e38f;
  float l_run = 0.f;

  for (int kb = 0; kb < 4; ++kb) {
    __syncthreads();  // all waves done computing previous kb before overwrite
    {
      const u16* kp = kbase + (size_t)(kb * 64 + prow) * 64 + pc16;
      short8 ka = *(const short8*)kp;
      short8 kb2 = *(const short8*)(kp + 8);
      const u16* vp = vbase + (size_t)(kb * 64 + prow) * 64 + pc16;
      short8 va = *(const short8*)vp;
      short8 vb2 = *(const short8*)(vp + 8);
      *(short8*)&KbB[prow * 68 + pc16] = ka;
      *(short8*)&KbB[prow * 68 + pc16 + 8] = kb2;
#pragma unroll
      for (int e = 0; e < 8; ++e) {
        VtB[(pc16 + e) * 70 + prow] = (u16)va[e];
        VtB[(pc16 + 8 + e) * 70 + prow] = (u16)vb2[e];
      }
    }
    __syncthreads();  // kb block staged
    f32x16 s0 = {}, s1 = {};
#pragma unroll
    for (int c = 0; c < 4; ++c) {
      frag8 kf0 = *(const frag8*)&KbB[l31 * 68 + c * 16 + l5 * 8];
      frag8 kf1 = *(const frag8*)&KbB[(32 + l31) * 68 + c * 16 + l5 * 8];
      s0 = MFMA32(kf0, qf[c], s0);
      s1 = MFMA32(kf1, qf[c], s1);
    }
    float tm[16];
#pragma unroll
    for (int r = 0; r < 16; ++r) tm[r] = fmaxf(s0[r], s1[r]);
#pragma unroll
    for (int r = 0; r < 8; ++r) tm[r] = fmaxf(tm[r], tm[r + 8]);
#pragma unroll
    for (int r = 0; r < 4; ++r) tm[r] = fmaxf(tm[r], tm[r + 4]);
    float pm = fmaxf(fmaxf(tm[0], tm[1]), fmaxf(tm[2], tm[3]));
    pm = fmaxf(pm, __shfl_xor(pm, 32));
    if (!__all(pm <= m_run + 64.f)) {  // defer-max (thr 8 post-scale)
      float mn = fmaxf(m_run, pm);
      float corr = __expf((m_run - mn) * 0.125f);
      l_run *= corr;
#pragma unroll
      for (int dt = 0; dt < 2; ++dt)
#pragma unroll
        for (int r = 0; r < 16; ++r) of[dt][r] *= corr;
      m_run = mn;
    }
    const float mqt = m_run;
    float ls = 0.f;
#pragma unroll
    for (int kt = 0; kt < 2; ++kt) {
      const f32x16 sv = kt ? s1 : s0;
      float p[16];
#pragma unroll
      for (int r = 0; r < 16; ++r) p[r] = __expf((sv[r] - mqt) * 0.125f);
      float e0 = (p[0] + p[1]) + (p[2] + p[3]);
      float e1 = (p[4] + p[5]) + (p[6] + p[7]);
      float e2 = (p[8] + p[9]) + (p[10] + p[11]);
      float e3 = (p[12] + p[13]) + (p[14] + p[15]);
      ls += (e0 + e1) + (e2 + e3);
#pragma unroll
      for (int cc = 0; cc < 2; ++cc) {
        const int bx = cc * 8;
        unsigned a0 = cvtpk_bf16(p[bx + 0], p[bx + 1]);
        unsigned a1 = cvtpk_bf16(p[bx + 2], p[bx + 3]);
        unsigned b0 = cvtpk_bf16(p[bx + 4], p[bx + 5]);
        unsigned b1 = cvtpk_bf16(p[bx + 6], p[bx + 7]);
        // cross-half exchange: D_new={D.lo,S.lo}, S_new={D.hi,S.hi}
        asm("v_permlane32_swap_b32 %0, %1" : "+v"(a0), "+v"(b0));
        asm("v_permlane32_swap_b32 %0, %1" : "+v"(a1), "+v"(b1));
        uint4 fu;
        fu.x = a0;
        fu.y = a1;
        fu.z = b0;
        fu.w = b1;
        frag8 pb = __builtin_bit_cast(frag8, fu);
#pragma unroll
        for (int dt = 0; dt < 2; ++dt) {
          frag8 va = *(const frag8*)&VtB[(dt * 32 + l31) * 70 + kt * 32 + cc * 16 + l5 * 8];
          of[dt] = MFMA32(va, pb, of[dt]);
        }
      }
    }
    l_run += ls;
  }

  float lt = l_run + __shfl_xor(l_run, 32);
  float inv = 1.0f / lt;
  u16* sc = smem + wv * 2176;  // per-wave [32][68] scratch (reuses K/V LDS)
  __syncthreads();             // all waves done reading K/V
#pragma unroll
  for (int dt = 0; dt < 2; ++dt)
#pragma unroll
    for (int j = 0; j < 4; ++j) {
      unsigned w0 = cvtpk_bf16(of[dt][4 * j + 0] * inv, of[dt][4 * j + 1] * inv);
      unsigned w1 = cvtpk_bf16(of[dt][4 * j + 2] * inv, of[dt][4 * j + 3] * inv);
      *(uint2*)&sc[l31 * 68 + dt * 32 + 8 * j + 4 * l5] = make_uint2(w0, w1);
    }
  asm volatile("" ::: "memory");
  // head-major aout': contiguous 1KB per rep instr
  u16* obase = aout + (size_t)win * 131072 + (size_t)h * 16384 + (size_t)qrow0 * 64;
#pragma unroll
  for (int rep = 0; rep < 4; ++rep) {
    int row = rep * 8 + (lane >> 3);
    uint2 lo = *(const uint2*)&sc[row * 68 + (lane & 7) * 8];
    uint2 hi = *(const uint2*)&sc[row * 68 + (lane & 7) * 8 + 4];
    *(int4*)&obase[(size_t)row * 64 + (lane & 7) * 8] =
        make_int4((int)lo.x, (int)lo.y, (int)hi.x, (int)hi.y);
  }
}

// ---------------------------------------------------------------- finalize
__global__ void k_final(const float* __restrict__ x, const u16* __restrict__ proj,
                        const int* __restrict__ kept, const float* __restrict__ mult,
                        float* __restrict__ out) {
  const size_t idx = (size_t)blockIdx.x * 256 + threadIdx.x;
  const int dci = (int)(idx & 31);
  const int pix = (int)((idx >> 5) & 16383);
  const int b = (int)(idx >> 19);
  const int y = pix >> 7, xc = pix & 127;
  float acc[16];
#pragma unroll
  for (int e = 0; e < 16; ++e) acc[e] = 0.f;
  float c = 0.f;
  const int wyh = y >> 3, wxh = xc >> 3;
#pragma unroll
  for (int a = 0; a < 2; ++a) {
    int wy = wyh - 1 + a;
    if (wy < 0 || wy > 14) continue;
#pragma unroll
    for (int bb = 0; bb < 2; ++bb) {
      int wx = wxh - 1 + bb;
      if (wx < 0 || wx > 14) continue;
      int w = wy * 15 + wx;
      int slot = kept[b * 225 + w];
      if (slot < 0) continue;
      float ml = mult[b * 225 + w];
      c += ml;
      const u16* pr = proj +
                      ((size_t)((b * 44 + slot) * 256 + (y - wy * 8) * 16 + (xc - wx * 8))) * 512 +
                      (size_t)dci * 16;
      short8 v0 = *(const short8*)pr;
      short8 v1 = *(const short8*)(pr + 8);
#pragma unroll
      for (int e = 0; e < 8; ++e) acc[e] += ml * bf2f((u16)v0[e]);
#pragma unroll
      for (int e = 0; e < 8; ++e) acc[8 + e] += ml * bf2f((u16)v1[e]);
    }
  }
  const float inv = 1.f / (c + 1e-10f);
  const size_t off = ((size_t)(b * 16384 + pix)) * 512 + (size_t)dci * 16;
  const float4* xp = (const float4*)(x + off);
  float4* op = (float4*)(out + off);
#pragma unroll
  for (int q4 = 0; q4 < 4; ++q4) {
    float4 xv = xp[q4];
    float4 ov;
    ov.x = xv.x + acc[q4 * 4 + 0] * inv;
    ov.y = xv.y + acc[q4 * 4 + 1] * inv;
    ov.z = xv.z + acc[q4 * 4 + 2] * inv;
    ov.w = xv.w + acc[q4 * 4 + 3] * inv;
    op[q4] = ov;
  }
}

// ---------------------------------------------------------------- launch
extern "C" void kernel_launch(void* const* d_in, const int* in_sizes, int n_in, void* d_out,
                              int out_size, void* d_ws, size_t ws_size, hipStream_t stream) {
  const float* x = (const float*)d_in[0];
  const float* prob = (const float*)d_in[1];
  const float* wfix = (const float*)d_in[2];
  const float* Wq = (const float*)d_in[3];
  const float* Wo = (const float*)d_in[4];
  const float* bo = (const float*)d_in[5];
  float* out = (float*)d_out;
  char* ws = (char*)d_ws;

  float* scores = (float*)(ws + 0);
  int* sel = (int*)(ws + 8192);
  int* kept = (int*)(ws + 16384);
  float* mult = (float*)(ws + 24576);
  u16* wqb = (u16*)(ws + 32768);
  u16* wob = (u16*)(ws + 32768 + 1572864);
  u16* xi = (u16*)(ws + 4194304);
  u16* qkv = (u16*)(ws + 4194304 + 92274688);
  u16* aout = xi;   // head-major aout' reuses xi buffer
  u16* proj = qkv;  // proj output reuses qkv buffer

  k_score<<<8, 256, 0, stream>>>(prob, wfix, scores);
  k_nms<<<8, 256, 0, stream>>>(scores, sel, kept, mult);
  k_castw<<<4096, 256, 0, stream>>>(Wq, Wo, wqb, wob);
  k_gather<<<22528, 256, 0, stream>>>(x, sel, xi);
  k_gemm128<0, 1, 0><<<8448, 256, 0, stream>>>(xi, wqb, qkv, nullptr, 90112, 1536, 512, 12);
  k_attn<<<5632, 256, 0, stream>>>(qkv, aout);
  k_gemm128<1, 0, 1><<<2816, 256, 0, stream>>>(aout, wob, proj, bo, 90112, 512, 512, 4);
  k_final<<<16384, 256, 0, stream>>>(x, proj, kept, mult, out);
}

// Round 17
// 691.840 us; speedup vs baseline: 1.5156x; 1.0095x over previous
//
#include <hip/hip_runtime.h>
#include <type_traits>
#include <utility>

typedef unsigned short u16;
typedef __attribute__((ext_vector_type(8))) short short8;
typedef __attribute__((ext_vector_type(8))) __bf16 bf16v8;
typedef __attribute__((ext_vector_type(4))) float f32x4;
typedef __attribute__((ext_vector_type(16))) float f32x16;

template <typename T, typename = void> struct mfma_ok : std::false_type {};
template <typename T>
struct mfma_ok<T, std::void_t<decltype(__builtin_amdgcn_mfma_f32_16x16x32_bf16(
    std::declval<T>(), std::declval<T>(), std::declval<f32x4>(), 0, 0, 0))>>
    : std::true_type {};
using frag8 = std::conditional_t<mfma_ok<bf16v8>::value, bf16v8, short8>;

#define MFMA16(a, b, c) __builtin_amdgcn_mfma_f32_16x16x32_bf16((a), (b), (c), 0, 0, 0)
#define MFMA32(a, b, c) __builtin_amdgcn_mfma_f32_32x32x16_bf16((a), (b), (c), 0, 0, 0)

__device__ __forceinline__ float bf2f(u16 u) {
  unsigned v = ((unsigned)u) << 16;
  return __builtin_bit_cast(float, v);
}
__device__ __forceinline__ u16 f2bf(float f) {
  unsigned u = __builtin_bit_cast(unsigned, f);
  u = (u + 0x7fffu + ((u >> 16) & 1u)) >> 16;
  return (u16)u;
}
__device__ __forceinline__ unsigned cvtpk_bf16(float lo, float hi) {
  unsigned r;
  asm("v_cvt_pk_bf16_f32 %0, %1, %2" : "=v"(r) : "v"(lo), "v"(hi));
  return r;
}
// async global->LDS, 16B per lane; lds ptr must be wave-uniform base (+lane*16 implicit)
__device__ __forceinline__ void gl16(const u16* g, u16* l) {
  __builtin_amdgcn_global_load_lds((__attribute__((address_space(1))) void*)(g),
                                   (__attribute__((address_space(3))) void*)(l), 16, 0, 0);
}
__device__ __forceinline__ void vmw8() { asm volatile("s_waitcnt vmcnt(8)" ::: "memory"); }
__device__ __forceinline__ void vmw0() { asm volatile("s_waitcnt vmcnt(0)" ::: "memory"); }
__device__ __forceinline__ void lgw0() { asm volatile("s_waitcnt lgkmcnt(0)" ::: "memory"); }

// head-major qkv layout (u16 units): win*393216 + type*131072 + h*16384 + r*64 + d
// head-major aout layout:            win*131072 + h*16384 + r*64 + d

// ---------------------------------------------------------------- score
__global__ void k_score(const float* __restrict__ prob, const float* __restrict__ wfix,
                        float* __restrict__ scores) {
  const int b = blockIdx.x, tid = threadIdx.x;
  __shared__ float ent[64 * 64];
  __shared__ float wf[64];
  if (tid < 64) wf[tid] = wfix[tid];
  const float* pb = prob + (size_t)b * 4 * 4096;
  for (int p = tid; p < 4096; p += 256) {
    float e = 0.f;
#pragma unroll
    for (int ch = 0; ch < 4; ++ch) {
      float v = pb[ch * 4096 + p];
      e -= v * log2f(v + 1e-10f);
    }
    ent[p] = e;
  }
  __syncthreads();
  if (tid < 225) {
    int wy = tid / 15, wx = tid % 15;
    float s = 0.f;
    for (int a = 0; a < 8; ++a)
      for (int c = 0; c < 8; ++c)
        s += ent[(wy * 4 + a) * 64 + wx * 4 + c] * wf[a * 8 + c];
    scores[b * 225 + tid] = s * (1.0f / 64.0f);
  }
}

// ---------------------------------------------------------------- nms
__device__ __forceinline__ float iou_pair(int wa, int wb) {
  float x1a = (float)((wa % 15) * 8), y1a = (float)((wa / 15) * 8);
  float x1b = (float)((wb % 15) * 8), y1b = (float)((wb / 15) * 8);
  float iw = fminf(x1a, x1b) + 15.f - fmaxf(x1a, x1b);
  float ih = fminf(y1a, y1b) + 15.f - fmaxf(y1a, y1b);
  iw = fmaxf(iw, 0.f);
  ih = fmaxf(ih, 0.f);
  float inter = iw * ih;
  return inter / (450.f - inter);
}

__global__ void k_nms(const float* __restrict__ scores, int* __restrict__ sel,
                      int* __restrict__ kept, float* __restrict__ mult) {
  const int b = blockIdx.x, t = threadIdx.x;
  __shared__ float s[225];
  __shared__ int order[225];
  __shared__ unsigned char supp[225];
  __shared__ int idx44[44];
  __shared__ int ks[225];
  __shared__ float ml[225];
  if (t < 225) s[t] = scores[b * 225 + t];
  __syncthreads();
  if (t < 225) {
    float st = s[t];
    int r = 0;
    for (int j = 0; j < 225; ++j) {
      float sj = s[j];
      r += (sj > st) || (sj == st && j < t);
    }
    order[r] = t;
    supp[t] = 0;
    ks[t] = -1;
    ml[t] = 0.f;
  }
  __syncthreads();
  for (int i = 0; i < 224; ++i) {
    if (t > i && t < 225 && !supp[i]) {
      if (iou_pair(order[i], order[t]) > 0.2f) supp[t] = 1;
    }
    __syncthreads();
  }
  if (t == 0) {
    int k = 0;
    for (int i = 0; i < 225 && k < 44; ++i)
      if (!supp[i]) idx44[k++] = order[i];
    while (k < 44) idx44[k++] = order[224];
    for (int k2 = 0; k2 < 44; ++k2) {
      int w = idx44[k2];
      if (ks[w] < 0) ks[w] = k2;
      ml[w] += 1.f;
    }
  }
  __syncthreads();
  if (t < 225) {
    kept[b * 225 + t] = ks[t];
    mult[b * 225 + t] = ml[t];
  }
  if (t < 44) sel[b * 44 + t] = idx44[t];
}

// ---------------------------------------------------------------- weight cast
__global__ void k_castw(const float* __restrict__ Wq, const float* __restrict__ Wo,
                        u16* __restrict__ wqb, u16* __restrict__ wob) {
  int idx = blockIdx.x * 256 + threadIdx.x;
  if (idx < 786432) wqb[idx] = f2bf(Wq[idx]);
  int i2 = idx - 786432;
  if (i2 >= 0 && i2 < 262144) wob[i2] = f2bf(Wo[i2]);
}

// ---------------------------------------------------------------- gather + bilinear (direct 4-tap)
__global__ __launch_bounds__(256) void k_gather(const float* __restrict__ x,
                                                const int* __restrict__ sel,
                                                u16* __restrict__ xi) {
  const size_t idx = (size_t)blockIdx.x * 256 + threadIdx.x;
  const int dc = (int)(idx & 63);
  const int pq = (int)((idx >> 6) & 255);
  const int g = (int)(idx >> 14);
  const int b = g / 44;
  const int w = sel[g];
  const int sy = (w / 15) * 8, sx = (w % 15) * 8;
  const int p = pq >> 4, q = pq & 15;
  float rp = ((float)p + 0.5f) * 0.9375f;
  int i0 = (int)rp;
  float fp = rp - (float)i0;
  float rq = ((float)q + 0.5f) * 0.9375f;
  int j0 = (int)rq;
  float fq = rq - (float)j0;
  const float w00 = (1.f - fp) * (1.f - fq), w01 = (1.f - fp) * fq;
  const float w10 = fp * (1.f - fq), w11 = fp * fq;
  const float* xb = x + ((size_t)b * 16384 + (size_t)(sy + i0) * 128 + sx + j0) * 512 + dc * 8;
  const float4* t00 = (const float4*)xb;
  const float4* t01 = (const float4*)(xb + 512);
  const float4* t10 = (const float4*)(xb + 512 * 128);
  const float4* t11 = (const float4*)(xb + 512 * 129);
  float acc[8];
#pragma unroll
  for (int h = 0; h < 2; ++h) {
    float4 a = t00[h], bb = t01[h], c = t10[h], d = t11[h];
    acc[h * 4 + 0] = w00 * a.x + w01 * bb.x + w10 * c.x + w11 * d.x;
    acc[h * 4 + 1] = w00 * a.y + w01 * bb.y + w10 * c.y + w11 * d.y;
    acc[h * 4 + 2] = w00 * a.z + w01 * bb.z + w10 * c.z + w11 * d.z;
    acc[h * 4 + 3] = w00 * a.w + w01 * bb.w + w10 * c.w + w11 * d.w;
  }
  short8 o;
#pragma unroll
  for (int e = 0; e < 8; ++e) o[e] = (short)f2bf(acc[e]);
  *(short8*)&xi[((size_t)g * 256 + pq) * 512 + dc * 8] = o;
}

// ---------------------------------------------------------------- GEMM 128x128, BK=64, 4 waves
// Counted-vmcnt dbuf + T2 XOR swizzle; 2 blocks/CU. Epilogue packs C through LDS -> 8x 1KB
// contiguous dwordx4 stores per wave.
template <int BIAS, int OPERM, int APERM>
__global__ __launch_bounds__(256, 2) void k_gemm128(const u16* __restrict__ A,
                                                    const u16* __restrict__ B, u16* __restrict__ C,
                                                    const float* __restrict__ bias, int M, int N,
                                                    int K, int nbn) {
  __shared__ u16 smem[32768];  // sA = smem[0..16383], sB = smem[16384..32767]; reused by epilogue
  u16* sA = smem;
  u16* sB = smem + 16384;
  const int tid = threadIdx.x, lane = tid & 63, wv = tid >> 6;
  const int f = blockIdx.x;
  const int q8 = gridDim.x >> 3;
  const int wg = (f & 7) * q8 + (f >> 3);  // bijective XCD swizzle (nwg % 8 == 0)
  const int bm = wg / nbn, bn = wg % nbn;
  const int wm = (wv >> 1) * 64, wn = (wv & 1) * 64;
  const int l15 = lane & 15, k8 = (lane >> 4) * 8;
  const int xorv = (l15 & 7) * 8;  // read-side swizzle (elements)
  const int srow = tid >> 3;                     // 0..31 (rows within 32-row chunk)
  const int sc8 = ((tid ^ (tid >> 3)) & 7) * 8;  // pre-swizzled source col
  const int arow0 = bm * 128 + srow, brow0 = bn * 128 + srow;

  f32x4 acc[4][4] = {};

  // STAGE tile kt into buf: 8 gl16 (4 chunks x A,B), 32 rows per chunk
#define STAGE(kt, buf)                                                                      \
  {                                                                                         \
    _Pragma("unroll") for (int c = 0; c < 4; ++c) {                                         \
      const int ar = arow0 + c * 32;                                                        \
      size_t aoffs = APERM ? ((size_t)(ar >> 8) * 131072 + (size_t)(kt) * 16384 +           \
                              (size_t)(ar & 255) * 64 + sc8)                                \
                           : ((size_t)ar * K + (kt) * 64 + sc8);                            \
      gl16(A + aoffs, &sA[(buf) * 8192 + c * 2048 + wv * 512]);                             \
      gl16(B + (size_t)(brow0 + c * 32) * K + (kt) * 64 + sc8,                              \
           &sB[(buf) * 8192 + c * 2048 + wv * 512]);                                        \
    }                                                                                       \
  }

  STAGE(0, 0);
  STAGE(1, 1);

  for (int t = 0; t < 8; ++t) {
    const int buf = t & 1;
    if (t == 7)
      vmw0();
    else
      vmw8();  // counted: next tile's 8 loads stay in flight
    __builtin_amdgcn_sched_barrier(0);
    __builtin_amdgcn_s_barrier();  // tile t resident for all waves
    frag8 af[4][2], bf[4][2];
#pragma unroll
    for (int i = 0; i < 4; ++i)
#pragma unroll
      for (int kk = 0; kk < 2; ++kk) {
        af[i][kk] =
            *(const frag8*)&sA[buf * 8192 + (wm + i * 16 + l15) * 64 + ((kk * 32 + k8) ^ xorv)];
        bf[i][kk] =
            *(const frag8*)&sB[buf * 8192 + (wn + i * 16 + l15) * 64 + ((kk * 32 + k8) ^ xorv)];
      }
    __builtin_amdgcn_s_setprio(1);
#pragma unroll
    for (int i = 0; i < 4; ++i)
#pragma unroll
      for (int j = 0; j < 4; ++j)
#pragma unroll
        for (int kk = 0; kk < 2; ++kk)
          acc[i][j] = MFMA16(af[i][kk], bf[j][kk], acc[i][j]);
    __builtin_amdgcn_s_setprio(0);
    lgw0();  // this wave's ds_reads fully retired before buf can be overwritten
    __builtin_amdgcn_sched_barrier(0);
    __builtin_amdgcn_s_barrier();  // all waves done reading buf
    if (t < 6) STAGE(t + 2, buf);  // issued here: flies under next tile's compute
  }
#undef STAGE

  // epilogue: pack through LDS (per-wave disjoint region), store contiguous 16B/lane.
  const int cc = lane & 15, rr = (lane >> 4) * 4;
  u16* sc = smem + wv * 4352;  // [64][68] per wave
#pragma unroll
  for (int i = 0; i < 4; ++i)
#pragma unroll
    for (int j = 0; j < 4; ++j) {
      int cloc = j * 16 + cc;
      float badd = BIAS ? bias[bn * 128 + wn + cloc] : 0.f;
#pragma unroll
      for (int e = 0; e < 4; ++e)
        sc[(i * 16 + rr + e) * 68 + cloc] = f2bf(acc[i][j][e] + badd);
    }
  asm volatile("" ::: "memory");  // in-wave LDS write->read ordering (compiler fence)
  const int row0 = bm * 128 + wm, col0 = bn * 128 + wn;
  u16* Cb;
  size_t rstride;
  if (OPERM) {
    Cb = C + (size_t)(row0 >> 8) * 393216 + (size_t)(col0 >> 9) * 131072 +
         (size_t)((col0 >> 6) & 7) * 16384 + (size_t)(row0 & 255) * 64;
    rstride = 64;
  } else {
    Cb = C + (size_t)row0 * N + col0;
    rstride = (size_t)N;
  }
#pragma unroll
  for (int rep = 0; rep < 8; ++rep) {
    int r = rep * 8 + (lane >> 3);
    int c8 = (lane & 7) * 8;
    uint2 lo = *(const uint2*)&sc[r * 68 + c8];
    uint2 hi = *(const uint2*)&sc[r * 68 + c8 + 4];
    *(int4*)&Cb[(size_t)r * rstride + c8] = make_int4((int)lo.x, (int)lo.y, (int)hi.x, (int)hi.y);
  }
}

// ---------------------------------------------------------------- attention (swapped 32x32)
// grid 2816: ONE 512-thread block per (win,head); 8 waves x 32 q-rows. K/V for ALL 256 keys
// staged once (halves fetch + V-scatter vs 2-block version); kb loop is barrier-free.
// LDS 68.4KB -> 2 blocks/CU = 16 waves. Head-major layout.
__global__ __launch_bounds__(512, 4) void k_attn(const u16* __restrict__ qkv,
                                                 u16* __restrict__ aout) {
  const int g = blockIdx.x;
  const int win = g % 352, h = g / 352;
  const int tid = threadIdx.x, lane = tid & 63, wv = tid >> 6;
  const int l31 = lane & 31, l5 = lane >> 5;
  __shared__ u16 smem[34176];  // Kb[256][68] (17408 u16) | Vt[64][262] (16768 u16)
  u16* KbB = smem;
  u16* VtB = smem + 17408;
  const u16* qbase = qkv + (size_t)win * 393216 + (size_t)h * 16384;
  const u16* kbase = qbase + 131072;
  const u16* vbase = qbase + 262144;
  const int qrow0 = wv * 32;

  // Q B-frags (single 32-row tile per wave)
  frag8 qf[4];
#pragma unroll
  for (int c = 0; c < 4; ++c)
    qf[c] = *(const frag8*)(qbase + (size_t)(qrow0 + l31) * 64 + c * 16 + l5 * 8);
  // Stage all 256 K rows + V^T once: thread owns row srow=tid>>1, half kcol=(tid&1)*32
  {
    const int srow = tid >> 1, kcol = (tid & 1) * 32;
    const u16* kp = kbase + (size_t)srow * 64 + kcol;
    const u16* vp = vbase + (size_t)srow * 64 + kcol;
    short8 kv[4], vv[4];
#pragma unroll
    for (int c4 = 0; c4 < 4; ++c4) {
      kv[c4] = *(const short8*)(kp + c4 * 8);
      vv[c4] = *(const short8*)(vp + c4 * 8);
    }
#pragma unroll
    for (int c4 = 0; c4 < 4; ++c4) *(short8*)&KbB[srow * 68 + kcol + c4 * 8] = kv[c4];
#pragma unroll
    for (int c4 = 0; c4 < 4; ++c4)
#pragma unroll
      for (int e = 0; e < 8; ++e) VtB[(kcol + c4 * 8 + e) * 262 + srow] = (u16)vv[c4][e];
  }
  __syncthreads();  // K/V resident; kb loop is barrier-free

  f32x16 of[2] = {};
  float m_run = -3e38f;
  float l_run = 0.f;

  for (int kb = 0; kb < 4; ++kb) {
    f32x16 s0 = {}, s1 = {};
#pragma unroll
    for (int c = 0; c < 4; ++c) {
      frag8 kf0 = *(const frag8*)&KbB[(kb * 64 + l31) * 68 + c * 16 + l5 * 8];
      frag8 kf1 = *(const frag8*)&KbB[(kb * 64 + 32 + l31) * 68 + c * 16 + l5 * 8];
      s0 = MFMA32(kf0, qf[c], s0);
      s1 = MFMA32(kf1, qf[c], s1);
    }
    float tm[16];
#pragma unroll
    for (int r = 0; r < 16; ++r) tm[r] = fmaxf(s0[r], s1[r]);
#pragma unroll
    for (int r = 0; r < 8; ++r) tm[r] = fmaxf(tm[r], tm[r + 8]);
#pragma unroll
    for (int r = 0; r < 4; ++r) tm[r] = fmaxf(tm[r], tm[r + 4]);
    float pm = fmaxf(fmaxf(tm[0], tm[1]), fmaxf(tm[2], tm[3]));
    pm = fmaxf(pm, __shfl_xor(pm, 32));
    if (!__all(pm <= m_run + 64.f)) {  // defer-max (thr 8 post-scale)
      float mn = fmaxf(m_run, pm);
      float corr = __expf((m_run - mn) * 0.125f);
      l_run *= corr;
#pragma unroll
      for (int dt = 0; dt < 2; ++dt)
#pragma unroll
        for (int r = 0; r < 16; ++r) of[dt][r] *= corr;
      m_run = mn;
    }
    const float mqt = m_run;
    float ls = 0.f;
#pragma unroll
    for (int kt = 0; kt < 2; ++kt) {
      const f32x16 sv = kt ? s1 : s0;
      float p[16];
#pragma unroll
      for (int r = 0; r < 16; ++r) p[r] = __expf((sv[r] - mqt) * 0.125f);
      float e0 = (p[0] + p[1]) + (p[2] + p[3]);
      float e1 = (p[4] + p[5]) + (p[6] + p[7]);
      float e2 = (p[8] + p[9]) + (p[10] + p[11]);
      float e3 = (p[12] + p[13]) + (p[14] + p[15]);
      ls += (e0 + e1) + (e2 + e3);
#pragma unroll
      for (int cc = 0; cc < 2; ++cc) {
        const int bx = cc * 8;
        unsigned a0 = cvtpk_bf16(p[bx + 0], p[bx + 1]);
        unsigned a1 = cvtpk_bf16(p[bx + 2], p[bx + 3]);
        unsigned b0 = cvtpk_bf16(p[bx + 4], p[bx + 5]);
        unsigned b1 = cvtpk_bf16(p[bx + 6], p[bx + 7]);
        // cross-half exchange: D_new={D.lo,S.lo}, S_new={D.hi,S.hi}
        asm("v_permlane32_swap_b32 %0, %1" : "+v"(a0), "+v"(b0));
        asm("v_permlane32_swap_b32 %0, %1" : "+v"(a1), "+v"(b1));
        uint4 fu;
        fu.x = a0;
        fu.y = a1;
        fu.z = b0;
        fu.w = b1;
        frag8 pb = __builtin_bit_cast(frag8, fu);
#pragma unroll
        for (int dt = 0; dt < 2; ++dt) {
          frag8 va =
              *(const frag8*)&VtB[(dt * 32 + l31) * 262 + kb * 64 + kt * 32 + cc * 16 + l5 * 8];
          of[dt] = MFMA32(va, pb, of[dt]);
        }
      }
    }
    l_run += ls;
  }

  float lt = l_run + __shfl_xor(l_run, 32);
  float inv = 1.0f / lt;
  u16* sc = smem + wv * 2176;  // per-wave [32][68] scratch (reuses Kb LDS; 8*2176=17408 fits)
  __syncthreads();             // all waves done reading K/V
#pragma unroll
  for (int dt = 0; dt < 2; ++dt)
#pragma unroll
    for (int j = 0; j < 4; ++j) {
      unsigned w0 = cvtpk_bf16(of[dt][4 * j + 0] * inv, of[dt][4 * j + 1] * inv);
      unsigned w1 = cvtpk_bf16(of[dt][4 * j + 2] * inv, of[dt][4 * j + 3] * inv);
      *(uint2*)&sc[l31 * 68 + dt * 32 + 8 * j + 4 * l5] = make_uint2(w0, w1);
    }
  asm volatile("" ::: "memory");
  // head-major aout': contiguous 1KB per rep instr
  u16* obase = aout + (size_t)win * 131072 + (size_t)h * 16384 + (size_t)qrow0 * 64;
#pragma unroll
  for (int rep = 0; rep < 4; ++rep) {
    int row = rep * 8 + (lane >> 3);
    uint2 lo = *(const uint2*)&sc[row * 68 + (lane & 7) * 8];
    uint2 hi = *(const uint2*)&sc[row * 68 + (lane & 7) * 8 + 4];
    *(int4*)&obase[(size_t)row * 64 + (lane & 7) * 8] =
        make_int4((int)lo.x, (int)lo.y, (int)hi.x, (int)hi.y);
  }
}

// ---------------------------------------------------------------- finalize
__global__ void k_final(const float* __restrict__ x, const u16* __restrict__ proj,
                        const int* __restrict__ kept, const float* __restrict__ mult,
                        float* __restrict__ out) {
  const size_t idx = (size_t)blockIdx.x * 256 + threadIdx.x;
  const int dci = (int)(idx & 31);
  const int pix = (int)((idx >> 5) & 16383);
  const int b = (int)(idx >> 19);
  const int y = pix >> 7, xc = pix & 127;
  float acc[16];
#pragma unroll
  for (int e = 0; e < 16; ++e) acc[e] = 0.f;
  float c = 0.f;
  const int wyh = y >> 3, wxh = xc >> 3;
#pragma unroll
  for (int a = 0; a < 2; ++a) {
    int wy = wyh - 1 + a;
    if (wy < 0 || wy > 14) continue;
#pragma unroll
    for (int bb = 0; bb < 2; ++bb) {
      int wx = wxh - 1 + bb;
      if (wx < 0 || wx > 14) continue;
      int w = wy * 15 + wx;
      int slot = kept[b * 225 + w];
      if (slot < 0) continue;
      float ml = mult[b * 225 + w];
      c += ml;
      const u16* pr = proj +
                      ((size_t)((b * 44 + slot) * 256 + (y - wy * 8) * 16 + (xc - wx * 8))) * 512 +
                      (size_t)dci * 16;
      short8 v0 = *(const short8*)pr;
      short8 v1 = *(const short8*)(pr + 8);
#pragma unroll
      for (int e = 0; e < 8; ++e) acc[e] += ml * bf2f((u16)v0[e]);
#pragma unroll
      for (int e = 0; e < 8; ++e) acc[8 + e] += ml * bf2f((u16)v1[e]);
    }
  }
  const float inv = 1.f / (c + 1e-10f);
  const size_t off = ((size_t)(b * 16384 + pix)) * 512 + (size_t)dci * 16;
  const float4* xp = (const float4*)(x + off);
  float4* op = (float4*)(out + off);
#pragma unroll
  for (int q4 = 0; q4 < 4; ++q4) {
    float4 xv = xp[q4];
    float4 ov;
    ov.x = xv.x + acc[q4 * 4 + 0] * inv;
    ov.y = xv.y + acc[q4 * 4 + 1] * inv;
    ov.z = xv.z + acc[q4 * 4 + 2] * inv;
    ov.w = xv.w + acc[q4 * 4 + 3] * inv;
    op[q4] = ov;
  }
}

// ---------------------------------------------------------------- launch
extern "C" void kernel_launch(void* const* d_in, const int* in_sizes, int n_in, void* d_out,
                              int out_size, void* d_ws, size_t ws_size, hipStream_t stream) {
  const float* x = (const float*)d_in[0];
  const float* prob = (const float*)d_in[1];
  const float* wfix = (const float*)d_in[2];
  const float* Wq = (const float*)d_in[3];
  const float* Wo = (const float*)d_in[4];
  const float* bo = (const float*)d_in[5];
  float* out = (float*)d_out;
  char* ws = (char*)d_ws;

  float* scores = (float*)(ws + 0);
  int* sel = (int*)(ws + 8192);
  int* kept = (int*)(ws + 16384);
  float* mult = (float*)(ws + 24576);
  u16* wqb = (u16*)(ws + 32768);
  u16* wob = (u16*)(ws + 32768 + 1572864);
  u16* xi = (u16*)(ws + 4194304);
  u16* qkv = (u16*)(ws + 4194304 + 92274688);
  u16* aout = xi;   // head-major aout' reuses xi buffer
  u16* proj = qkv;  // proj output reuses qkv buffer

  k_score<<<8, 256, 0, stream>>>(prob, wfix, scores);
  k_nms<<<8, 256, 0, stream>>>(scores, sel, kept, mult);
  k_castw<<<4096, 256, 0, stream>>>(Wq, Wo, wqb, wob);
  k_gather<<<22528, 256, 0, stream>>>(x, sel, xi);
  k_gemm128<0, 1, 0><<<8448, 256, 0, stream>>>(xi, wqb, qkv, nullptr, 90112, 1536, 512, 12);
  k_attn<<<2816, 512, 0, stream>>>(qkv, aout);
  k_gemm128<1, 0, 1><<<2816, 256, 0, stream>>>(aout, wob, proj, bo, 90112, 512, 512, 4);
  k_final<<<16384, 256, 0, stream>>>(x, proj, kept, mult, out);
}